// Round 1
// baseline (808.460 us; speedup 1.0000x reference)
//
#include <hip/hip_runtime.h>

#define N_NODES 50000
#define N_EDGES 625000
#define H 128
#define B 32

// ---------------------------------------------------------------------------
// K2: edge scatter.  thread = (edge, feature).  aggd[d] += x[s]; aggu[s] += x[d]
// ---------------------------------------------------------------------------
__global__ __launch_bounds__(256) void scatter_kernel(
    const float* __restrict__ x,
    const int* __restrict__ ei,
    float* __restrict__ aggd,
    float* __restrict__ aggu)
{
    long long t = (long long)blockIdx.x * 256 + threadIdx.x;
    int e = (int)(t >> 7);
    int f = (int)(t & 127);
    if (e >= N_EDGES) return;
    int s = ei[e];
    int d = ei[N_EDGES + e];
    float vs = x[(size_t)s * H + f];
    float vd = x[(size_t)d * H + f];
    unsafeAtomicAdd(&aggd[(size_t)d * H + f], vs);
    unsafeAtomicAdd(&aggu[(size_t)s * H + f], vd);
}

// ---------------------------------------------------------------------------
// K3: fused per-node pipeline.  One wave (64 lanes) per node, 4 nodes/block.
// Each lane owns features (lane) and (lane+64).
// Overwrites aggd/aggu in place with h_down/h_up.
// ---------------------------------------------------------------------------
__global__ __launch_bounds__(256) void node_kernel(
    const float* __restrict__ x,
    float* __restrict__ aggd,
    float* __restrict__ aggu,
    const float* __restrict__ eps_d_p,
    const float* __restrict__ eps_u_p,
    const float* __restrict__ dw1, const float* __restrict__ dg1,
    const float* __restrict__ db1, const float* __restrict__ dw2,
    const float* __restrict__ uw1, const float* __restrict__ ug1,
    const float* __restrict__ ub1, const float* __restrict__ uw2,
    const float* __restrict__ ln1g, const float* __restrict__ ln1b,
    const float* __restrict__ ln2g, const float* __restrict__ ln2b,
    const float* __restrict__ dir_emb)
{
    __shared__ float hd_lds[4][128];
    __shared__ float hu_lds[4][128];
    __shared__ float r_lds[4][64];

    int w = threadIdx.x >> 6;
    int lane = threadIdx.x & 63;
    int node = blockIdx.x * 4 + w;          // grid = 12500, exact
    int f0 = lane, f1 = lane + 64;

    float epsd = 1.0f + eps_d_p[0];
    float epsu = 1.0f + eps_u_p[0];

    size_t rowb = (size_t)node * H;
    float x0 = x[rowb + f0], x1 = x[rowb + f1];
    float hd0 = epsd * x0 + aggd[rowb + f0];
    float hd1 = epsd * x1 + aggd[rowb + f1];
    float hu0 = epsu * x0 + aggu[rowb + f0];
    float hu1 = epsu * x1 + aggu[rowb + f1];

    hd_lds[w][f0] = hd0; hd_lds[w][f1] = hd1;
    hu_lds[w][f0] = hu0; hu_lds[w][f1] = hu1;
    __syncthreads();

    // stage-1 GEMV: lanes 0..31 -> down (col j=lane), lanes 32..63 -> up
    int j = lane & 31;
    const float* w1   = (lane < 32) ? dw1 : uw1;
    const float* hrow = (lane < 32) ? hd_lds[w] : hu_lds[w];
    float t = 0.f;
    #pragma unroll 8
    for (int i = 0; i < H; ++i) t += hrow[i] * w1[i * B + j];

    // LN over B=32 (xor masks <=16 keep the two 32-lane halves independent)
    float s = t, s2 = t * t;
    #pragma unroll
    for (int m = 1; m <= 16; m <<= 1) {
        s  += __shfl_xor(s, m);
        s2 += __shfl_xor(s2, m);
    }
    float mean = s * (1.f / 32.f);
    float var  = s2 * (1.f / 32.f) - mean * mean;
    float rs   = rsqrtf(var + 1e-5f);
    float g  = (lane < 32) ? dg1[j] : ug1[j];
    float bb = (lane < 32) ? db1[j] : ub1[j];
    float r = fmaxf((t - mean) * rs * g + bb, 0.f);
    r_lds[w][lane] = r;   // [0..31]=down relu, [32..63]=up relu
    __syncthreads();

    // stage-2 GEMV: each lane computes features f0,f1 for both directions
    float gd0 = 0.f, gd1 = 0.f, gu0 = 0.f, gu1 = 0.f;
    #pragma unroll 8
    for (int jj = 0; jj < B; ++jj) {
        float rd = r_lds[w][jj];
        float ru = r_lds[w][32 + jj];
        gd0 += rd * dw2[jj * H + f0];
        gd1 += rd * dw2[jj * H + f1];
        gu0 += ru * uw2[jj * H + f0];
        gu1 += ru * uw2[jj * H + f1];
    }
    float a_d0 = fmaxf(gd0 + dir_emb[f0], 0.f);
    float a_d1 = fmaxf(gd1 + dir_emb[f1], 0.f);
    float a_u0 = fmaxf(gu0 + dir_emb[H + f0], 0.f);
    float a_u1 = fmaxf(gu1 + dir_emb[H + f1], 0.f);

    // outer LN over H=128 per direction (full-wave reduction)
    float sd = a_d0 + a_d1, sd2 = a_d0 * a_d0 + a_d1 * a_d1;
    float su = a_u0 + a_u1, su2 = a_u0 * a_u0 + a_u1 * a_u1;
    #pragma unroll
    for (int m = 1; m <= 32; m <<= 1) {
        sd += __shfl_xor(sd, m);  sd2 += __shfl_xor(sd2, m);
        su += __shfl_xor(su, m);  su2 += __shfl_xor(su2, m);
    }
    float md = sd * (1.f / 128.f), vd = sd2 * (1.f / 128.f) - md * md;
    float mu = su * (1.f / 128.f), vu = su2 * (1.f / 128.f) - mu * mu;
    float rsd = rsqrtf(vd + 1e-5f), rsu = rsqrtf(vu + 1e-5f);

    aggd[rowb + f0] = (a_d0 - md) * rsd * ln1g[f0] + ln1b[f0];
    aggd[rowb + f1] = (a_d1 - md) * rsd * ln1g[f1] + ln1b[f1];
    aggu[rowb + f0] = (a_u0 - mu) * rsu * ln2g[f0] + ln2b[f0];
    aggu[rowb + f1] = (a_u1 - mu) * rsu * ln2g[f1] + ln2b[f1];
}

// ---------------------------------------------------------------------------
// K4: out = [hD | hU] @ cw + cb.  Whole cw (128 KiB) in LDS, 16 nodes/block.
// thread t -> node (t>>4), feature group (t&15); 8 outputs/thread (stride 16).
// ---------------------------------------------------------------------------
#define K4_NODES 16
__global__ __launch_bounds__(256) void combine_kernel(
    const float* __restrict__ hD, const float* __restrict__ hU,
    const float* __restrict__ cw, const float* __restrict__ cb,
    float* __restrict__ out)
{
    __shared__ float cw_lds[2 * H * H];        // 32768 f32 = 128 KiB
    __shared__ float cat_lds[K4_NODES][260];   // pad 256->260 breaks bank collide

    // cooperative cw load: 256 threads x 32 float4
    for (int i = threadIdx.x * 4; i < 2 * H * H; i += 256 * 4) {
        *(float4*)&cw_lds[i] = *(const float4*)&cw[i];
    }

    int node0 = blockIdx.x * K4_NODES;          // grid = 3125, exact
    int nn = threadIdx.x >> 4;
    int part = threadIdx.x & 15;                // 16 floats per thread
    {
        const float* srcD = hD + (size_t)(node0 + nn) * H;
        const float* srcU = hU + (size_t)(node0 + nn) * H;
        int base = part * 16;
        float* dstrow = cat_lds[nn];
        #pragma unroll
        for (int q = 0; q < 4; ++q) {
            int off = base + q * 4;
            float4 v = (off < H) ? *(const float4*)&srcD[off]
                                 : *(const float4*)&srcU[off - H];
            *(float4*)&dstrow[off] = v;
        }
    }
    __syncthreads();

    int fg = threadIdx.x & 15;
    int nd = threadIdx.x >> 4;
    float acc[8];
    #pragma unroll
    for (int u = 0; u < 8; ++u) acc[u] = cb[fg + 16 * u];

    const float* crow = cat_lds[nd];
    for (int k = 0; k < 2 * H; ++k) {
        float c = crow[k];
        const float* wrow = &cw_lds[k * H];
        #pragma unroll
        for (int u = 0; u < 8; ++u) acc[u] += c * wrow[fg + 16 * u];
    }

    float* orow = out + (size_t)(node0 + nd) * H;
    #pragma unroll
    for (int u = 0; u < 8; ++u) orow[fg + 16 * u] = acc[u];
}

// ---------------------------------------------------------------------------
extern "C" void kernel_launch(void* const* d_in, const int* in_sizes, int n_in,
                              void* d_out, int out_size, void* d_ws, size_t ws_size,
                              hipStream_t stream) {
    const float* x     = (const float*)d_in[0];
    const int*   ei    = (const int*)d_in[1];
    const float* eps_d = (const float*)d_in[2];
    const float* dw1   = (const float*)d_in[3];
    const float* dg1   = (const float*)d_in[4];
    const float* db1   = (const float*)d_in[5];
    const float* dw2   = (const float*)d_in[6];
    const float* eps_u = (const float*)d_in[7];
    const float* uw1   = (const float*)d_in[8];
    const float* ug1   = (const float*)d_in[9];
    const float* ub1   = (const float*)d_in[10];
    const float* uw2   = (const float*)d_in[11];
    const float* ln1g  = (const float*)d_in[12];
    const float* ln1b  = (const float*)d_in[13];
    const float* ln2g  = (const float*)d_in[14];
    const float* ln2b  = (const float*)d_in[15];
    const float* dire  = (const float*)d_in[16];
    const float* cw    = (const float*)d_in[17];
    const float* cb    = (const float*)d_in[18];

    float* aggd = (float*)d_ws;
    float* aggu = aggd + (size_t)N_NODES * H;

    hipMemsetAsync(d_ws, 0, (size_t)2 * N_NODES * H * sizeof(float), stream);

    {
        long long total = (long long)N_EDGES * 128;
        int blocks = (int)(total / 256);        // 312500, exact
        scatter_kernel<<<blocks, 256, 0, stream>>>(x, ei, aggd, aggu);
    }

    node_kernel<<<N_NODES / 4, 256, 0, stream>>>(
        x, aggd, aggu, eps_d, eps_u,
        dw1, dg1, db1, dw2, uw1, ug1, ub1, uw2,
        ln1g, ln1b, ln2g, ln2b, dire);

    combine_kernel<<<N_NODES / K4_NODES, 256, 0, stream>>>(
        aggd, aggu, cw, cb, (float*)d_out);
}

// Round 2
// 563.152 us; speedup vs baseline: 1.4356x; 1.4356x over previous
//
#include <hip/hip_runtime.h>

#define N_NODES 50000
#define N_EDGES 625000
#define H 128
#define B 32
#define TOTAL_DEG (2 * N_EDGES)

// d_ws layout (ints):
//   deg[100000] | offs[100000] | cursor[100000] | bsums[128] | bucket[1250000]
// then floats: hD[50000*128] | hU[50000*128]

// ---------------------------------------------------------------------------
// K1: count degrees.  deg[0..N) = in-degree (dst), deg[N..2N) = out-degree (src)
// ---------------------------------------------------------------------------
__global__ __launch_bounds__(256) void count_kernel(
    const int* __restrict__ ei, int* __restrict__ deg)
{
    int e = blockIdx.x * 256 + threadIdx.x;
    if (e >= N_EDGES) return;
    int s = ei[e];
    int d = ei[N_EDGES + e];
    atomicAdd(&deg[d], 1);
    atomicAdd(&deg[N_NODES + s], 1);
}

// ---------------------------------------------------------------------------
// Scan: exclusive prefix sum of deg[0..100000) into offs, hierarchical.
// scan_a: 98 blocks x 1024 elems (256 thr x 4), local excl scan + block sums
// ---------------------------------------------------------------------------
__global__ __launch_bounds__(256) void scan_a(
    const int* __restrict__ deg, int* __restrict__ offs, int* __restrict__ bsums)
{
    __shared__ int lds[256];
    int tid = threadIdx.x;
    int base = blockIdx.x * 1024 + tid * 4;
    int v[4];
    int tsum = 0;
    #pragma unroll
    for (int q = 0; q < 4; ++q) {
        v[q] = (base + q < 2 * N_NODES) ? deg[base + q] : 0;
        tsum += v[q];
    }
    lds[tid] = tsum;
    __syncthreads();
    #pragma unroll
    for (int off = 1; off < 256; off <<= 1) {
        int t = (tid >= off) ? lds[tid - off] : 0;
        __syncthreads();
        lds[tid] += t;
        __syncthreads();
    }
    int excl = lds[tid] - tsum;
    if (tid == 255) bsums[blockIdx.x] = lds[tid];
    int run = excl;
    #pragma unroll
    for (int q = 0; q < 4; ++q) {
        if (base + q < 2 * N_NODES) offs[base + q] = run;
        run += v[q];
    }
}

__global__ __launch_bounds__(128) void scan_b(int* __restrict__ bsums)
{
    __shared__ int lds[128];
    int tid = threadIdx.x;
    int v = (tid < 98) ? bsums[tid] : 0;
    lds[tid] = v;
    __syncthreads();
    #pragma unroll
    for (int off = 1; off < 128; off <<= 1) {
        int t = (tid >= off) ? lds[tid - off] : 0;
        __syncthreads();
        lds[tid] += t;
        __syncthreads();
    }
    if (tid < 98) bsums[tid] = lds[tid] - v;   // exclusive
}

__global__ __launch_bounds__(256) void scan_c(
    int* __restrict__ offs, int* __restrict__ cursor, const int* __restrict__ bsums)
{
    int add = bsums[blockIdx.x];
    int base = blockIdx.x * 1024 + threadIdx.x * 4;
    #pragma unroll
    for (int q = 0; q < 4; ++q) {
        int i = base + q;
        if (i < 2 * N_NODES) {
            int o = offs[i] + add;
            offs[i] = o;
            cursor[i] = o;
        }
    }
}

// ---------------------------------------------------------------------------
// K2: fill buckets.  bucket[p] = neighbor id (src for down region, dst for up)
// ---------------------------------------------------------------------------
__global__ __launch_bounds__(256) void fill_kernel(
    const int* __restrict__ ei, int* __restrict__ cursor, int* __restrict__ bucket)
{
    int e = blockIdx.x * 256 + threadIdx.x;
    if (e >= N_EDGES) return;
    int s = ei[e];
    int d = ei[N_EDGES + e];
    int p = atomicAdd(&cursor[d], 1);
    bucket[p] = s;
    int q = atomicAdd(&cursor[N_NODES + s], 1);
    bucket[q] = d;
}

// ---------------------------------------------------------------------------
// K3: fused gather + GIN MLP + outer LN.  One wave per node, 4 nodes/block.
// Lane owns features (2*lane, 2*lane+1) -> one float2 per lane = full 512B row.
// ---------------------------------------------------------------------------
__global__ __launch_bounds__(256) void node_kernel(
    const float* __restrict__ x,
    const int* __restrict__ offs,
    const int* __restrict__ bucket,
    float* __restrict__ hD,
    float* __restrict__ hU,
    const float* __restrict__ eps_d_p,
    const float* __restrict__ eps_u_p,
    const float* __restrict__ dw1, const float* __restrict__ dg1,
    const float* __restrict__ db1, const float* __restrict__ dw2,
    const float* __restrict__ uw1, const float* __restrict__ ug1,
    const float* __restrict__ ub1, const float* __restrict__ uw2,
    const float* __restrict__ ln1g, const float* __restrict__ ln1b,
    const float* __restrict__ ln2g, const float* __restrict__ ln2b,
    const float* __restrict__ dir_emb)
{
    __shared__ float hd_lds[4][128];
    __shared__ float hu_lds[4][128];
    __shared__ float r_lds[4][64];

    int w = threadIdx.x >> 6;
    int lane = threadIdx.x & 63;
    int node = blockIdx.x * 4 + w;          // grid = 12500, exact

    // ---- gather down (in-edges: dst == node, read x[src]) ----
    float2 aggd = {0.f, 0.f};
    {
        int s0 = offs[node];
        int e0 = (node == N_NODES - 1) ? offs[N_NODES] : offs[node + 1];
        for (int basei = s0; basei < e0; basei += 64) {
            int m = e0 - basei; if (m > 64) m = 64;
            int id = (lane < m) ? bucket[basei + lane] : 0;
            int j = 0;
            for (; j + 1 < m; j += 2) {
                int nb0 = __shfl(id, j);
                int nb1 = __shfl(id, j + 1);
                float2 r0 = ((const float2*)(x + (size_t)nb0 * H))[lane];
                float2 r1 = ((const float2*)(x + (size_t)nb1 * H))[lane];
                aggd.x += r0.x + r1.x;
                aggd.y += r0.y + r1.y;
            }
            if (j < m) {
                int nb = __shfl(id, j);
                float2 r0 = ((const float2*)(x + (size_t)nb * H))[lane];
                aggd.x += r0.x; aggd.y += r0.y;
            }
        }
    }
    // ---- gather up (out-edges: src == node, read x[dst]) ----
    float2 aggu = {0.f, 0.f};
    {
        int s0 = offs[N_NODES + node];
        int e0 = (node == N_NODES - 1) ? TOTAL_DEG : offs[N_NODES + node + 1];
        for (int basei = s0; basei < e0; basei += 64) {
            int m = e0 - basei; if (m > 64) m = 64;
            int id = (lane < m) ? bucket[basei + lane] : 0;
            int j = 0;
            for (; j + 1 < m; j += 2) {
                int nb0 = __shfl(id, j);
                int nb1 = __shfl(id, j + 1);
                float2 r0 = ((const float2*)(x + (size_t)nb0 * H))[lane];
                float2 r1 = ((const float2*)(x + (size_t)nb1 * H))[lane];
                aggu.x += r0.x + r1.x;
                aggu.y += r0.y + r1.y;
            }
            if (j < m) {
                int nb = __shfl(id, j);
                float2 r0 = ((const float2*)(x + (size_t)nb * H))[lane];
                aggu.x += r0.x; aggu.y += r0.y;
            }
        }
    }

    float epsd = 1.0f + eps_d_p[0];
    float epsu = 1.0f + eps_u_p[0];
    size_t rowb = (size_t)node * H;
    float2 xv = ((const float2*)(x + rowb))[lane];

    float2 hd = {epsd * xv.x + aggd.x, epsd * xv.y + aggd.y};
    float2 hu = {epsu * xv.x + aggu.x, epsu * xv.y + aggu.y};

    ((float2*)hd_lds[w])[lane] = hd;
    ((float2*)hu_lds[w])[lane] = hu;
    __syncthreads();

    // stage-1 GEMV: lanes 0..31 -> down (col j=lane&31), lanes 32..63 -> up
    int j = lane & 31;
    const float* w1   = (lane < 32) ? dw1 : uw1;
    const float* hrow = (lane < 32) ? hd_lds[w] : hu_lds[w];
    float t = 0.f;
    #pragma unroll 8
    for (int i = 0; i < H; ++i) t += hrow[i] * w1[i * B + j];

    // LN over B=32 (xor masks <=16 keep 32-lane halves independent)
    float s = t, s2 = t * t;
    #pragma unroll
    for (int m = 1; m <= 16; m <<= 1) {
        s  += __shfl_xor(s, m);
        s2 += __shfl_xor(s2, m);
    }
    float mean = s * (1.f / 32.f);
    float var  = s2 * (1.f / 32.f) - mean * mean;
    float rs   = rsqrtf(var + 1e-5f);
    float g  = (lane < 32) ? dg1[j] : ug1[j];
    float bb = (lane < 32) ? db1[j] : ub1[j];
    float r = fmaxf((t - mean) * rs * g + bb, 0.f);
    r_lds[w][lane] = r;
    __syncthreads();

    // stage-2 GEMV: lane computes features (2*lane, 2*lane+1), both directions
    float gd0 = 0.f, gd1 = 0.f, gu0 = 0.f, gu1 = 0.f;
    #pragma unroll 8
    for (int jj = 0; jj < B; ++jj) {
        float rd = r_lds[w][jj];
        float ru = r_lds[w][32 + jj];
        float2 wd = ((const float2*)(dw2 + jj * H))[lane];
        float2 wu = ((const float2*)(uw2 + jj * H))[lane];
        gd0 += rd * wd.x;  gd1 += rd * wd.y;
        gu0 += ru * wu.x;  gu1 += ru * wu.y;
    }
    float2 ded = ((const float2*)dir_emb)[lane];
    float2 deu = ((const float2*)(dir_emb + H))[lane];
    float a_d0 = fmaxf(gd0 + ded.x, 0.f);
    float a_d1 = fmaxf(gd1 + ded.y, 0.f);
    float a_u0 = fmaxf(gu0 + deu.x, 0.f);
    float a_u1 = fmaxf(gu1 + deu.y, 0.f);

    // outer LN over H=128 per direction
    float sd = a_d0 + a_d1, sd2 = a_d0 * a_d0 + a_d1 * a_d1;
    float su = a_u0 + a_u1, su2 = a_u0 * a_u0 + a_u1 * a_u1;
    #pragma unroll
    for (int m = 1; m <= 32; m <<= 1) {
        sd += __shfl_xor(sd, m);  sd2 += __shfl_xor(sd2, m);
        su += __shfl_xor(su, m);  su2 += __shfl_xor(su2, m);
    }
    float md = sd * (1.f / 128.f), vd = sd2 * (1.f / 128.f) - md * md;
    float mu = su * (1.f / 128.f), vu = su2 * (1.f / 128.f) - mu * mu;
    float rsd = rsqrtf(vd + 1e-5f), rsu = rsqrtf(vu + 1e-5f);

    float2 g1v = ((const float2*)ln1g)[lane];
    float2 b1v = ((const float2*)ln1b)[lane];
    float2 g2v = ((const float2*)ln2g)[lane];
    float2 b2v = ((const float2*)ln2b)[lane];

    float2 od = {(a_d0 - md) * rsd * g1v.x + b1v.x,
                 (a_d1 - md) * rsd * g1v.y + b1v.y};
    float2 ou = {(a_u0 - mu) * rsu * g2v.x + b2v.x,
                 (a_u1 - mu) * rsu * g2v.y + b2v.y};
    ((float2*)(hD + rowb))[lane] = od;
    ((float2*)(hU + rowb))[lane] = ou;
}

// ---------------------------------------------------------------------------
// K4: out = [hD | hU] @ cw + cb.  Whole cw (128 KiB) in LDS, 16 nodes/block.
// ---------------------------------------------------------------------------
#define K4_NODES 16
__global__ __launch_bounds__(256) void combine_kernel(
    const float* __restrict__ hD, const float* __restrict__ hU,
    const float* __restrict__ cw, const float* __restrict__ cb,
    float* __restrict__ out)
{
    __shared__ float cw_lds[2 * H * H];        // 128 KiB
    __shared__ float cat_lds[K4_NODES][260];

    for (int i = threadIdx.x * 4; i < 2 * H * H; i += 256 * 4) {
        *(float4*)&cw_lds[i] = *(const float4*)&cw[i];
    }

    int node0 = blockIdx.x * K4_NODES;          // grid = 3125, exact
    int nn = threadIdx.x >> 4;
    int part = threadIdx.x & 15;
    {
        const float* srcD = hD + (size_t)(node0 + nn) * H;
        const float* srcU = hU + (size_t)(node0 + nn) * H;
        int base = part * 16;
        float* dstrow = cat_lds[nn];
        #pragma unroll
        for (int q = 0; q < 4; ++q) {
            int off = base + q * 4;
            float4 v = (off < H) ? *(const float4*)&srcD[off]
                                 : *(const float4*)&srcU[off - H];
            *(float4*)&dstrow[off] = v;
        }
    }
    __syncthreads();

    int fg = threadIdx.x & 15;
    int nd = threadIdx.x >> 4;
    float acc[8];
    #pragma unroll
    for (int u = 0; u < 8; ++u) acc[u] = cb[fg + 16 * u];

    const float* crow = cat_lds[nd];
    for (int k = 0; k < 2 * H; ++k) {
        float c = crow[k];
        const float* wrow = &cw_lds[k * H];
        #pragma unroll
        for (int u = 0; u < 8; ++u) acc[u] += c * wrow[fg + 16 * u];
    }

    float* orow = out + (size_t)(node0 + nd) * H;
    #pragma unroll
    for (int u = 0; u < 8; ++u) orow[fg + 16 * u] = acc[u];
}

// ---------------------------------------------------------------------------
extern "C" void kernel_launch(void* const* d_in, const int* in_sizes, int n_in,
                              void* d_out, int out_size, void* d_ws, size_t ws_size,
                              hipStream_t stream) {
    const float* x     = (const float*)d_in[0];
    const int*   ei    = (const int*)d_in[1];
    const float* eps_d = (const float*)d_in[2];
    const float* dw1   = (const float*)d_in[3];
    const float* dg1   = (const float*)d_in[4];
    const float* db1   = (const float*)d_in[5];
    const float* dw2   = (const float*)d_in[6];
    const float* eps_u = (const float*)d_in[7];
    const float* uw1   = (const float*)d_in[8];
    const float* ug1   = (const float*)d_in[9];
    const float* ub1   = (const float*)d_in[10];
    const float* uw2   = (const float*)d_in[11];
    const float* ln1g  = (const float*)d_in[12];
    const float* ln1b  = (const float*)d_in[13];
    const float* ln2g  = (const float*)d_in[14];
    const float* ln2b  = (const float*)d_in[15];
    const float* dire  = (const float*)d_in[16];
    const float* cw    = (const float*)d_in[17];
    const float* cb    = (const float*)d_in[18];

    int* deg    = (int*)d_ws;
    int* offs   = deg + 2 * N_NODES;
    int* cursor = offs + 2 * N_NODES;
    int* bsums  = cursor + 2 * N_NODES;
    int* bucket = bsums + 128;
    float* hD   = (float*)(bucket + TOTAL_DEG);
    float* hU   = hD + (size_t)N_NODES * H;

    hipMemsetAsync(deg, 0, 2 * N_NODES * sizeof(int), stream);

    int eblocks = (N_EDGES + 255) / 256;
    count_kernel<<<eblocks, 256, 0, stream>>>(ei, deg);

    scan_a<<<98, 256, 0, stream>>>(deg, offs, bsums);
    scan_b<<<1, 128, 0, stream>>>(bsums);
    scan_c<<<98, 256, 0, stream>>>(offs, cursor, bsums);

    fill_kernel<<<eblocks, 256, 0, stream>>>(ei, cursor, bucket);

    node_kernel<<<N_NODES / 4, 256, 0, stream>>>(
        x, offs, bucket, hD, hU, eps_d, eps_u,
        dw1, dg1, db1, dw2, uw1, ug1, ub1, uw2,
        ln1g, ln1b, ln2g, ln2b, dire);

    combine_kernel<<<N_NODES / K4_NODES, 256, 0, stream>>>(
        hD, hU, cw, cb, (float*)d_out);
}

// Round 3
// 398.527 us; speedup vs baseline: 2.0286x; 1.4131x over previous
//
#include <hip/hip_runtime.h>

#define N_NODES 50000
#define N_EDGES 625000
#define H 128
#define B 32
#define TOTAL_DEG (2 * N_EDGES)

using bf16x8 = __attribute__((ext_vector_type(8))) short;
using f32x4  = __attribute__((ext_vector_type(4))) float;

static __device__ __forceinline__ unsigned short f2bf(float f) {
    unsigned u = __float_as_uint(f);
    unsigned r = (u + 0x7fff + ((u >> 16) & 1)) >> 16;   // RNE
    return (unsigned short)r;
}

// ---------------------------------------------------------------------------
// K1: count degrees.  deg[0..N) = in-degree (dst), deg[N..2N) = out-degree (src)
// ---------------------------------------------------------------------------
__global__ __launch_bounds__(256) void count_kernel(
    const int* __restrict__ ei, int* __restrict__ deg)
{
    int e = blockIdx.x * 256 + threadIdx.x;
    if (e >= N_EDGES) return;
    int s = ei[e];
    int d = ei[N_EDGES + e];
    atomicAdd(&deg[d], 1);
    atomicAdd(&deg[N_NODES + s], 1);
}

// ---------------------------------------------------------------------------
// Hierarchical exclusive scan of deg[0..100000) -> offs (and cursor copy)
// ---------------------------------------------------------------------------
__global__ __launch_bounds__(256) void scan_a(
    const int* __restrict__ deg, int* __restrict__ offs, int* __restrict__ bsums)
{
    __shared__ int lds[256];
    int tid = threadIdx.x;
    int base = blockIdx.x * 1024 + tid * 4;
    int v[4];
    int tsum = 0;
    #pragma unroll
    for (int q = 0; q < 4; ++q) {
        v[q] = (base + q < 2 * N_NODES) ? deg[base + q] : 0;
        tsum += v[q];
    }
    lds[tid] = tsum;
    __syncthreads();
    #pragma unroll
    for (int off = 1; off < 256; off <<= 1) {
        int t = (tid >= off) ? lds[tid - off] : 0;
        __syncthreads();
        lds[tid] += t;
        __syncthreads();
    }
    int excl = lds[tid] - tsum;
    if (tid == 255) bsums[blockIdx.x] = lds[tid];
    int run = excl;
    #pragma unroll
    for (int q = 0; q < 4; ++q) {
        if (base + q < 2 * N_NODES) offs[base + q] = run;
        run += v[q];
    }
}

__global__ __launch_bounds__(128) void scan_b(int* __restrict__ bsums)
{
    __shared__ int lds[128];
    int tid = threadIdx.x;
    int v = (tid < 98) ? bsums[tid] : 0;
    lds[tid] = v;
    __syncthreads();
    #pragma unroll
    for (int off = 1; off < 128; off <<= 1) {
        int t = (tid >= off) ? lds[tid - off] : 0;
        __syncthreads();
        lds[tid] += t;
        __syncthreads();
    }
    if (tid < 98) bsums[tid] = lds[tid] - v;   // exclusive
}

__global__ __launch_bounds__(256) void scan_c(
    int* __restrict__ offs, int* __restrict__ cursor, const int* __restrict__ bsums)
{
    int add = bsums[blockIdx.x];
    int base = blockIdx.x * 1024 + threadIdx.x * 4;
    #pragma unroll
    for (int q = 0; q < 4; ++q) {
        int i = base + q;
        if (i < 2 * N_NODES) {
            int o = offs[i] + add;
            offs[i] = o;
            cursor[i] = o;
        }
    }
}

// ---------------------------------------------------------------------------
// K2: fill buckets.
// ---------------------------------------------------------------------------
__global__ __launch_bounds__(256) void fill_kernel(
    const int* __restrict__ ei, int* __restrict__ cursor, int* __restrict__ bucket)
{
    int e = blockIdx.x * 256 + threadIdx.x;
    if (e >= N_EDGES) return;
    int s = ei[e];
    int d = ei[N_EDGES + e];
    int p = atomicAdd(&cursor[d], 1);
    bucket[p] = s;
    int q = atomicAdd(&cursor[N_NODES + s], 1);
    bucket[q] = d;
}

// ---------------------------------------------------------------------------
// K3: fused gather + GIN MLP + outer LN.  One wave per (node, direction);
// 4 waves/block -> 2 nodes/block.  No __syncthreads (waves self-contained).
// Lane owns features (2*lane, 2*lane+1).  Output: hcat bf16 [node][256].
// ---------------------------------------------------------------------------
__global__ __launch_bounds__(256) void node_kernel(
    const float* __restrict__ x,
    const int* __restrict__ offs,
    const int* __restrict__ bucket,
    unsigned short* __restrict__ hcat,
    const float* __restrict__ eps_d_p,
    const float* __restrict__ eps_u_p,
    const float* __restrict__ dw1, const float* __restrict__ dg1,
    const float* __restrict__ db1, const float* __restrict__ dw2,
    const float* __restrict__ uw1, const float* __restrict__ ug1,
    const float* __restrict__ ub1, const float* __restrict__ uw2,
    const float* __restrict__ ln1g, const float* __restrict__ ln1b,
    const float* __restrict__ ln2g, const float* __restrict__ ln2b,
    const float* __restrict__ dir_emb)
{
    __shared__ float h_lds[4][128];

    int w    = threadIdx.x >> 6;
    int lane = threadIdx.x & 63;
    int node = blockIdx.x * 2 + (w >> 1);   // grid = 25000, exact
    int dir  = w & 1;                       // 0 = down, 1 = up

    int ridx = dir * N_NODES + node;
    int s0 = offs[ridx];
    int e0 = (ridx == 2 * N_NODES - 1) ? TOTAL_DEG : offs[ridx + 1];

    float2 agg = {0.f, 0.f};
    for (int base = s0; base < e0; base += 64) {
        int m = e0 - base; if (m > 64) m = 64;
        int id = (lane < m) ? bucket[base + lane] : 0;
        int j = 0;
        for (; j + 8 <= m; j += 8) {
            float2 r[8];
            #pragma unroll
            for (int q = 0; q < 8; ++q) {
                int nb = __shfl(id, j + q);
                r[q] = ((const float2*)(x + (size_t)nb * H))[lane];
            }
            #pragma unroll
            for (int q = 0; q < 8; ++q) { agg.x += r[q].x; agg.y += r[q].y; }
        }
        if (j + 4 <= m) {
            float2 r[4];
            #pragma unroll
            for (int q = 0; q < 4; ++q) {
                int nb = __shfl(id, j + q);
                r[q] = ((const float2*)(x + (size_t)nb * H))[lane];
            }
            #pragma unroll
            for (int q = 0; q < 4; ++q) { agg.x += r[q].x; agg.y += r[q].y; }
            j += 4;
        }
        if (j + 2 <= m) {
            float2 r[2];
            #pragma unroll
            for (int q = 0; q < 2; ++q) {
                int nb = __shfl(id, j + q);
                r[q] = ((const float2*)(x + (size_t)nb * H))[lane];
            }
            agg.x += r[0].x + r[1].x;
            agg.y += r[0].y + r[1].y;
            j += 2;
        }
        if (j < m) {
            int nb = __shfl(id, j);
            float2 r0 = ((const float2*)(x + (size_t)nb * H))[lane];
            agg.x += r0.x; agg.y += r0.y;
        }
    }

    float eps = 1.0f + (dir ? eps_u_p[0] : eps_d_p[0]);
    size_t rowb = (size_t)node * H;
    float2 xv = ((const float2*)(x + rowb))[lane];
    float2 h = {eps * xv.x + agg.x, eps * xv.y + agg.y};
    ((float2*)h_lds[w])[lane] = h;   // same wave produces & consumes: no barrier

    // stage-1 GEMV: col j1 = lane&31; halves split H then combine
    const float* w1 = dir ? uw1 : dw1;
    int j1 = lane & 31;
    int half = lane >> 5;
    const float* hrow = h_lds[w];
    float t = 0.f;
    #pragma unroll 8
    for (int i = 0; i < 64; ++i) {
        int ii = half * 64 + i;
        t += hrow[ii] * w1[ii * B + j1];
    }
    t += __shfl_xor(t, 32);

    // LN over B=32 (masks <=16: the two 32-lane halves reduce identically)
    float s = t, s2 = t * t;
    #pragma unroll
    for (int m = 1; m <= 16; m <<= 1) {
        s  += __shfl_xor(s, m);
        s2 += __shfl_xor(s2, m);
    }
    float mean = s * (1.f / 32.f);
    float var  = s2 * (1.f / 32.f) - mean * mean;
    float rs   = rsqrtf(var + 1e-5f);
    float g  = (dir ? ug1 : dg1)[j1];
    float bb = (dir ? ub1 : db1)[j1];
    float r = fmaxf((t - mean) * rs * g + bb, 0.f);

    // stage-2 GEMV: lane computes feats (2*lane, 2*lane+1)
    const float* w2 = dir ? uw2 : dw2;
    float g0 = 0.f, g1 = 0.f;
    #pragma unroll 8
    for (int jj = 0; jj < 32; ++jj) {
        float rv = __shfl(r, jj);
        float2 wv = ((const float2*)(w2 + jj * H))[lane];
        g0 += rv * wv.x;
        g1 += rv * wv.y;
    }
    float2 de = ((const float2*)(dir_emb + dir * H))[lane];
    float a0 = fmaxf(g0 + de.x, 0.f);
    float a1 = fmaxf(g1 + de.y, 0.f);

    // outer LN over H=128
    float sd = a0 + a1, sd2 = a0 * a0 + a1 * a1;
    #pragma unroll
    for (int m = 1; m <= 32; m <<= 1) {
        sd  += __shfl_xor(sd, m);
        sd2 += __shfl_xor(sd2, m);
    }
    float md = sd * (1.f / 128.f);
    float vd = sd2 * (1.f / 128.f) - md * md;
    float rsd = rsqrtf(vd + 1e-5f);
    const float* lg = dir ? ln2g : ln1g;
    const float* lb = dir ? ln2b : ln1b;
    float2 gv = ((const float2*)lg)[lane];
    float2 bv = ((const float2*)lb)[lane];
    float o0 = (a0 - md) * rsd * gv.x + bv.x;
    float o1 = (a1 - md) * rsd * gv.y + bv.y;

    unsigned packed = ((unsigned)f2bf(o1) << 16) | (unsigned)f2bf(o0);
    ((unsigned*)(hcat + (size_t)node * 256 + dir * 128))[lane] = packed;
}

// ---------------------------------------------------------------------------
// cw [256][128] f32 -> cwbT [128 cols][256 k] bf16
// ---------------------------------------------------------------------------
__global__ __launch_bounds__(256) void convert_cw(
    const float* __restrict__ cw, unsigned short* __restrict__ cwbT)
{
    int i = blockIdx.x * 256 + threadIdx.x;   // 32768, grid 128
    int k = i >> 7;
    int c = i & 127;
    cwbT[(size_t)c * 256 + k] = f2bf(cw[i]);
}

// ---------------------------------------------------------------------------
// K4: out = hcat(bf16) @ W(bf16) + cb via MFMA 16x16x32.
// Wave computes 16 nodes x 128 cols (8 col-tiles, 8 k-steps). No LDS.
// A frag: row = lane&15, k-chunk = (lane>>4)*8 (contig in hcat row).
// B frag: col = lane&15, k-chunk = (lane>>4)*8 (contig in cwbT col row).
// D: col = lane&15, node = (lane>>4)*4 + reg.
// ---------------------------------------------------------------------------
__global__ __launch_bounds__(256) void combine_mfma(
    const unsigned short* __restrict__ hcat,
    const unsigned short* __restrict__ cwbT,
    const float* __restrict__ cb,
    float* __restrict__ out)
{
    int wv   = threadIdx.x >> 6;
    int lane = threadIdx.x & 63;
    int mbase = (blockIdx.x * 4 + wv) * 16;
    if (mbase >= N_NODES) return;

    int row = lane & 15;
    int kc  = (lane >> 4) * 8;

    int nodeA = mbase + row;
    if (nodeA >= N_NODES) nodeA = N_NODES - 1;   // clamp for tail wave

    f32x4 acc[8];
    #pragma unroll
    for (int c = 0; c < 8; ++c) acc[c] = (f32x4){0.f, 0.f, 0.f, 0.f};

    const unsigned short* arow = hcat + (size_t)nodeA * 256;
    #pragma unroll
    for (int ks = 0; ks < 8; ++ks) {
        bf16x8 a = *(const bf16x8*)(arow + ks * 32 + kc);
        #pragma unroll
        for (int c = 0; c < 8; ++c) {
            bf16x8 b = *(const bf16x8*)(cwbT + (size_t)(c * 16 + row) * 256 + ks * 32 + kc);
            acc[c] = __builtin_amdgcn_mfma_f32_16x16x32_bf16(a, b, acc[c], 0, 0, 0);
        }
    }

    int dnode = mbase + (lane >> 4) * 4;
    #pragma unroll
    for (int c = 0; c < 8; ++c) {
        int feat = c * 16 + (lane & 15);
        float bias = cb[feat];
        #pragma unroll
        for (int rg = 0; rg < 4; ++rg) {
            int nd = dnode + rg;
            if (nd < N_NODES)
                out[(size_t)nd * 128 + feat] = acc[c][rg] + bias;
        }
    }
}

// ---------------------------------------------------------------------------
extern "C" void kernel_launch(void* const* d_in, const int* in_sizes, int n_in,
                              void* d_out, int out_size, void* d_ws, size_t ws_size,
                              hipStream_t stream) {
    const float* x     = (const float*)d_in[0];
    const int*   ei    = (const int*)d_in[1];
    const float* eps_d = (const float*)d_in[2];
    const float* dw1   = (const float*)d_in[3];
    const float* dg1   = (const float*)d_in[4];
    const float* db1   = (const float*)d_in[5];
    const float* dw2   = (const float*)d_in[6];
    const float* eps_u = (const float*)d_in[7];
    const float* uw1   = (const float*)d_in[8];
    const float* ug1   = (const float*)d_in[9];
    const float* ub1   = (const float*)d_in[10];
    const float* uw2   = (const float*)d_in[11];
    const float* ln1g  = (const float*)d_in[12];
    const float* ln1b  = (const float*)d_in[13];
    const float* ln2g  = (const float*)d_in[14];
    const float* ln2b  = (const float*)d_in[15];
    const float* dire  = (const float*)d_in[16];
    const float* cw    = (const float*)d_in[17];
    const float* cb    = (const float*)d_in[18];

    int* deg    = (int*)d_ws;
    int* offs   = deg + 2 * N_NODES;
    int* cursor = offs + 2 * N_NODES;
    int* bsums  = cursor + 2 * N_NODES;
    int* bucket = bsums + 128;                       // 1,250,000 ints
    unsigned short* hcat = (unsigned short*)(bucket + TOTAL_DEG);   // [N][256] bf16
    unsigned short* cwbT = hcat + (size_t)N_NODES * 256;            // [128][256] bf16

    hipMemsetAsync(deg, 0, 2 * N_NODES * sizeof(int), stream);

    int eblocks = (N_EDGES + 255) / 256;
    count_kernel<<<eblocks, 256, 0, stream>>>(ei, deg);

    scan_a<<<98, 256, 0, stream>>>(deg, offs, bsums);
    scan_b<<<1, 128, 0, stream>>>(bsums);
    scan_c<<<98, 256, 0, stream>>>(offs, cursor, bsums);

    fill_kernel<<<eblocks, 256, 0, stream>>>(ei, cursor, bucket);

    convert_cw<<<128, 256, 0, stream>>>(cw, cwbT);

    node_kernel<<<N_NODES / 2, 256, 0, stream>>>(
        x, offs, bucket, hcat, eps_d, eps_u,
        dw1, dg1, db1, dw2, uw1, ug1, ub1, uw2,
        ln1g, ln1b, ln2g, ln2b, dire);

    {
        int mblocks = (N_NODES + 63) / 64;   // 782
        combine_mfma<<<mblocks, 256, 0, stream>>>(hcat, cwbT, cb, (float*)d_out);
    }
}

// Round 4
// 349.384 us; speedup vs baseline: 2.3140x; 1.1407x over previous
//
#include <hip/hip_runtime.h>

#define N_NODES 50000
#define NPAD 50048            // 64*782, padded rows per direction
#define N_EDGES 625000
#define H 128
#define B 32
#define TOTAL_DEG (2 * N_EDGES)
#define PSTRIDE 40            // ushorts per LDS row (80B, 16B-aligned, bank-spread)

using bf16x8  = __attribute__((ext_vector_type(8))) short;
using f32x4   = __attribute__((ext_vector_type(4))) float;
using u16x4   = __attribute__((ext_vector_type(4))) unsigned short;

static __device__ __forceinline__ unsigned short f2bf(float f) {
    unsigned u = __float_as_uint(f);
    unsigned r = (u + 0x7fff + ((u >> 16) & 1)) >> 16;   // RNE
    return (unsigned short)r;
}
static __device__ __forceinline__ float bf2f(unsigned short h) {
    return __uint_as_float(((unsigned)h) << 16);
}

// ---------------------------------------------------------------------------
// count degrees
// ---------------------------------------------------------------------------
__global__ __launch_bounds__(256) void count_kernel(
    const int* __restrict__ ei, int* __restrict__ deg)
{
    int e = blockIdx.x * 256 + threadIdx.x;
    if (e >= N_EDGES) return;
    int s = ei[e];
    int d = ei[N_EDGES + e];
    atomicAdd(&deg[d], 1);
    atomicAdd(&deg[N_NODES + s], 1);
}

// ---------------------------------------------------------------------------
// hierarchical exclusive scan (100000 elems)
// ---------------------------------------------------------------------------
__global__ __launch_bounds__(256) void scan_a(
    const int* __restrict__ deg, int* __restrict__ offs, int* __restrict__ bsums)
{
    __shared__ int lds[256];
    int tid = threadIdx.x;
    int base = blockIdx.x * 1024 + tid * 4;
    int v[4]; int tsum = 0;
    #pragma unroll
    for (int q = 0; q < 4; ++q) {
        v[q] = (base + q < 2 * N_NODES) ? deg[base + q] : 0;
        tsum += v[q];
    }
    lds[tid] = tsum;
    __syncthreads();
    #pragma unroll
    for (int off = 1; off < 256; off <<= 1) {
        int t = (tid >= off) ? lds[tid - off] : 0;
        __syncthreads();
        lds[tid] += t;
        __syncthreads();
    }
    int excl = lds[tid] - tsum;
    if (tid == 255) bsums[blockIdx.x] = lds[tid];
    int run = excl;
    #pragma unroll
    for (int q = 0; q < 4; ++q) {
        if (base + q < 2 * N_NODES) offs[base + q] = run;
        run += v[q];
    }
}

__global__ __launch_bounds__(128) void scan_b(int* __restrict__ bsums)
{
    __shared__ int lds[128];
    int tid = threadIdx.x;
    int v = (tid < 98) ? bsums[tid] : 0;
    lds[tid] = v;
    __syncthreads();
    #pragma unroll
    for (int off = 1; off < 128; off <<= 1) {
        int t = (tid >= off) ? lds[tid - off] : 0;
        __syncthreads();
        lds[tid] += t;
        __syncthreads();
    }
    if (tid < 98) bsums[tid] = lds[tid] - v;
}

__global__ __launch_bounds__(256) void scan_c(
    int* __restrict__ offs, int* __restrict__ cursor, const int* __restrict__ bsums)
{
    int add = bsums[blockIdx.x];
    int base = blockIdx.x * 1024 + threadIdx.x * 4;
    #pragma unroll
    for (int q = 0; q < 4; ++q) {
        int i = base + q;
        if (i < 2 * N_NODES) {
            int o = offs[i] + add;
            offs[i] = o;
            cursor[i] = o;
        }
    }
}

// ---------------------------------------------------------------------------
// fill CSR buckets
// ---------------------------------------------------------------------------
__global__ __launch_bounds__(256) void fill_kernel(
    const int* __restrict__ ei, int* __restrict__ cursor, int* __restrict__ bucket)
{
    int e = blockIdx.x * 256 + threadIdx.x;
    if (e >= N_EDGES) return;
    int s = ei[e];
    int d = ei[N_EDGES + e];
    int p = atomicAdd(&cursor[d], 1);
    bucket[p] = s;
    int q = atomicAdd(&cursor[N_NODES + s], 1);
    bucket[q] = d;
}

// ---------------------------------------------------------------------------
// x f32 -> xb bf16 (packed pairs)
// ---------------------------------------------------------------------------
__global__ __launch_bounds__(256) void convert_x(
    const float* __restrict__ x, unsigned* __restrict__ xb)
{
    int i = blockIdx.x * 256 + threadIdx.x;     // 3,200,000 exact
    float2 v = ((const float2*)x)[i];
    xb[i] = ((unsigned)f2bf(v.y) << 16) | f2bf(v.x);
}

// ---------------------------------------------------------------------------
// weight transpose + hi/lo bf16 split:  src[K][C] f32 -> hi/lo [C][K] bf16
// ---------------------------------------------------------------------------
__global__ __launch_bounds__(256) void convert_wT(
    const float* __restrict__ src, unsigned short* __restrict__ hi,
    unsigned short* __restrict__ lo, int K, int C)
{
    int i = blockIdx.x * 256 + threadIdx.x;
    if (i >= K * C) return;
    int c = i / K, k = i - c * K;
    float v = src[k * C + c];
    unsigned short h = f2bf(v);
    hi[i] = h;
    lo[i] = f2bf(v - bf2f(h));
}

// ---------------------------------------------------------------------------
// gather: one wave per (node, dir).  bf16 rows, ILP-8, h = (1+eps)x + agg
// written as hi/lo bf16 planes at row dir*NPAD + node.
// ---------------------------------------------------------------------------
__global__ __launch_bounds__(256) void gather_kernel(
    const float* __restrict__ x, const unsigned* __restrict__ xb,
    const int* __restrict__ offs, const int* __restrict__ bucket,
    unsigned* __restrict__ hhi, unsigned* __restrict__ hlo,
    const float* __restrict__ eps_d_p, const float* __restrict__ eps_u_p)
{
    int w = threadIdx.x >> 6, lane = threadIdx.x & 63;
    int gw = blockIdx.x * 4 + w;            // 0..99999, grid 25000
    int node = gw >> 1;
    int dir  = gw & 1;
    int ridx = dir * N_NODES + node;
    int s0 = offs[ridx];
    int e0 = (ridx == 2 * N_NODES - 1) ? TOTAL_DEG : offs[ridx + 1];

    float a0 = 0.f, a1 = 0.f;
    for (int base = s0; base < e0; base += 64) {
        int m = e0 - base; if (m > 64) m = 64;
        int id = (lane < m) ? bucket[base + lane] : 0;
        int lim = m - 1;
        for (int j = 0; j < m; j += 8) {
            unsigned r[8];
            #pragma unroll
            for (int q = 0; q < 8; ++q) {
                int idx = j + q; if (idx > lim) idx = lim;   // clamp keeps 8 loads in flight
                int nb = __shfl(id, idx);
                r[q] = xb[nb * 64 + lane];
            }
            #pragma unroll
            for (int q = 0; q < 8; ++q) {
                if (j + q > lim) r[q] = 0;                   // zero duplicates
                a0 += __uint_as_float(r[q] << 16);
                a1 += __uint_as_float(r[q] & 0xffff0000u);
            }
        }
    }

    float eps = 1.f + (dir ? eps_u_p[0] : eps_d_p[0]);
    float2 xv = ((const float2*)(x + (size_t)node * H))[lane];   // self term in f32
    float h0 = eps * xv.x + a0;
    float h1 = eps * xv.y + a1;
    unsigned short h0h = f2bf(h0), h1h = f2bf(h1);
    int orow = dir * NPAD + node;
    hhi[orow * 64 + lane] = ((unsigned)h1h << 16) | h0h;
    hlo[orow * 64 + lane] =
        ((unsigned)f2bf(h1 - bf2f(h1h)) << 16) | f2bf(h0 - bf2f(h0h));
}

// ---------------------------------------------------------------------------
// batched MLP: per wave 16 rows of one direction.
// stage1 (swapped operands): D1[j][node] = (w1^T hi/lo) x (h^T hi/lo)
//   -> lane holds row l&15 (node), cols j = t*16 + g*4 + reg  (g = lane>>4)
// LN over 32, ReLU, bf16 hi/lo -> LDS transpose -> stage2 same trick ->
// +dir_emb, ReLU, LN over 128 -> hcat bf16 [node][256] (+dir*128).
// ---------------------------------------------------------------------------
__global__ __launch_bounds__(256) void mlp_kernel(
    const unsigned short* __restrict__ hhi, const unsigned short* __restrict__ hlo,
    const unsigned short* __restrict__ w1bT_hi, const unsigned short* __restrict__ w1bT_lo,
    const unsigned short* __restrict__ w2bT_hi, const unsigned short* __restrict__ w2bT_lo,
    const float* __restrict__ dg1, const float* __restrict__ db1,
    const float* __restrict__ ug1, const float* __restrict__ ub1,
    const float* __restrict__ ln1g, const float* __restrict__ ln1b,
    const float* __restrict__ ln2g, const float* __restrict__ ln2b,
    const float* __restrict__ dir_emb,
    unsigned short* __restrict__ hcat)
{
    __shared__ unsigned short plds[4][2][16 * PSTRIDE];   // per-wave private

    int w = threadIdx.x >> 6, lane = threadIdx.x & 63;
    int l15 = lane & 15, g = lane >> 4;
    int blk = blockIdx.x;                 // 0..1563
    int dir = (blk >= 782) ? 1 : 0;
    int r0 = (blk - dir * 782) * 64 + w * 16;

    const unsigned short* w1h = w1bT_hi + dir * 4096;
    const unsigned short* w1l = w1bT_lo + dir * 4096;
    const unsigned short* w2h = w2bT_hi + dir * 4096;
    const unsigned short* w2l = w2bT_lo + dir * 4096;

    // ---- stage 1: C1 = h @ w1, computed transposed ----
    size_t hbase = ((size_t)(dir * NPAD + r0 + l15)) * H;
    f32x4 acc1[2];
    acc1[0] = (f32x4){0.f,0.f,0.f,0.f};
    acc1[1] = (f32x4){0.f,0.f,0.f,0.f};
    #pragma unroll
    for (int ks = 0; ks < 4; ++ks) {
        int ko = ks * 32 + g * 8;
        bf16x8 bh = *(const bf16x8*)(hhi + hbase + ko);
        bf16x8 bl = *(const bf16x8*)(hlo + hbase + ko);
        #pragma unroll
        for (int t = 0; t < 2; ++t) {
            bf16x8 ah = *(const bf16x8*)(w1h + (t * 16 + l15) * H + ko);
            bf16x8 al = *(const bf16x8*)(w1l + (t * 16 + l15) * H + ko);
            acc1[t] = __builtin_amdgcn_mfma_f32_16x16x32_bf16(ah, bh, acc1[t], 0, 0, 0);
            acc1[t] = __builtin_amdgcn_mfma_f32_16x16x32_bf16(al, bh, acc1[t], 0, 0, 0);
            acc1[t] = __builtin_amdgcn_mfma_f32_16x16x32_bf16(ah, bl, acc1[t], 0, 0, 0);
        }
    }

    // LN over B=32 per row (row = l15; partials across g-groups)
    float s = 0.f, s2 = 0.f;
    #pragma unroll
    for (int t = 0; t < 2; ++t)
        #pragma unroll
        for (int r = 0; r < 4; ++r) { float v = acc1[t][r]; s += v; s2 += v * v; }
    s  += __shfl_xor(s, 16);  s  += __shfl_xor(s, 32);
    s2 += __shfl_xor(s2, 16); s2 += __shfl_xor(s2, 32);
    float mean = s * (1.f / 32.f);
    float var  = s2 * (1.f / 32.f) - mean * mean;
    float rs   = rsqrtf(var + 1e-5f);

    const float* g1p = dir ? ug1 : dg1;
    const float* b1p = dir ? ub1 : db1;
    unsigned short* mh = &plds[w][0][0];
    unsigned short* ml = &plds[w][1][0];
    #pragma unroll
    for (int t = 0; t < 2; ++t) {
        float4 gv = *(const float4*)(g1p + t * 16 + g * 4);
        float4 bv = *(const float4*)(b1p + t * 16 + g * 4);
        float p0 = fmaxf((acc1[t][0] - mean) * rs * gv.x + bv.x, 0.f);
        float p1 = fmaxf((acc1[t][1] - mean) * rs * gv.y + bv.y, 0.f);
        float p2 = fmaxf((acc1[t][2] - mean) * rs * gv.z + bv.z, 0.f);
        float p3 = fmaxf((acc1[t][3] - mean) * rs * gv.w + bv.w, 0.f);
        unsigned short q0 = f2bf(p0), q1 = f2bf(p1), q2 = f2bf(p2), q3 = f2bf(p3);
        u16x4 ph = {q0, q1, q2, q3};
        u16x4 pl = {f2bf(p0 - bf2f(q0)), f2bf(p1 - bf2f(q1)),
                    f2bf(p2 - bf2f(q2)), f2bf(p3 - bf2f(q3))};
        int off = l15 * PSTRIDE + t * 16 + g * 4;
        *(u16x4*)(mh + off) = ph;
        *(u16x4*)(ml + off) = pl;
    }

    // ---- stage 2: C2 = P @ w2, transposed ----
    bf16x8 pbh = *(const bf16x8*)(mh + l15 * PSTRIDE + g * 8);
    bf16x8 pbl = *(const bf16x8*)(ml + l15 * PSTRIDE + g * 8);

    f32x4 acc2[8];
    #pragma unroll
    for (int t = 0; t < 8; ++t) acc2[t] = (f32x4){0.f,0.f,0.f,0.f};
    #pragma unroll
    for (int t = 0; t < 8; ++t) {
        bf16x8 ah = *(const bf16x8*)(w2h + (t * 16 + l15) * 32 + g * 8);
        bf16x8 al = *(const bf16x8*)(w2l + (t * 16 + l15) * 32 + g * 8);
        acc2[t] = __builtin_amdgcn_mfma_f32_16x16x32_bf16(ah, pbh, acc2[t], 0, 0, 0);
        acc2[t] = __builtin_amdgcn_mfma_f32_16x16x32_bf16(al, pbh, acc2[t], 0, 0, 0);
        acc2[t] = __builtin_amdgcn_mfma_f32_16x16x32_bf16(ah, pbl, acc2[t], 0, 0, 0);
    }

    // + dir_emb, relu, LN over 128
    float av[8][4];
    float u = 0.f, u2 = 0.f;
    #pragma unroll
    for (int t = 0; t < 8; ++t) {
        float4 de = *(const float4*)(dir_emb + dir * H + t * 16 + g * 4);
        av[t][0] = fmaxf(acc2[t][0] + de.x, 0.f);
        av[t][1] = fmaxf(acc2[t][1] + de.y, 0.f);
        av[t][2] = fmaxf(acc2[t][2] + de.z, 0.f);
        av[t][3] = fmaxf(acc2[t][3] + de.w, 0.f);
        #pragma unroll
        for (int r = 0; r < 4; ++r) { u += av[t][r]; u2 += av[t][r] * av[t][r]; }
    }
    u  += __shfl_xor(u, 16);  u  += __shfl_xor(u, 32);
    u2 += __shfl_xor(u2, 16); u2 += __shfl_xor(u2, 32);
    float m2  = u * (1.f / 128.f);
    float v2  = u2 * (1.f / 128.f) - m2 * m2;
    float rs2 = rsqrtf(v2 + 1e-5f);

    const float* lgp = dir ? ln2g : ln1g;
    const float* lbp = dir ? ln2b : ln1b;
    bool valid = (r0 + l15) < N_NODES;
    if (valid) {
        unsigned short* orow = hcat + (size_t)(r0 + l15) * 256 + dir * 128;
        #pragma unroll
        for (int t = 0; t < 8; ++t) {
            float4 gv = *(const float4*)(lgp + t * 16 + g * 4);
            float4 bv = *(const float4*)(lbp + t * 16 + g * 4);
            u16x4 o;
            o[0] = f2bf((av[t][0] - m2) * rs2 * gv.x + bv.x);
            o[1] = f2bf((av[t][1] - m2) * rs2 * gv.y + bv.y);
            o[2] = f2bf((av[t][2] - m2) * rs2 * gv.z + bv.z);
            o[3] = f2bf((av[t][3] - m2) * rs2 * gv.w + bv.w);
            *(u16x4*)(orow + t * 16 + g * 4) = o;
        }
    }
}

// ---------------------------------------------------------------------------
// combine: out = hcat @ cw + cb, transposed operands, cw hi/lo split.
// Wave: 16 nodes x 128 cols; lane stores f32x4 (4 consecutive cols).
// ---------------------------------------------------------------------------
__global__ __launch_bounds__(256) void combine_mfma(
    const unsigned short* __restrict__ hcat,
    const unsigned short* __restrict__ cwh, const unsigned short* __restrict__ cwl,
    const float* __restrict__ cb, float* __restrict__ out)
{
    int w = threadIdx.x >> 6, lane = threadIdx.x & 63;
    int l15 = lane & 15, g = lane >> 4;
    int m0 = (blockIdx.x * 4 + w) * 16;          // grid 782 -> up to 50032
    if (m0 >= N_NODES) return;
    int node = m0 + l15; if (node >= N_NODES) node = N_NODES - 1;
    size_t abase = (size_t)node * 256;

    f32x4 acc[8];
    #pragma unroll
    for (int t = 0; t < 8; ++t) acc[t] = (f32x4){0.f,0.f,0.f,0.f};

    #pragma unroll
    for (int ks = 0; ks < 8; ++ks) {
        bf16x8 bfrag = *(const bf16x8*)(hcat + abase + ks * 32 + g * 8);
        #pragma unroll
        for (int t = 0; t < 8; ++t) {
            bf16x8 ah = *(const bf16x8*)(cwh + (t * 16 + l15) * 256 + ks * 32 + g * 8);
            bf16x8 al = *(const bf16x8*)(cwl + (t * 16 + l15) * 256 + ks * 32 + g * 8);
            acc[t] = __builtin_amdgcn_mfma_f32_16x16x32_bf16(ah, bfrag, acc[t], 0, 0, 0);
            acc[t] = __builtin_amdgcn_mfma_f32_16x16x32_bf16(al, bfrag, acc[t], 0, 0, 0);
        }
    }

    if ((m0 + l15) < N_NODES) {
        float* orow = out + (size_t)(m0 + l15) * 128;
        #pragma unroll
        for (int t = 0; t < 8; ++t) {
            float4 bias = *(const float4*)(cb + t * 16 + g * 4);
            f32x4 v = acc[t];
            v[0] += bias.x; v[1] += bias.y; v[2] += bias.z; v[3] += bias.w;
            *(f32x4*)(orow + t * 16 + g * 4) = v;
        }
    }
}

// ---------------------------------------------------------------------------
extern "C" void kernel_launch(void* const* d_in, const int* in_sizes, int n_in,
                              void* d_out, int out_size, void* d_ws, size_t ws_size,
                              hipStream_t stream) {
    const float* x     = (const float*)d_in[0];
    const int*   ei    = (const int*)d_in[1];
    const float* eps_d = (const float*)d_in[2];
    const float* dw1   = (const float*)d_in[3];
    const float* dg1   = (const float*)d_in[4];
    const float* db1   = (const float*)d_in[5];
    const float* dw2   = (const float*)d_in[6];
    const float* eps_u = (const float*)d_in[7];
    const float* uw1   = (const float*)d_in[8];
    const float* ug1   = (const float*)d_in[9];
    const float* ub1   = (const float*)d_in[10];
    const float* uw2   = (const float*)d_in[11];
    const float* ln1g  = (const float*)d_in[12];
    const float* ln1b  = (const float*)d_in[13];
    const float* ln2g  = (const float*)d_in[14];
    const float* ln2b  = (const float*)d_in[15];
    const float* dire  = (const float*)d_in[16];
    const float* cw    = (const float*)d_in[17];
    const float* cb    = (const float*)d_in[18];

    int* deg    = (int*)d_ws;                       // 100000
    int* offs   = deg + 2 * N_NODES;                // 100000
    int* cursor = offs + 2 * N_NODES;               // 100000
    int* bsums  = cursor + 2 * N_NODES;             // 128
    int* bucket = bsums + 128;                      // 1,250,000
    unsigned* xb  = (unsigned*)(bucket + TOTAL_DEG);        // N*64
    unsigned* hhi = xb + (size_t)N_NODES * 64;              // 2*NPAD*64
    unsigned* hlo = hhi + (size_t)2 * NPAD * 64;            // 2*NPAD*64
    unsigned short* hcat    = (unsigned short*)(hlo + (size_t)2 * NPAD * 64); // N*256
    unsigned short* w1bT_hi = hcat + (size_t)N_NODES * 256;  // 2*4096
    unsigned short* w1bT_lo = w1bT_hi + 8192;
    unsigned short* w2bT_hi = w1bT_lo + 8192;
    unsigned short* w2bT_lo = w2bT_hi + 8192;
    unsigned short* cwbT_hi = w2bT_lo + 8192;                // 32768
    unsigned short* cwbT_lo = cwbT_hi + 32768;

    hipMemsetAsync(deg, 0, 2 * N_NODES * sizeof(int), stream);

    int eblocks = (N_EDGES + 255) / 256;
    count_kernel<<<eblocks, 256, 0, stream>>>(ei, deg);
    scan_a<<<98, 256, 0, stream>>>(deg, offs, bsums);
    scan_b<<<1, 128, 0, stream>>>(bsums);
    scan_c<<<98, 256, 0, stream>>>(offs, cursor, bsums);
    fill_kernel<<<eblocks, 256, 0, stream>>>(ei, cursor, bucket);

    convert_x<<<12500, 256, 0, stream>>>(x, xb);
    convert_wT<<<16, 256, 0, stream>>>(dw1, w1bT_hi,        w1bT_lo,        128, 32);
    convert_wT<<<16, 256, 0, stream>>>(uw1, w1bT_hi + 4096, w1bT_lo + 4096, 128, 32);
    convert_wT<<<16, 256, 0, stream>>>(dw2, w2bT_hi,        w2bT_lo,        32, 128);
    convert_wT<<<16, 256, 0, stream>>>(uw2, w2bT_hi + 4096, w2bT_lo + 4096, 32, 128);
    convert_wT<<<128, 256, 0, stream>>>(cw, cwbT_hi, cwbT_lo, 256, 128);

    gather_kernel<<<25000, 256, 0, stream>>>(x, xb, offs, bucket, hhi, hlo, eps_d, eps_u);

    mlp_kernel<<<1564, 256, 0, stream>>>(
        (const unsigned short*)hhi, (const unsigned short*)hlo,
        w1bT_hi, w1bT_lo, w2bT_hi, w2bT_lo,
        dg1, db1, ug1, ub1, ln1g, ln1b, ln2g, ln2b, dire, hcat);

    combine_mfma<<<782, 256, 0, stream>>>(hcat, cwbT_hi, cwbT_lo, cb, (float*)d_out);
}

// Round 5
// 305.605 us; speedup vs baseline: 2.6454x; 1.1433x over previous
//
#include <hip/hip_runtime.h>

#define N_NODES 50000
#define NPAD 50048            // 64*782, padded rows per direction
#define N_EDGES 625000
#define H 128
#define B 32
#define TOTAL_DEG (2 * N_EDGES)
#define PSTRIDE 40            // ushorts per LDS row
#define NPART 8
#define ROWS_PER_PART (2 * N_NODES / NPART)   // 12500

using bf16x8  = __attribute__((ext_vector_type(8))) short;
using f32x4   = __attribute__((ext_vector_type(4))) float;
using u16x4   = __attribute__((ext_vector_type(4))) unsigned short;

static __device__ __forceinline__ unsigned short f2bf(float f) {
    unsigned u = __float_as_uint(f);
    unsigned r = (u + 0x7fff + ((u >> 16) & 1)) >> 16;   // RNE
    return (unsigned short)r;
}
static __device__ __forceinline__ float bf2f(unsigned short h) {
    return __uint_as_float(((unsigned)h) << 16);
}

// ---------------------------------------------------------------------------
// count degrees, XCD-partitioned: block b -> partition p=b&7 of row space.
// ---------------------------------------------------------------------------
__global__ __launch_bounds__(256) void count_kernel(
    const int* __restrict__ ei, int* __restrict__ deg)
{
    int p  = blockIdx.x & 7;
    int eb = blockIdx.x >> 3;
    int e = eb * 256 + threadIdx.x;
    if (e >= N_EDGES) return;
    int lo = p * ROWS_PER_PART, hi = lo + ROWS_PER_PART;
    int s = ei[e];
    int d = ei[N_EDGES + e];
    int r2 = N_NODES + s;
    if (d >= lo && d < hi)  atomicAdd(&deg[d], 1);
    if (r2 >= lo && r2 < hi) atomicAdd(&deg[r2], 1);
}

// ---------------------------------------------------------------------------
// hierarchical exclusive scan (100000 elems)
// ---------------------------------------------------------------------------
__global__ __launch_bounds__(256) void scan_a(
    const int* __restrict__ deg, int* __restrict__ offs, int* __restrict__ bsums)
{
    __shared__ int lds[256];
    int tid = threadIdx.x;
    int base = blockIdx.x * 1024 + tid * 4;
    int v[4]; int tsum = 0;
    #pragma unroll
    for (int q = 0; q < 4; ++q) {
        v[q] = (base + q < 2 * N_NODES) ? deg[base + q] : 0;
        tsum += v[q];
    }
    lds[tid] = tsum;
    __syncthreads();
    #pragma unroll
    for (int off = 1; off < 256; off <<= 1) {
        int t = (tid >= off) ? lds[tid - off] : 0;
        __syncthreads();
        lds[tid] += t;
        __syncthreads();
    }
    int excl = lds[tid] - tsum;
    if (tid == 255) bsums[blockIdx.x] = lds[tid];
    int run = excl;
    #pragma unroll
    for (int q = 0; q < 4; ++q) {
        if (base + q < 2 * N_NODES) offs[base + q] = run;
        run += v[q];
    }
}

__global__ __launch_bounds__(128) void scan_b(int* __restrict__ bsums)
{
    __shared__ int lds[128];
    int tid = threadIdx.x;
    int v = (tid < 98) ? bsums[tid] : 0;
    lds[tid] = v;
    __syncthreads();
    #pragma unroll
    for (int off = 1; off < 128; off <<= 1) {
        int t = (tid >= off) ? lds[tid - off] : 0;
        __syncthreads();
        lds[tid] += t;
        __syncthreads();
    }
    if (tid < 98) bsums[tid] = lds[tid] - v;
}

__global__ __launch_bounds__(256) void scan_c(
    int* __restrict__ offs, int* __restrict__ cursor, const int* __restrict__ bsums)
{
    int add = bsums[blockIdx.x];
    int base = blockIdx.x * 1024 + threadIdx.x * 4;
    #pragma unroll
    for (int q = 0; q < 4; ++q) {
        int i = base + q;
        if (i < 2 * N_NODES) {
            int o = offs[i] + add;
            offs[i] = o;
            cursor[i] = o;
        }
    }
}

// ---------------------------------------------------------------------------
// fill CSR buckets, XCD-partitioned like count.
// ---------------------------------------------------------------------------
__global__ __launch_bounds__(256) void fill_kernel(
    const int* __restrict__ ei, int* __restrict__ cursor, int* __restrict__ bucket)
{
    int p  = blockIdx.x & 7;
    int eb = blockIdx.x >> 3;
    int e = eb * 256 + threadIdx.x;
    if (e >= N_EDGES) return;
    int lo = p * ROWS_PER_PART, hi = lo + ROWS_PER_PART;
    int s = ei[e];
    int d = ei[N_EDGES + e];
    int r2 = N_NODES + s;
    if (d >= lo && d < hi) {
        int pos = atomicAdd(&cursor[d], 1);
        bucket[pos] = s;
    }
    if (r2 >= lo && r2 < hi) {
        int pos = atomicAdd(&cursor[r2], 1);
        bucket[pos] = d;
    }
}

// ---------------------------------------------------------------------------
// x f32 -> xb bf16 (packed pairs)
// ---------------------------------------------------------------------------
__global__ __launch_bounds__(256) void convert_x(
    const float* __restrict__ x, unsigned* __restrict__ xb)
{
    int i = blockIdx.x * 256 + threadIdx.x;     // 3,200,000 exact
    float2 v = ((const float2*)x)[i];
    xb[i] = ((unsigned)f2bf(v.y) << 16) | f2bf(v.x);
}

// ---------------------------------------------------------------------------
// weight transpose + hi/lo bf16 split:  src[K][C] f32 -> hi/lo [C][K] bf16
// ---------------------------------------------------------------------------
__global__ __launch_bounds__(256) void convert_wT(
    const float* __restrict__ src, unsigned short* __restrict__ hi,
    unsigned short* __restrict__ lo, int K, int C)
{
    int i = blockIdx.x * 256 + threadIdx.x;
    if (i >= K * C) return;
    int c = i / K, k = i - c * K;
    float v = src[k * C + c];
    unsigned short h = f2bf(v);
    hi[i] = h;
    lo[i] = f2bf(v - bf2f(h));
}

// ---------------------------------------------------------------------------
// gather: 32-lane group per (node, dir); 2 pairs per wave, 8 waves... 4/block.
// Lane (l32) owns features 4*l32..4*l32+3 (8B of bf16 per row).  ILP-8.
// ---------------------------------------------------------------------------
__global__ __launch_bounds__(256) void gather_kernel(
    const float* __restrict__ x, const unsigned* __restrict__ xb,
    const int* __restrict__ offs, const int* __restrict__ bucket,
    unsigned* __restrict__ hhi, unsigned* __restrict__ hlo,
    const float* __restrict__ eps_d_p, const float* __restrict__ eps_u_p)
{
    int w = threadIdx.x >> 6, lane = threadIdx.x & 63;
    int half = lane >> 5, l32 = lane & 31;
    int gp = (blockIdx.x * 4 + w) * 2 + half;   // 0..99999, grid 12500
    int node = gp >> 1;
    int dir  = gp & 1;
    int ridx = dir * N_NODES + node;
    int s0 = offs[ridx];
    int e0 = (ridx == 2 * N_NODES - 1) ? TOTAL_DEG : offs[ridx + 1];

    float a0 = 0.f, a1 = 0.f, a2 = 0.f, a3 = 0.f;
    for (int base = s0; base < e0; base += 32) {
        int m = e0 - base; if (m > 32) m = 32;
        int id = (l32 < m) ? bucket[base + l32] : 0;
        int lim = m - 1;
        for (int j = 0; j < m; j += 8) {
            uint2 r[8];
            #pragma unroll
            for (int q = 0; q < 8; ++q) {
                int idx = j + q; if (idx > lim) idx = lim;
                int nb = __shfl(id, (half << 5) + idx);
                r[q] = ((const uint2*)(xb + nb * 64))[l32];
            }
            #pragma unroll
            for (int q = 0; q < 8; ++q) {
                if (j + q <= lim) {
                    a0 += __uint_as_float(r[q].x << 16);
                    a1 += __uint_as_float(r[q].x & 0xffff0000u);
                    a2 += __uint_as_float(r[q].y << 16);
                    a3 += __uint_as_float(r[q].y & 0xffff0000u);
                }
            }
        }
    }

    float eps = 1.f + (dir ? eps_u_p[0] : eps_d_p[0]);
    float4 xv = ((const float4*)(x + (size_t)node * H))[l32];   // self term f32
    float h0 = eps * xv.x + a0;
    float h1 = eps * xv.y + a1;
    float h2 = eps * xv.z + a2;
    float h3 = eps * xv.w + a3;
    unsigned short q0 = f2bf(h0), q1 = f2bf(h1), q2 = f2bf(h2), q3 = f2bf(h3);
    int orow = dir * NPAD + node;
    uint2 hv = {((unsigned)q1 << 16) | q0, ((unsigned)q3 << 16) | q2};
    uint2 lv = {((unsigned)f2bf(h1 - bf2f(q1)) << 16) | f2bf(h0 - bf2f(q0)),
                ((unsigned)f2bf(h3 - bf2f(q3)) << 16) | f2bf(h2 - bf2f(q2))};
    ((uint2*)(hhi + (size_t)orow * 64))[l32] = hv;
    ((uint2*)(hlo + (size_t)orow * 64))[l32] = lv;
}

// ---------------------------------------------------------------------------
// batched MLP: per wave 16 rows of one direction (see r3 notes).
// ---------------------------------------------------------------------------
__global__ __launch_bounds__(256) void mlp_kernel(
    const unsigned short* __restrict__ hhi, const unsigned short* __restrict__ hlo,
    const unsigned short* __restrict__ w1bT_hi, const unsigned short* __restrict__ w1bT_lo,
    const unsigned short* __restrict__ w2bT_hi, const unsigned short* __restrict__ w2bT_lo,
    const float* __restrict__ dg1, const float* __restrict__ db1,
    const float* __restrict__ ug1, const float* __restrict__ ub1,
    const float* __restrict__ ln1g, const float* __restrict__ ln1b,
    const float* __restrict__ ln2g, const float* __restrict__ ln2b,
    const float* __restrict__ dir_emb,
    unsigned short* __restrict__ hcat)
{
    __shared__ unsigned short plds[4][2][16 * PSTRIDE];

    int w = threadIdx.x >> 6, lane = threadIdx.x & 63;
    int l15 = lane & 15, g = lane >> 4;
    int blk = blockIdx.x;                 // 0..1563
    int dir = (blk >= 782) ? 1 : 0;
    int r0 = (blk - dir * 782) * 64 + w * 16;

    const unsigned short* w1h = w1bT_hi + dir * 4096;
    const unsigned short* w1l = w1bT_lo + dir * 4096;
    const unsigned short* w2h = w2bT_hi + dir * 4096;
    const unsigned short* w2l = w2bT_lo + dir * 4096;

    // ---- stage 1 ----
    size_t hbase = ((size_t)(dir * NPAD + r0 + l15)) * H;
    f32x4 acc1[2];
    acc1[0] = (f32x4){0.f,0.f,0.f,0.f};
    acc1[1] = (f32x4){0.f,0.f,0.f,0.f};
    #pragma unroll
    for (int ks = 0; ks < 4; ++ks) {
        int ko = ks * 32 + g * 8;
        bf16x8 bh = *(const bf16x8*)(hhi + hbase + ko);
        bf16x8 bl = *(const bf16x8*)(hlo + hbase + ko);
        #pragma unroll
        for (int t = 0; t < 2; ++t) {
            bf16x8 ah = *(const bf16x8*)(w1h + (t * 16 + l15) * H + ko);
            bf16x8 al = *(const bf16x8*)(w1l + (t * 16 + l15) * H + ko);
            acc1[t] = __builtin_amdgcn_mfma_f32_16x16x32_bf16(ah, bh, acc1[t], 0, 0, 0);
            acc1[t] = __builtin_amdgcn_mfma_f32_16x16x32_bf16(al, bh, acc1[t], 0, 0, 0);
            acc1[t] = __builtin_amdgcn_mfma_f32_16x16x32_bf16(ah, bl, acc1[t], 0, 0, 0);
        }
    }

    float s = 0.f, s2 = 0.f;
    #pragma unroll
    for (int t = 0; t < 2; ++t)
        #pragma unroll
        for (int r = 0; r < 4; ++r) { float v = acc1[t][r]; s += v; s2 += v * v; }
    s  += __shfl_xor(s, 16);  s  += __shfl_xor(s, 32);
    s2 += __shfl_xor(s2, 16); s2 += __shfl_xor(s2, 32);
    float mean = s * (1.f / 32.f);
    float var  = s2 * (1.f / 32.f) - mean * mean;
    float rs   = rsqrtf(var + 1e-5f);

    const float* g1p = dir ? ug1 : dg1;
    const float* b1p = dir ? ub1 : db1;
    unsigned short* mh = &plds[w][0][0];
    unsigned short* ml = &plds[w][1][0];
    #pragma unroll
    for (int t = 0; t < 2; ++t) {
        float4 gv = *(const float4*)(g1p + t * 16 + g * 4);
        float4 bv = *(const float4*)(b1p + t * 16 + g * 4);
        float p0 = fmaxf((acc1[t][0] - mean) * rs * gv.x + bv.x, 0.f);
        float p1 = fmaxf((acc1[t][1] - mean) * rs * gv.y + bv.y, 0.f);
        float p2 = fmaxf((acc1[t][2] - mean) * rs * gv.z + bv.z, 0.f);
        float p3 = fmaxf((acc1[t][3] - mean) * rs * gv.w + bv.w, 0.f);
        unsigned short q0 = f2bf(p0), q1 = f2bf(p1), q2 = f2bf(p2), q3 = f2bf(p3);
        u16x4 ph = {q0, q1, q2, q3};
        u16x4 pl = {f2bf(p0 - bf2f(q0)), f2bf(p1 - bf2f(q1)),
                    f2bf(p2 - bf2f(q2)), f2bf(p3 - bf2f(q3))};
        int off = l15 * PSTRIDE + t * 16 + g * 4;
        *(u16x4*)(mh + off) = ph;
        *(u16x4*)(ml + off) = pl;
    }

    // ---- stage 2 ----
    bf16x8 pbh = *(const bf16x8*)(mh + l15 * PSTRIDE + g * 8);
    bf16x8 pbl = *(const bf16x8*)(ml + l15 * PSTRIDE + g * 8);

    f32x4 acc2[8];
    #pragma unroll
    for (int t = 0; t < 8; ++t) acc2[t] = (f32x4){0.f,0.f,0.f,0.f};
    #pragma unroll
    for (int t = 0; t < 8; ++t) {
        bf16x8 ah = *(const bf16x8*)(w2h + (t * 16 + l15) * 32 + g * 8);
        bf16x8 al = *(const bf16x8*)(w2l + (t * 16 + l15) * 32 + g * 8);
        acc2[t] = __builtin_amdgcn_mfma_f32_16x16x32_bf16(ah, pbh, acc2[t], 0, 0, 0);
        acc2[t] = __builtin_amdgcn_mfma_f32_16x16x32_bf16(al, pbh, acc2[t], 0, 0, 0);
        acc2[t] = __builtin_amdgcn_mfma_f32_16x16x32_bf16(ah, pbl, acc2[t], 0, 0, 0);
    }

    float av[8][4];
    float u = 0.f, u2 = 0.f;
    #pragma unroll
    for (int t = 0; t < 8; ++t) {
        float4 de = *(const float4*)(dir_emb + dir * H + t * 16 + g * 4);
        av[t][0] = fmaxf(acc2[t][0] + de.x, 0.f);
        av[t][1] = fmaxf(acc2[t][1] + de.y, 0.f);
        av[t][2] = fmaxf(acc2[t][2] + de.z, 0.f);
        av[t][3] = fmaxf(acc2[t][3] + de.w, 0.f);
        #pragma unroll
        for (int r = 0; r < 4; ++r) { u += av[t][r]; u2 += av[t][r] * av[t][r]; }
    }
    u  += __shfl_xor(u, 16);  u  += __shfl_xor(u, 32);
    u2 += __shfl_xor(u2, 16); u2 += __shfl_xor(u2, 32);
    float m2  = u * (1.f / 128.f);
    float v2  = u2 * (1.f / 128.f) - m2 * m2;
    float rs2 = rsqrtf(v2 + 1e-5f);

    const float* lgp = dir ? ln2g : ln1g;
    const float* lbp = dir ? ln2b : ln1b;
    if ((r0 + l15) < N_NODES) {
        unsigned short* orow = hcat + (size_t)(r0 + l15) * 256 + dir * 128;
        #pragma unroll
        for (int t = 0; t < 8; ++t) {
            float4 gv = *(const float4*)(lgp + t * 16 + g * 4);
            float4 bv = *(const float4*)(lbp + t * 16 + g * 4);
            u16x4 o;
            o[0] = f2bf((av[t][0] - m2) * rs2 * gv.x + bv.x);
            o[1] = f2bf((av[t][1] - m2) * rs2 * gv.y + bv.y);
            o[2] = f2bf((av[t][2] - m2) * rs2 * gv.z + bv.z);
            o[3] = f2bf((av[t][3] - m2) * rs2 * gv.w + bv.w);
            *(u16x4*)(orow + t * 16 + g * 4) = o;
        }
    }
}

// ---------------------------------------------------------------------------
// combine: out = hcat @ cw + cb, transposed operands, cw hi/lo split.
// ---------------------------------------------------------------------------
__global__ __launch_bounds__(256) void combine_mfma(
    const unsigned short* __restrict__ hcat,
    const unsigned short* __restrict__ cwh, const unsigned short* __restrict__ cwl,
    const float* __restrict__ cb, float* __restrict__ out)
{
    int w = threadIdx.x >> 6, lane = threadIdx.x & 63;
    int l15 = lane & 15, g = lane >> 4;
    int m0 = (blockIdx.x * 4 + w) * 16;
    if (m0 >= N_NODES) return;
    int node = m0 + l15; if (node >= N_NODES) node = N_NODES - 1;
    size_t abase = (size_t)node * 256;

    f32x4 acc[8];
    #pragma unroll
    for (int t = 0; t < 8; ++t) acc[t] = (f32x4){0.f,0.f,0.f,0.f};

    #pragma unroll
    for (int ks = 0; ks < 8; ++ks) {
        bf16x8 bfrag = *(const bf16x8*)(hcat + abase + ks * 32 + g * 8);
        #pragma unroll
        for (int t = 0; t < 8; ++t) {
            bf16x8 ah = *(const bf16x8*)(cwh + (t * 16 + l15) * 256 + ks * 32 + g * 8);
            bf16x8 al = *(const bf16x8*)(cwl + (t * 16 + l15) * 256 + ks * 32 + g * 8);
            acc[t] = __builtin_amdgcn_mfma_f32_16x16x32_bf16(ah, bfrag, acc[t], 0, 0, 0);
            acc[t] = __builtin_amdgcn_mfma_f32_16x16x32_bf16(al, bfrag, acc[t], 0, 0, 0);
        }
    }

    if ((m0 + l15) < N_NODES) {
        float* orow = out + (size_t)(m0 + l15) * 128;
        #pragma unroll
        for (int t = 0; t < 8; ++t) {
            float4 bias = *(const float4*)(cb + t * 16 + g * 4);
            f32x4 v = acc[t];
            v[0] += bias.x; v[1] += bias.y; v[2] += bias.z; v[3] += bias.w;
            *(f32x4*)(orow + t * 16 + g * 4) = v;
        }
    }
}

// ---------------------------------------------------------------------------
extern "C" void kernel_launch(void* const* d_in, const int* in_sizes, int n_in,
                              void* d_out, int out_size, void* d_ws, size_t ws_size,
                              hipStream_t stream) {
    const float* x     = (const float*)d_in[0];
    const int*   ei    = (const int*)d_in[1];
    const float* eps_d = (const float*)d_in[2];
    const float* dw1   = (const float*)d_in[3];
    const float* dg1   = (const float*)d_in[4];
    const float* db1   = (const float*)d_in[5];
    const float* dw2   = (const float*)d_in[6];
    const float* eps_u = (const float*)d_in[7];
    const float* uw1   = (const float*)d_in[8];
    const float* ug1   = (const float*)d_in[9];
    const float* ub1   = (const float*)d_in[10];
    const float* uw2   = (const float*)d_in[11];
    const float* ln1g  = (const float*)d_in[12];
    const float* ln1b  = (const float*)d_in[13];
    const float* ln2g  = (const float*)d_in[14];
    const float* ln2b  = (const float*)d_in[15];
    const float* dire  = (const float*)d_in[16];
    const float* cw    = (const float*)d_in[17];
    const float* cb    = (const float*)d_in[18];

    int* deg    = (int*)d_ws;                       // 100000
    int* offs   = deg + 2 * N_NODES;                // 100000
    int* cursor = offs + 2 * N_NODES;               // 100000
    int* bsums  = cursor + 2 * N_NODES;             // 128
    int* bucket = bsums + 128;                      // 1,250,000
    unsigned* xb  = (unsigned*)(bucket + TOTAL_DEG);        // N*64
    unsigned* hhi = xb + (size_t)N_NODES * 64;              // 2*NPAD*64
    unsigned* hlo = hhi + (size_t)2 * NPAD * 64;            // 2*NPAD*64
    unsigned short* hcat    = (unsigned short*)(hlo + (size_t)2 * NPAD * 64); // N*256
    unsigned short* w1bT_hi = hcat + (size_t)N_NODES * 256;
    unsigned short* w1bT_lo = w1bT_hi + 8192;
    unsigned short* w2bT_hi = w1bT_lo + 8192;
    unsigned short* w2bT_lo = w2bT_hi + 8192;
    unsigned short* cwbT_hi = w2bT_lo + 8192;
    unsigned short* cwbT_lo = cwbT_hi + 32768;

    hipMemsetAsync(deg, 0, 2 * N_NODES * sizeof(int), stream);

    int eblocks = (N_EDGES + 255) / 256;            // 2443
    count_kernel<<<eblocks * NPART, 256, 0, stream>>>(ei, deg);
    scan_a<<<98, 256, 0, stream>>>(deg, offs, bsums);
    scan_b<<<1, 128, 0, stream>>>(bsums);
    scan_c<<<98, 256, 0, stream>>>(offs, cursor, bsums);
    fill_kernel<<<eblocks * NPART, 256, 0, stream>>>(ei, cursor, bucket);

    convert_x<<<12500, 256, 0, stream>>>(x, xb);
    convert_wT<<<16, 256, 0, stream>>>(dw1, w1bT_hi,        w1bT_lo,        128, 32);
    convert_wT<<<16, 256, 0, stream>>>(uw1, w1bT_hi + 4096, w1bT_lo + 4096, 128, 32);
    convert_wT<<<16, 256, 0, stream>>>(dw2, w2bT_hi,        w2bT_lo,        32, 128);
    convert_wT<<<16, 256, 0, stream>>>(uw2, w2bT_hi + 4096, w2bT_lo + 4096, 32, 128);
    convert_wT<<<128, 256, 0, stream>>>(cw, cwbT_hi, cwbT_lo, 256, 128);

    gather_kernel<<<12500, 256, 0, stream>>>(x, xb, offs, bucket, hhi, hlo, eps_d, eps_u);

    mlp_kernel<<<1564, 256, 0, stream>>>(
        (const unsigned short*)hhi, (const unsigned short*)hlo,
        w1bT_hi, w1bT_lo, w2bT_hi, w2bT_lo,
        dg1, db1, ug1, ub1, ln1g, ln1b, ln2g, ln2b, dire, hcat);

    combine_mfma<<<782, 256, 0, stream>>>(hcat, cwbT_hi, cwbT_lo, cb, (float*)d_out);
}

// Round 6
// 297.693 us; speedup vs baseline: 2.7157x; 1.0266x over previous
//
#include <hip/hip_runtime.h>

#define N_NODES 50000
#define NPAD 50048            // 64*782, padded rows per direction
#define N_EDGES 625000
#define H 128
#define B 32
#define TOTAL_DEG (2 * N_EDGES)
#define PSTRIDE 40            // ushorts per LDS row
#define NPART 8
#define ROWS_PER_PART (2 * N_NODES / NPART)   // 12500

using bf16x8  = __attribute__((ext_vector_type(8))) short;
using f32x4   = __attribute__((ext_vector_type(4))) float;
using u16x4   = __attribute__((ext_vector_type(4))) unsigned short;

static __device__ __forceinline__ unsigned short f2bf(float f) {
    unsigned u = __float_as_uint(f);
    unsigned r = (u + 0x7fff + ((u >> 16) & 1)) >> 16;   // RNE
    return (unsigned short)r;
}
static __device__ __forceinline__ float bf2f(unsigned short h) {
    return __uint_as_float(((unsigned)h) << 16);
}

// ---------------------------------------------------------------------------
// count degrees, XCD-partitioned: block b -> partition p=b&7 of row space.
// ---------------------------------------------------------------------------
__global__ __launch_bounds__(256) void count_kernel(
    const int* __restrict__ ei, int* __restrict__ deg)
{
    int p  = blockIdx.x & 7;
    int eb = blockIdx.x >> 3;
    int e = eb * 256 + threadIdx.x;
    if (e >= N_EDGES) return;
    int lo = p * ROWS_PER_PART, hi = lo + ROWS_PER_PART;
    int s = ei[e];
    int d = ei[N_EDGES + e];
    int r2 = N_NODES + s;
    if (d >= lo && d < hi)  atomicAdd(&deg[d], 1);
    if (r2 >= lo && r2 < hi) atomicAdd(&deg[r2], 1);
}

// ---------------------------------------------------------------------------
// hierarchical exclusive scan (100000 elems)
// ---------------------------------------------------------------------------
__global__ __launch_bounds__(256) void scan_a(
    const int* __restrict__ deg, int* __restrict__ offs, int* __restrict__ bsums)
{
    __shared__ int lds[256];
    int tid = threadIdx.x;
    int base = blockIdx.x * 1024 + tid * 4;
    int v[4]; int tsum = 0;
    #pragma unroll
    for (int q = 0; q < 4; ++q) {
        v[q] = (base + q < 2 * N_NODES) ? deg[base + q] : 0;
        tsum += v[q];
    }
    lds[tid] = tsum;
    __syncthreads();
    #pragma unroll
    for (int off = 1; off < 256; off <<= 1) {
        int t = (tid >= off) ? lds[tid - off] : 0;
        __syncthreads();
        lds[tid] += t;
        __syncthreads();
    }
    int excl = lds[tid] - tsum;
    if (tid == 255) bsums[blockIdx.x] = lds[tid];
    int run = excl;
    #pragma unroll
    for (int q = 0; q < 4; ++q) {
        if (base + q < 2 * N_NODES) offs[base + q] = run;
        run += v[q];
    }
}

__global__ __launch_bounds__(128) void scan_b(int* __restrict__ bsums)
{
    __shared__ int lds[128];
    int tid = threadIdx.x;
    int v = (tid < 98) ? bsums[tid] : 0;
    lds[tid] = v;
    __syncthreads();
    #pragma unroll
    for (int off = 1; off < 128; off <<= 1) {
        int t = (tid >= off) ? lds[tid - off] : 0;
        __syncthreads();
        lds[tid] += t;
        __syncthreads();
    }
    if (tid < 98) bsums[tid] = lds[tid] - v;
}

__global__ __launch_bounds__(256) void scan_c(
    int* __restrict__ offs, int* __restrict__ cursor, const int* __restrict__ bsums)
{
    int add = bsums[blockIdx.x];
    int base = blockIdx.x * 1024 + threadIdx.x * 4;
    #pragma unroll
    for (int q = 0; q < 4; ++q) {
        int i = base + q;
        if (i < 2 * N_NODES) {
            int o = offs[i] + add;
            offs[i] = o;
            cursor[i] = o;
        }
    }
}

// ---------------------------------------------------------------------------
// fill CSR buckets, XCD-partitioned like count.
// ---------------------------------------------------------------------------
__global__ __launch_bounds__(256) void fill_kernel(
    const int* __restrict__ ei, int* __restrict__ cursor, int* __restrict__ bucket)
{
    int p  = blockIdx.x & 7;
    int eb = blockIdx.x >> 3;
    int e = eb * 256 + threadIdx.x;
    if (e >= N_EDGES) return;
    int lo = p * ROWS_PER_PART, hi = lo + ROWS_PER_PART;
    int s = ei[e];
    int d = ei[N_EDGES + e];
    int r2 = N_NODES + s;
    if (d >= lo && d < hi) {
        int pos = atomicAdd(&cursor[d], 1);
        bucket[pos] = s;
    }
    if (r2 >= lo && r2 < hi) {
        int pos = atomicAdd(&cursor[r2], 1);
        bucket[pos] = d;
    }
}

// ---------------------------------------------------------------------------
// x f32 -> xb bf16 (packed pairs)
// ---------------------------------------------------------------------------
__global__ __launch_bounds__(256) void convert_x(
    const float* __restrict__ x, unsigned* __restrict__ xb)
{
    int i = blockIdx.x * 256 + threadIdx.x;     // 3,200,000 exact
    float2 v = ((const float2*)x)[i];
    xb[i] = ((unsigned)f2bf(v.y) << 16) | f2bf(v.x);
}

// ---------------------------------------------------------------------------
// weight transpose + hi/lo bf16 split:  src[K][C] f32 -> hi/lo [C][K] bf16
// ---------------------------------------------------------------------------
__global__ __launch_bounds__(256) void convert_wT(
    const float* __restrict__ src, unsigned short* __restrict__ hi,
    unsigned short* __restrict__ lo, int K, int C)
{
    int i = blockIdx.x * 256 + threadIdx.x;
    if (i >= K * C) return;
    int c = i / K, k = i - c * K;
    float v = src[k * C + c];
    unsigned short h = f2bf(v);
    hi[i] = h;
    lo[i] = f2bf(v - bf2f(h));
}

// ---------------------------------------------------------------------------
// gather: 32-lane group per (node, dir); 2 pairs per wave.
// Lane (l32) owns features 4*l32..4*l32+3 (8B of bf16 per row).  ILP-8.
// ---------------------------------------------------------------------------
__global__ __launch_bounds__(256) void gather_kernel(
    const float* __restrict__ x, const unsigned* __restrict__ xb,
    const int* __restrict__ offs, const int* __restrict__ bucket,
    unsigned* __restrict__ hhi, unsigned* __restrict__ hlo,
    const float* __restrict__ eps_d_p, const float* __restrict__ eps_u_p)
{
    int w = threadIdx.x >> 6, lane = threadIdx.x & 63;
    int half = lane >> 5, l32 = lane & 31;
    int gp = (blockIdx.x * 4 + w) * 2 + half;   // 0..99999, grid 12500
    int node = gp >> 1;
    int dir  = gp & 1;
    int ridx = dir * N_NODES + node;
    int s0 = offs[ridx];
    int e0 = (ridx == 2 * N_NODES - 1) ? TOTAL_DEG : offs[ridx + 1];

    float a0 = 0.f, a1 = 0.f, a2 = 0.f, a3 = 0.f;
    for (int base = s0; base < e0; base += 32) {
        int m = e0 - base; if (m > 32) m = 32;
        int id = (l32 < m) ? bucket[base + l32] : 0;
        int lim = m - 1;
        for (int j = 0; j < m; j += 8) {
            uint2 r[8];
            #pragma unroll
            for (int q = 0; q < 8; ++q) {
                int idx = j + q; if (idx > lim) idx = lim;
                int nb = __shfl(id, (half << 5) + idx);
                r[q] = ((const uint2*)(xb + nb * 64))[l32];
            }
            #pragma unroll
            for (int q = 0; q < 8; ++q) {
                if (j + q <= lim) {
                    a0 += __uint_as_float(r[q].x << 16);
                    a1 += __uint_as_float(r[q].x & 0xffff0000u);
                    a2 += __uint_as_float(r[q].y << 16);
                    a3 += __uint_as_float(r[q].y & 0xffff0000u);
                }
            }
        }
    }

    float eps = 1.f + (dir ? eps_u_p[0] : eps_d_p[0]);
    float4 xv = ((const float4*)(x + (size_t)node * H))[l32];   // self term f32
    float h0 = eps * xv.x + a0;
    float h1 = eps * xv.y + a1;
    float h2 = eps * xv.z + a2;
    float h3 = eps * xv.w + a3;
    unsigned short q0 = f2bf(h0), q1 = f2bf(h1), q2 = f2bf(h2), q3 = f2bf(h3);
    int orow = dir * NPAD + node;
    uint2 hv = {((unsigned)q1 << 16) | q0, ((unsigned)q3 << 16) | q2};
    uint2 lv = {((unsigned)f2bf(h1 - bf2f(q1)) << 16) | f2bf(h0 - bf2f(q0)),
                ((unsigned)f2bf(h3 - bf2f(q3)) << 16) | f2bf(h2 - bf2f(q2))};
    ((uint2*)(hhi + (size_t)orow * 64))[l32] = hv;
    ((uint2*)(hlo + (size_t)orow * 64))[l32] = lv;
}

// ---------------------------------------------------------------------------
// batched MLP: per wave 16 rows of one direction.
// ---------------------------------------------------------------------------
__global__ __launch_bounds__(256) void mlp_kernel(
    const unsigned short* __restrict__ hhi, const unsigned short* __restrict__ hlo,
    const unsigned short* __restrict__ w1bT_hi, const unsigned short* __restrict__ w1bT_lo,
    const unsigned short* __restrict__ w2bT_hi, const unsigned short* __restrict__ w2bT_lo,
    const float* __restrict__ dg1, const float* __restrict__ db1,
    const float* __restrict__ ug1, const float* __restrict__ ub1,
    const float* __restrict__ ln1g, const float* __restrict__ ln1b,
    const float* __restrict__ ln2g, const float* __restrict__ ln2b,
    const float* __restrict__ dir_emb,
    unsigned short* __restrict__ hcat)
{
    __shared__ unsigned short plds[4][2][16 * PSTRIDE];

    int w = threadIdx.x >> 6, lane = threadIdx.x & 63;
    int l15 = lane & 15, g = lane >> 4;
    int blk = blockIdx.x;                 // 0..1563
    int dir = (blk >= 782) ? 1 : 0;
    int r0 = (blk - dir * 782) * 64 + w * 16;

    const unsigned short* w1h = w1bT_hi + dir * 4096;
    const unsigned short* w1l = w1bT_lo + dir * 4096;
    const unsigned short* w2h = w2bT_hi + dir * 4096;
    const unsigned short* w2l = w2bT_lo + dir * 4096;

    // ---- stage 1 ----
    size_t hbase = ((size_t)(dir * NPAD + r0 + l15)) * H;
    f32x4 acc1[2];
    acc1[0] = (f32x4){0.f,0.f,0.f,0.f};
    acc1[1] = (f32x4){0.f,0.f,0.f,0.f};
    #pragma unroll
    for (int ks = 0; ks < 4; ++ks) {
        int ko = ks * 32 + g * 8;
        bf16x8 bh = *(const bf16x8*)(hhi + hbase + ko);
        bf16x8 bl = *(const bf16x8*)(hlo + hbase + ko);
        #pragma unroll
        for (int t = 0; t < 2; ++t) {
            bf16x8 ah = *(const bf16x8*)(w1h + (t * 16 + l15) * H + ko);
            bf16x8 al = *(const bf16x8*)(w1l + (t * 16 + l15) * H + ko);
            acc1[t] = __builtin_amdgcn_mfma_f32_16x16x32_bf16(ah, bh, acc1[t], 0, 0, 0);
            acc1[t] = __builtin_amdgcn_mfma_f32_16x16x32_bf16(al, bh, acc1[t], 0, 0, 0);
            acc1[t] = __builtin_amdgcn_mfma_f32_16x16x32_bf16(ah, bl, acc1[t], 0, 0, 0);
        }
    }

    float s = 0.f, s2 = 0.f;
    #pragma unroll
    for (int t = 0; t < 2; ++t)
        #pragma unroll
        for (int r = 0; r < 4; ++r) { float v = acc1[t][r]; s += v; s2 += v * v; }
    s  += __shfl_xor(s, 16);  s  += __shfl_xor(s, 32);
    s2 += __shfl_xor(s2, 16); s2 += __shfl_xor(s2, 32);
    float mean = s * (1.f / 32.f);
    float var  = s2 * (1.f / 32.f) - mean * mean;
    float rs   = rsqrtf(var + 1e-5f);

    const float* g1p = dir ? ug1 : dg1;
    const float* b1p = dir ? ub1 : db1;
    unsigned short* mh = &plds[w][0][0];
    unsigned short* ml = &plds[w][1][0];
    #pragma unroll
    for (int t = 0; t < 2; ++t) {
        float4 gv = *(const float4*)(g1p + t * 16 + g * 4);
        float4 bv = *(const float4*)(b1p + t * 16 + g * 4);
        float p0 = fmaxf((acc1[t][0] - mean) * rs * gv.x + bv.x, 0.f);
        float p1 = fmaxf((acc1[t][1] - mean) * rs * gv.y + bv.y, 0.f);
        float p2 = fmaxf((acc1[t][2] - mean) * rs * gv.z + bv.z, 0.f);
        float p3 = fmaxf((acc1[t][3] - mean) * rs * gv.w + bv.w, 0.f);
        unsigned short q0 = f2bf(p0), q1 = f2bf(p1), q2 = f2bf(p2), q3 = f2bf(p3);
        u16x4 ph = {q0, q1, q2, q3};
        u16x4 pl = {f2bf(p0 - bf2f(q0)), f2bf(p1 - bf2f(q1)),
                    f2bf(p2 - bf2f(q2)), f2bf(p3 - bf2f(q3))};
        int off = l15 * PSTRIDE + t * 16 + g * 4;
        *(u16x4*)(mh + off) = ph;
        *(u16x4*)(ml + off) = pl;
    }

    // ---- stage 2 ----
    bf16x8 pbh = *(const bf16x8*)(mh + l15 * PSTRIDE + g * 8);
    bf16x8 pbl = *(const bf16x8*)(ml + l15 * PSTRIDE + g * 8);

    f32x4 acc2[8];
    #pragma unroll
    for (int t = 0; t < 8; ++t) acc2[t] = (f32x4){0.f,0.f,0.f,0.f};
    #pragma unroll
    for (int t = 0; t < 8; ++t) {
        bf16x8 ah = *(const bf16x8*)(w2h + (t * 16 + l15) * 32 + g * 8);
        bf16x8 al = *(const bf16x8*)(w2l + (t * 16 + l15) * 32 + g * 8);
        acc2[t] = __builtin_amdgcn_mfma_f32_16x16x32_bf16(ah, pbh, acc2[t], 0, 0, 0);
        acc2[t] = __builtin_amdgcn_mfma_f32_16x16x32_bf16(al, pbh, acc2[t], 0, 0, 0);
        acc2[t] = __builtin_amdgcn_mfma_f32_16x16x32_bf16(ah, pbl, acc2[t], 0, 0, 0);
    }

    float av[8][4];
    float u = 0.f, u2 = 0.f;
    #pragma unroll
    for (int t = 0; t < 8; ++t) {
        float4 de = *(const float4*)(dir_emb + dir * H + t * 16 + g * 4);
        av[t][0] = fmaxf(acc2[t][0] + de.x, 0.f);
        av[t][1] = fmaxf(acc2[t][1] + de.y, 0.f);
        av[t][2] = fmaxf(acc2[t][2] + de.z, 0.f);
        av[t][3] = fmaxf(acc2[t][3] + de.w, 0.f);
        #pragma unroll
        for (int r = 0; r < 4; ++r) { u += av[t][r]; u2 += av[t][r] * av[t][r]; }
    }
    u  += __shfl_xor(u, 16);  u  += __shfl_xor(u, 32);
    u2 += __shfl_xor(u2, 16); u2 += __shfl_xor(u2, 32);
    float m2  = u * (1.f / 128.f);
    float v2  = u2 * (1.f / 128.f) - m2 * m2;
    float rs2 = rsqrtf(v2 + 1e-5f);

    const float* lgp = dir ? ln2g : ln1g;
    const float* lbp = dir ? ln2b : ln1b;
    if ((r0 + l15) < N_NODES) {
        unsigned short* orow = hcat + (size_t)(r0 + l15) * 256 + dir * 128;
        #pragma unroll
        for (int t = 0; t < 8; ++t) {
            float4 gv = *(const float4*)(lgp + t * 16 + g * 4);
            float4 bv = *(const float4*)(lbp + t * 16 + g * 4);
            u16x4 o;
            o[0] = f2bf((av[t][0] - m2) * rs2 * gv.x + bv.x);
            o[1] = f2bf((av[t][1] - m2) * rs2 * gv.y + bv.y);
            o[2] = f2bf((av[t][2] - m2) * rs2 * gv.z + bv.z);
            o[3] = f2bf((av[t][3] - m2) * rs2 * gv.w + bv.w);
            *(u16x4*)(orow + t * 16 + g * 4) = o;
        }
    }
}

// ---------------------------------------------------------------------------
// combine: out = hcat @ cw + cb.  Wave = 16 nodes x 64 cols (col-half ch).
// Explicit 2-stage register pipeline over ks: prefetch A(ks+1) during MFMA(ks).
// ---------------------------------------------------------------------------
__global__ __launch_bounds__(256) void combine_mfma(
    const unsigned short* __restrict__ hcat,
    const unsigned short* __restrict__ cwh, const unsigned short* __restrict__ cwl,
    const float* __restrict__ cb, float* __restrict__ out)
{
    int w = threadIdx.x >> 6, lane = threadIdx.x & 63;
    int l15 = lane & 15, g = lane >> 4;
    int gid = blockIdx.x * 4 + w;               // grid 1564 -> 6256 waves
    int m0 = (gid >> 1) * 16;                   // node group of 16
    int ch = gid & 1;                           // column half: cols ch*64..+63
    if (m0 >= N_NODES) return;
    int node = m0 + l15; if (node >= N_NODES) node = N_NODES - 1;
    size_t abase = (size_t)node * 256;

    // preload all 8 B-fragments (hcat row, K=256)
    bf16x8 bfrag[8];
    #pragma unroll
    for (int ks = 0; ks < 8; ++ks)
        bfrag[ks] = *(const bf16x8*)(hcat + abase + ks * 32 + g * 8);

    const unsigned short* ah_base = cwh + (ch * 64 + l15) * 256 + g * 8;
    const unsigned short* al_base = cwl + (ch * 64 + l15) * 256 + g * 8;

    f32x4 acc[4];
    #pragma unroll
    for (int t = 0; t < 4; ++t) acc[t] = (f32x4){0.f,0.f,0.f,0.f};

    // 2-stage software pipeline (fully unrolled: cur/nxt fold statically)
    bf16x8 Ah0[4], Al0[4], Ah1[4], Al1[4];
    #pragma unroll
    for (int t = 0; t < 4; ++t) {
        Ah0[t] = *(const bf16x8*)(ah_base + (t * 16) * 256);
        Al0[t] = *(const bf16x8*)(al_base + (t * 16) * 256);
    }
    #pragma unroll
    for (int ks = 0; ks < 8; ++ks) {
        if (ks < 7) {
            int ko = (ks + 1) * 32;
            if ((ks & 1) == 0) {
                #pragma unroll
                for (int t = 0; t < 4; ++t) {
                    Ah1[t] = *(const bf16x8*)(ah_base + (t * 16) * 256 + ko);
                    Al1[t] = *(const bf16x8*)(al_base + (t * 16) * 256 + ko);
                }
            } else {
                #pragma unroll
                for (int t = 0; t < 4; ++t) {
                    Ah0[t] = *(const bf16x8*)(ah_base + (t * 16) * 256 + ko);
                    Al0[t] = *(const bf16x8*)(al_base + (t * 16) * 256 + ko);
                }
            }
        }
        if ((ks & 1) == 0) {
            #pragma unroll
            for (int t = 0; t < 4; ++t) {
                acc[t] = __builtin_amdgcn_mfma_f32_16x16x32_bf16(Ah0[t], bfrag[ks], acc[t], 0, 0, 0);
                acc[t] = __builtin_amdgcn_mfma_f32_16x16x32_bf16(Al0[t], bfrag[ks], acc[t], 0, 0, 0);
            }
        } else {
            #pragma unroll
            for (int t = 0; t < 4; ++t) {
                acc[t] = __builtin_amdgcn_mfma_f32_16x16x32_bf16(Ah1[t], bfrag[ks], acc[t], 0, 0, 0);
                acc[t] = __builtin_amdgcn_mfma_f32_16x16x32_bf16(Al1[t], bfrag[ks], acc[t], 0, 0, 0);
            }
        }
    }

    if ((m0 + l15) < N_NODES) {
        float* orow = out + (size_t)(m0 + l15) * 128 + ch * 64;
        #pragma unroll
        for (int t = 0; t < 4; ++t) {
            float4 bias = *(const float4*)(cb + ch * 64 + t * 16 + g * 4);
            f32x4 v = acc[t];
            v[0] += bias.x; v[1] += bias.y; v[2] += bias.z; v[3] += bias.w;
            *(f32x4*)(orow + t * 16 + g * 4) = v;
        }
    }
}

// ---------------------------------------------------------------------------
extern "C" void kernel_launch(void* const* d_in, const int* in_sizes, int n_in,
                              void* d_out, int out_size, void* d_ws, size_t ws_size,
                              hipStream_t stream) {
    const float* x     = (const float*)d_in[0];
    const int*   ei    = (const int*)d_in[1];
    const float* eps_d = (const float*)d_in[2];
    const float* dw1   = (const float*)d_in[3];
    const float* dg1   = (const float*)d_in[4];
    const float* db1   = (const float*)d_in[5];
    const float* dw2   = (const float*)d_in[6];
    const float* eps_u = (const float*)d_in[7];
    const float* uw1   = (const float*)d_in[8];
    const float* ug1   = (const float*)d_in[9];
    const float* ub1   = (const float*)d_in[10];
    const float* uw2   = (const float*)d_in[11];
    const float* ln1g  = (const float*)d_in[12];
    const float* ln1b  = (const float*)d_in[13];
    const float* ln2g  = (const float*)d_in[14];
    const float* ln2b  = (const float*)d_in[15];
    const float* dire  = (const float*)d_in[16];
    const float* cw    = (const float*)d_in[17];
    const float* cb    = (const float*)d_in[18];

    int* deg    = (int*)d_ws;                       // 100000
    int* offs   = deg + 2 * N_NODES;                // 100000
    int* cursor = offs + 2 * N_NODES;               // 100000
    int* bsums  = cursor + 2 * N_NODES;             // 128
    int* bucket = bsums + 128;                      // 1,250,000
    unsigned* xb  = (unsigned*)(bucket + TOTAL_DEG);        // N*64
    unsigned* hhi = xb + (size_t)N_NODES * 64;              // 2*NPAD*64
    unsigned* hlo = hhi + (size_t)2 * NPAD * 64;            // 2*NPAD*64
    unsigned short* hcat    = (unsigned short*)(hlo + (size_t)2 * NPAD * 64); // N*256
    unsigned short* w1bT_hi = hcat + (size_t)N_NODES * 256;
    unsigned short* w1bT_lo = w1bT_hi + 8192;
    unsigned short* w2bT_hi = w1bT_lo + 8192;
    unsigned short* w2bT_lo = w2bT_hi + 8192;
    unsigned short* cwbT_hi = w2bT_lo + 8192;
    unsigned short* cwbT_lo = cwbT_hi + 32768;

    hipMemsetAsync(deg, 0, 2 * N_NODES * sizeof(int), stream);

    int eblocks = (N_EDGES + 255) / 256;            // 2443
    count_kernel<<<eblocks * NPART, 256, 0, stream>>>(ei, deg);
    scan_a<<<98, 256, 0, stream>>>(deg, offs, bsums);
    scan_b<<<1, 128, 0, stream>>>(bsums);
    scan_c<<<98, 256, 0, stream>>>(offs, cursor, bsums);
    fill_kernel<<<eblocks * NPART, 256, 0, stream>>>(ei, cursor, bucket);

    convert_x<<<12500, 256, 0, stream>>>(x, xb);
    convert_wT<<<16, 256, 0, stream>>>(dw1, w1bT_hi,        w1bT_lo,        128, 32);
    convert_wT<<<16, 256, 0, stream>>>(uw1, w1bT_hi + 4096, w1bT_lo + 4096, 128, 32);
    convert_wT<<<16, 256, 0, stream>>>(dw2, w2bT_hi,        w2bT_lo,        32, 128);
    convert_wT<<<16, 256, 0, stream>>>(uw2, w2bT_hi + 4096, w2bT_lo + 4096, 32, 128);
    convert_wT<<<128, 256, 0, stream>>>(cw, cwbT_hi, cwbT_lo, 256, 128);

    gather_kernel<<<12500, 256, 0, stream>>>(x, xb, offs, bucket, hhi, hlo, eps_d, eps_u);

    mlp_kernel<<<1564, 256, 0, stream>>>(
        (const unsigned short*)hhi, (const unsigned short*)hlo,
        w1bT_hi, w1bT_lo, w2bT_hi, w2bT_lo,
        dg1, db1, ug1, ub1, ln1g, ln1b, ln2g, ln2b, dire, hcat);

    combine_mfma<<<1564, 256, 0, stream>>>(hcat, cwbT_hi, cwbT_lo, cb, (float*)d_out);
}

// Round 7
// 264.946 us; speedup vs baseline: 3.0514x; 1.1236x over previous
//
#include <hip/hip_runtime.h>

#define N_NODES 50000
#define NPAD 50048            // 64*782, padded rows per direction
#define N_EDGES 625000
#define H 128
#define B 32
#define TOTAL_DEG (2 * N_EDGES)
#define PSTRIDE 40            // ushorts per LDS row
#define NPART 8
#define ROWS_PER_PART (2 * N_NODES / NPART)   // 12500
#define NGRP 3125             // node groups of 16 (exact: 3125*16 = 50000)

using bf16x8  = __attribute__((ext_vector_type(8))) short;
using f32x4   = __attribute__((ext_vector_type(4))) float;
using u16x4   = __attribute__((ext_vector_type(4))) unsigned short;

static __device__ __forceinline__ unsigned short f2bf(float f) {
    unsigned u = __float_as_uint(f);
    unsigned r = (u + 0x7fff + ((u >> 16) & 1)) >> 16;   // RNE
    return (unsigned short)r;
}
static __device__ __forceinline__ float bf2f(unsigned short h) {
    return __uint_as_float(((unsigned)h) << 16);
}

// ---------------------------------------------------------------------------
// count degrees, XCD-partitioned: block b -> partition p=b&7 of row space.
// ---------------------------------------------------------------------------
__global__ __launch_bounds__(256) void count_kernel(
    const int* __restrict__ ei, int* __restrict__ deg)
{
    int p  = blockIdx.x & 7;
    int eb = blockIdx.x >> 3;
    int e = eb * 256 + threadIdx.x;
    if (e >= N_EDGES) return;
    int lo = p * ROWS_PER_PART, hi = lo + ROWS_PER_PART;
    int s = ei[e];
    int d = ei[N_EDGES + e];
    int r2 = N_NODES + s;
    if (d >= lo && d < hi)  atomicAdd(&deg[d], 1);
    if (r2 >= lo && r2 < hi) atomicAdd(&deg[r2], 1);
}

// ---------------------------------------------------------------------------
// hierarchical exclusive scan (100000 elems)
// ---------------------------------------------------------------------------
__global__ __launch_bounds__(256) void scan_a(
    const int* __restrict__ deg, int* __restrict__ offs, int* __restrict__ bsums)
{
    __shared__ int lds[256];
    int tid = threadIdx.x;
    int base = blockIdx.x * 1024 + tid * 4;
    int v[4]; int tsum = 0;
    #pragma unroll
    for (int q = 0; q < 4; ++q) {
        v[q] = (base + q < 2 * N_NODES) ? deg[base + q] : 0;
        tsum += v[q];
    }
    lds[tid] = tsum;
    __syncthreads();
    #pragma unroll
    for (int off = 1; off < 256; off <<= 1) {
        int t = (tid >= off) ? lds[tid - off] : 0;
        __syncthreads();
        lds[tid] += t;
        __syncthreads();
    }
    int excl = lds[tid] - tsum;
    if (tid == 255) bsums[blockIdx.x] = lds[tid];
    int run = excl;
    #pragma unroll
    for (int q = 0; q < 4; ++q) {
        if (base + q < 2 * N_NODES) offs[base + q] = run;
        run += v[q];
    }
}

__global__ __launch_bounds__(128) void scan_b(int* __restrict__ bsums)
{
    __shared__ int lds[128];
    int tid = threadIdx.x;
    int v = (tid < 98) ? bsums[tid] : 0;
    lds[tid] = v;
    __syncthreads();
    #pragma unroll
    for (int off = 1; off < 128; off <<= 1) {
        int t = (tid >= off) ? lds[tid - off] : 0;
        __syncthreads();
        lds[tid] += t;
        __syncthreads();
    }
    if (tid < 98) bsums[tid] = lds[tid] - v;
}

__global__ __launch_bounds__(256) void scan_c(
    int* __restrict__ offs, int* __restrict__ cursor, const int* __restrict__ bsums)
{
    int add = bsums[blockIdx.x];
    int base = blockIdx.x * 1024 + threadIdx.x * 4;
    #pragma unroll
    for (int q = 0; q < 4; ++q) {
        int i = base + q;
        if (i < 2 * N_NODES) {
            int o = offs[i] + add;
            offs[i] = o;
            cursor[i] = o;
        }
    }
}

// ---------------------------------------------------------------------------
// fill CSR buckets, XCD-partitioned like count.
// ---------------------------------------------------------------------------
__global__ __launch_bounds__(256) void fill_kernel(
    const int* __restrict__ ei, int* __restrict__ cursor, int* __restrict__ bucket)
{
    int p  = blockIdx.x & 7;
    int eb = blockIdx.x >> 3;
    int e = eb * 256 + threadIdx.x;
    if (e >= N_EDGES) return;
    int lo = p * ROWS_PER_PART, hi = lo + ROWS_PER_PART;
    int s = ei[e];
    int d = ei[N_EDGES + e];
    int r2 = N_NODES + s;
    if (d >= lo && d < hi) {
        int pos = atomicAdd(&cursor[d], 1);
        bucket[pos] = s;
    }
    if (r2 >= lo && r2 < hi) {
        int pos = atomicAdd(&cursor[r2], 1);
        bucket[pos] = d;
    }
}

// ---------------------------------------------------------------------------
// x f32 -> xb bf16 (packed pairs)
// ---------------------------------------------------------------------------
__global__ __launch_bounds__(256) void convert_x(
    const float* __restrict__ x, unsigned* __restrict__ xb)
{
    int i = blockIdx.x * 256 + threadIdx.x;     // 3,200,000 exact
    float2 v = ((const float2*)x)[i];
    xb[i] = ((unsigned)f2bf(v.y) << 16) | f2bf(v.x);
}

// ---------------------------------------------------------------------------
// weight transpose + hi/lo bf16 split:  src[K][C] f32 -> hi/lo [C][K] bf16
// ---------------------------------------------------------------------------
__global__ __launch_bounds__(256) void convert_wT(
    const float* __restrict__ src, unsigned short* __restrict__ hi,
    unsigned short* __restrict__ lo, int K, int C)
{
    int i = blockIdx.x * 256 + threadIdx.x;
    if (i >= K * C) return;
    int c = i / K, k = i - c * K;
    float v = src[k * C + c];
    unsigned short h = f2bf(v);
    hi[i] = h;
    lo[i] = f2bf(v - bf2f(h));
}

// cw transpose, hi only: cw[256][128] -> cwT[128][256] bf16
__global__ __launch_bounds__(256) void convert_cwT(
    const float* __restrict__ src, unsigned short* __restrict__ hi)
{
    int i = blockIdx.x * 256 + threadIdx.x;    // 32768, grid 128
    int c = i >> 8, k = i & 255;
    hi[i] = f2bf(src[k * 128 + c]);
}

// ---------------------------------------------------------------------------
// gather: 32-lane group per (node, dir); 2 pairs per wave.
// ---------------------------------------------------------------------------
__global__ __launch_bounds__(256) void gather_kernel(
    const float* __restrict__ x, const unsigned* __restrict__ xb,
    const int* __restrict__ offs, const int* __restrict__ bucket,
    unsigned* __restrict__ hhi, unsigned* __restrict__ hlo,
    const float* __restrict__ eps_d_p, const float* __restrict__ eps_u_p)
{
    int w = threadIdx.x >> 6, lane = threadIdx.x & 63;
    int half = lane >> 5, l32 = lane & 31;
    int gp = (blockIdx.x * 4 + w) * 2 + half;   // 0..99999, grid 12500
    int node = gp >> 1;
    int dir  = gp & 1;
    int ridx = dir * N_NODES + node;
    int s0 = offs[ridx];
    int e0 = (ridx == 2 * N_NODES - 1) ? TOTAL_DEG : offs[ridx + 1];

    float a0 = 0.f, a1 = 0.f, a2 = 0.f, a3 = 0.f;
    for (int base = s0; base < e0; base += 32) {
        int m = e0 - base; if (m > 32) m = 32;
        int id = (l32 < m) ? bucket[base + l32] : 0;
        int lim = m - 1;
        for (int j = 0; j < m; j += 8) {
            uint2 r[8];
            #pragma unroll
            for (int q = 0; q < 8; ++q) {
                int idx = j + q; if (idx > lim) idx = lim;
                int nb = __shfl(id, (half << 5) + idx);
                r[q] = ((const uint2*)(xb + nb * 64))[l32];
            }
            #pragma unroll
            for (int q = 0; q < 8; ++q) {
                if (j + q <= lim) {
                    a0 += __uint_as_float(r[q].x << 16);
                    a1 += __uint_as_float(r[q].x & 0xffff0000u);
                    a2 += __uint_as_float(r[q].y << 16);
                    a3 += __uint_as_float(r[q].y & 0xffff0000u);
                }
            }
        }
    }

    float eps = 1.f + (dir ? eps_u_p[0] : eps_d_p[0]);
    float4 xv = ((const float4*)(x + (size_t)node * H))[l32];   // self term f32
    float h0 = eps * xv.x + a0;
    float h1 = eps * xv.y + a1;
    float h2 = eps * xv.z + a2;
    float h3 = eps * xv.w + a3;
    unsigned short q0 = f2bf(h0), q1 = f2bf(h1), q2 = f2bf(h2), q3 = f2bf(h3);
    int orow = dir * NPAD + node;
    uint2 hv = {((unsigned)q1 << 16) | q0, ((unsigned)q3 << 16) | q2};
    uint2 lv = {((unsigned)f2bf(h1 - bf2f(q1)) << 16) | f2bf(h0 - bf2f(q0)),
                ((unsigned)f2bf(h3 - bf2f(q3)) << 16) | f2bf(h2 - bf2f(q2))};
    ((uint2*)(hhi + (size_t)orow * 64))[l32] = hv;
    ((uint2*)(hlo + (size_t)orow * 64))[l32] = lv;
}

// ---------------------------------------------------------------------------
// batched MLP: per wave 16 rows of one direction.
// ---------------------------------------------------------------------------
__global__ __launch_bounds__(256) void mlp_kernel(
    const unsigned short* __restrict__ hhi, const unsigned short* __restrict__ hlo,
    const unsigned short* __restrict__ w1bT_hi, const unsigned short* __restrict__ w1bT_lo,
    const unsigned short* __restrict__ w2bT_hi, const unsigned short* __restrict__ w2bT_lo,
    const float* __restrict__ dg1, const float* __restrict__ db1,
    const float* __restrict__ ug1, const float* __restrict__ ub1,
    const float* __restrict__ ln1g, const float* __restrict__ ln1b,
    const float* __restrict__ ln2g, const float* __restrict__ ln2b,
    const float* __restrict__ dir_emb,
    unsigned short* __restrict__ hcat)
{
    __shared__ unsigned short plds[4][2][16 * PSTRIDE];

    int w = threadIdx.x >> 6, lane = threadIdx.x & 63;
    int l15 = lane & 15, g = lane >> 4;
    int blk = blockIdx.x;                 // 0..1563
    int dir = (blk >= 782) ? 1 : 0;
    int r0 = (blk - dir * 782) * 64 + w * 16;

    const unsigned short* w1h = w1bT_hi + dir * 4096;
    const unsigned short* w1l = w1bT_lo + dir * 4096;
    const unsigned short* w2h = w2bT_hi + dir * 4096;
    const unsigned short* w2l = w2bT_lo + dir * 4096;

    // ---- stage 1 ----
    size_t hbase = ((size_t)(dir * NPAD + r0 + l15)) * H;
    f32x4 acc1[2];
    acc1[0] = (f32x4){0.f,0.f,0.f,0.f};
    acc1[1] = (f32x4){0.f,0.f,0.f,0.f};
    #pragma unroll
    for (int ks = 0; ks < 4; ++ks) {
        int ko = ks * 32 + g * 8;
        bf16x8 bh = *(const bf16x8*)(hhi + hbase + ko);
        bf16x8 bl = *(const bf16x8*)(hlo + hbase + ko);
        #pragma unroll
        for (int t = 0; t < 2; ++t) {
            bf16x8 ah = *(const bf16x8*)(w1h + (t * 16 + l15) * H + ko);
            bf16x8 al = *(const bf16x8*)(w1l + (t * 16 + l15) * H + ko);
            acc1[t] = __builtin_amdgcn_mfma_f32_16x16x32_bf16(ah, bh, acc1[t], 0, 0, 0);
            acc1[t] = __builtin_amdgcn_mfma_f32_16x16x32_bf16(al, bh, acc1[t], 0, 0, 0);
            acc1[t] = __builtin_amdgcn_mfma_f32_16x16x32_bf16(ah, bl, acc1[t], 0, 0, 0);
        }
    }

    float s = 0.f, s2 = 0.f;
    #pragma unroll
    for (int t = 0; t < 2; ++t)
        #pragma unroll
        for (int r = 0; r < 4; ++r) { float v = acc1[t][r]; s += v; s2 += v * v; }
    s  += __shfl_xor(s, 16);  s  += __shfl_xor(s, 32);
    s2 += __shfl_xor(s2, 16); s2 += __shfl_xor(s2, 32);
    float mean = s * (1.f / 32.f);
    float var  = s2 * (1.f / 32.f) - mean * mean;
    float rs   = rsqrtf(var + 1e-5f);

    const float* g1p = dir ? ug1 : dg1;
    const float* b1p = dir ? ub1 : db1;
    unsigned short* mh = &plds[w][0][0];
    unsigned short* ml = &plds[w][1][0];
    #pragma unroll
    for (int t = 0; t < 2; ++t) {
        float4 gv = *(const float4*)(g1p + t * 16 + g * 4);
        float4 bv = *(const float4*)(b1p + t * 16 + g * 4);
        float p0 = fmaxf((acc1[t][0] - mean) * rs * gv.x + bv.x, 0.f);
        float p1 = fmaxf((acc1[t][1] - mean) * rs * gv.y + bv.y, 0.f);
        float p2 = fmaxf((acc1[t][2] - mean) * rs * gv.z + bv.z, 0.f);
        float p3 = fmaxf((acc1[t][3] - mean) * rs * gv.w + bv.w, 0.f);
        unsigned short q0 = f2bf(p0), q1 = f2bf(p1), q2 = f2bf(p2), q3 = f2bf(p3);
        u16x4 ph = {q0, q1, q2, q3};
        u16x4 pl = {f2bf(p0 - bf2f(q0)), f2bf(p1 - bf2f(q1)),
                    f2bf(p2 - bf2f(q2)), f2bf(p3 - bf2f(q3))};
        int off = l15 * PSTRIDE + t * 16 + g * 4;
        *(u16x4*)(mh + off) = ph;
        *(u16x4*)(ml + off) = pl;
    }

    // ---- stage 2 ----
    bf16x8 pbh = *(const bf16x8*)(mh + l15 * PSTRIDE + g * 8);
    bf16x8 pbl = *(const bf16x8*)(ml + l15 * PSTRIDE + g * 8);

    f32x4 acc2[8];
    #pragma unroll
    for (int t = 0; t < 8; ++t) acc2[t] = (f32x4){0.f,0.f,0.f,0.f};
    #pragma unroll
    for (int t = 0; t < 8; ++t) {
        bf16x8 ah = *(const bf16x8*)(w2h + (t * 16 + l15) * 32 + g * 8);
        bf16x8 al = *(const bf16x8*)(w2l + (t * 16 + l15) * 32 + g * 8);
        acc2[t] = __builtin_amdgcn_mfma_f32_16x16x32_bf16(ah, pbh, acc2[t], 0, 0, 0);
        acc2[t] = __builtin_amdgcn_mfma_f32_16x16x32_bf16(al, pbh, acc2[t], 0, 0, 0);
        acc2[t] = __builtin_amdgcn_mfma_f32_16x16x32_bf16(ah, pbl, acc2[t], 0, 0, 0);
    }

    float av[8][4];
    float u = 0.f, u2 = 0.f;
    #pragma unroll
    for (int t = 0; t < 8; ++t) {
        float4 de = *(const float4*)(dir_emb + dir * H + t * 16 + g * 4);
        av[t][0] = fmaxf(acc2[t][0] + de.x, 0.f);
        av[t][1] = fmaxf(acc2[t][1] + de.y, 0.f);
        av[t][2] = fmaxf(acc2[t][2] + de.z, 0.f);
        av[t][3] = fmaxf(acc2[t][3] + de.w, 0.f);
        #pragma unroll
        for (int r = 0; r < 4; ++r) { u += av[t][r]; u2 += av[t][r] * av[t][r]; }
    }
    u  += __shfl_xor(u, 16);  u  += __shfl_xor(u, 32);
    u2 += __shfl_xor(u2, 16); u2 += __shfl_xor(u2, 32);
    float m2  = u * (1.f / 128.f);
    float v2  = u2 * (1.f / 128.f) - m2 * m2;
    float rs2 = rsqrtf(v2 + 1e-5f);

    const float* lgp = dir ? ln2g : ln1g;
    const float* lbp = dir ? ln2b : ln1b;
    if ((r0 + l15) < N_NODES) {
        unsigned short* orow = hcat + (size_t)(r0 + l15) * 256 + dir * 128;
        #pragma unroll
        for (int t = 0; t < 8; ++t) {
            float4 gv = *(const float4*)(lgp + t * 16 + g * 4);
            float4 bv = *(const float4*)(lbp + t * 16 + g * 4);
            u16x4 o;
            o[0] = f2bf((av[t][0] - m2) * rs2 * gv.x + bv.x);
            o[1] = f2bf((av[t][1] - m2) * rs2 * gv.y + bv.y);
            o[2] = f2bf((av[t][2] - m2) * rs2 * gv.z + bv.z);
            o[3] = f2bf((av[t][3] - m2) * rs2 * gv.w + bv.w);
            *(u16x4*)(orow + t * 16 + g * 4) = o;
        }
    }
}

// ---------------------------------------------------------------------------
// combine: out = hcat @ cw + cb.  Wave owns a 32-col strip (q = gid&3):
// 16 weight frags (hi-only) loaded ONCE into regs, then iterates node-groups
// j + 782k (k=0..3) with double-buffered hcat B-frags.
// ---------------------------------------------------------------------------
__global__ __launch_bounds__(256) void combine_mfma(
    const unsigned short* __restrict__ hcat,
    const unsigned short* __restrict__ cwh,
    const float* __restrict__ cb, float* __restrict__ out)
{
    int w = threadIdx.x >> 6, lane = threadIdx.x & 63;
    int l15 = lane & 15, g = lane >> 4;
    int gid = blockIdx.x * 4 + w;       // 0..3127
    int q = gid & 3;                    // col strip: cols q*32..q*32+31
    int j = gid >> 2;                   // 0..781

    // weights once: A-frag col = q*32 + t*16 + l15, k-chunk g*8
    const unsigned short* abase = cwh + (size_t)(q * 32 + l15) * 256 + g * 8;
    bf16x8 Ah[2][8];
    #pragma unroll
    for (int t = 0; t < 2; ++t)
        #pragma unroll
        for (int ks = 0; ks < 8; ++ks)
            Ah[t][ks] = *(const bf16x8*)(abase + (t * 16) * 256 + ks * 32);

    int grp[4]; int ng = 0;
    #pragma unroll
    for (int k = 0; k < 4; ++k) {
        int gg = j + 782 * k;
        if (gg < NGRP) grp[ng++] = gg;
    }
    if (ng == 0) return;

    bf16x8 Bc[8], Bn[8];
    {
        const unsigned short* bb = hcat + (size_t)grp[0] * 16 * 256 + l15 * 256 + g * 8;
        #pragma unroll
        for (int ks = 0; ks < 8; ++ks) Bc[ks] = *(const bf16x8*)(bb + ks * 32);
    }

    float4 bias0 = *(const float4*)(cb + q * 32 + g * 4);
    float4 bias1 = *(const float4*)(cb + q * 32 + 16 + g * 4);

    for (int i = 0; i < ng; ++i) {
        if (i + 1 < ng) {
            const unsigned short* bb = hcat + (size_t)grp[i + 1] * 16 * 256 + l15 * 256 + g * 8;
            #pragma unroll
            for (int ks = 0; ks < 8; ++ks) Bn[ks] = *(const bf16x8*)(bb + ks * 32);
        }

        f32x4 acc0 = (f32x4){0.f,0.f,0.f,0.f};
        f32x4 acc1 = (f32x4){0.f,0.f,0.f,0.f};
        #pragma unroll
        for (int ks = 0; ks < 8; ++ks) {
            acc0 = __builtin_amdgcn_mfma_f32_16x16x32_bf16(Ah[0][ks], Bc[ks], acc0, 0, 0, 0);
            acc1 = __builtin_amdgcn_mfma_f32_16x16x32_bf16(Ah[1][ks], Bc[ks], acc1, 0, 0, 0);
        }

        float* orow = out + (size_t)(grp[i] * 16 + l15) * 128 + q * 32;
        f32x4 v0 = acc0, v1 = acc1;
        v0[0] += bias0.x; v0[1] += bias0.y; v0[2] += bias0.z; v0[3] += bias0.w;
        v1[0] += bias1.x; v1[1] += bias1.y; v1[2] += bias1.z; v1[3] += bias1.w;
        *(f32x4*)(orow + g * 4) = v0;
        *(f32x4*)(orow + 16 + g * 4) = v1;

        #pragma unroll
        for (int ks = 0; ks < 8; ++ks) Bc[ks] = Bn[ks];
    }
}

// ---------------------------------------------------------------------------
extern "C" void kernel_launch(void* const* d_in, const int* in_sizes, int n_in,
                              void* d_out, int out_size, void* d_ws, size_t ws_size,
                              hipStream_t stream) {
    const float* x     = (const float*)d_in[0];
    const int*   ei    = (const int*)d_in[1];
    const float* eps_d = (const float*)d_in[2];
    const float* dw1   = (const float*)d_in[3];
    const float* dg1   = (const float*)d_in[4];
    const float* db1   = (const float*)d_in[5];
    const float* dw2   = (const float*)d_in[6];
    const float* eps_u = (const float*)d_in[7];
    const float* uw1   = (const float*)d_in[8];
    const float* ug1   = (const float*)d_in[9];
    const float* ub1   = (const float*)d_in[10];
    const float* uw2   = (const float*)d_in[11];
    const float* ln1g  = (const float*)d_in[12];
    const float* ln1b  = (const float*)d_in[13];
    const float* ln2g  = (const float*)d_in[14];
    const float* ln2b  = (const float*)d_in[15];
    const float* dire  = (const float*)d_in[16];
    const float* cw    = (const float*)d_in[17];
    const float* cb    = (const float*)d_in[18];

    int* deg    = (int*)d_ws;                       // 100000
    int* offs   = deg + 2 * N_NODES;                // 100000
    int* cursor = offs + 2 * N_NODES;               // 100000
    int* bsums  = cursor + 2 * N_NODES;             // 128
    int* bucket = bsums + 128;                      // 1,250,000
    unsigned* xb  = (unsigned*)(bucket + TOTAL_DEG);        // N*64
    unsigned* hhi = xb + (size_t)N_NODES * 64;              // 2*NPAD*64
    unsigned* hlo = hhi + (size_t)2 * NPAD * 64;            // 2*NPAD*64
    unsigned short* hcat    = (unsigned short*)(hlo + (size_t)2 * NPAD * 64); // N*256
    unsigned short* w1bT_hi = hcat + (size_t)N_NODES * 256;
    unsigned short* w1bT_lo = w1bT_hi + 8192;
    unsigned short* w2bT_hi = w1bT_lo + 8192;
    unsigned short* w2bT_lo = w2bT_hi + 8192;
    unsigned short* cwbT_hi = w2bT_lo + 8192;

    hipMemsetAsync(deg, 0, 2 * N_NODES * sizeof(int), stream);

    int eblocks = (N_EDGES + 255) / 256;            // 2443
    count_kernel<<<eblocks * NPART, 256, 0, stream>>>(ei, deg);
    scan_a<<<98, 256, 0, stream>>>(deg, offs, bsums);
    scan_b<<<1, 128, 0, stream>>>(bsums);
    scan_c<<<98, 256, 0, stream>>>(offs, cursor, bsums);
    fill_kernel<<<eblocks * NPART, 256, 0, stream>>>(ei, cursor, bucket);

    convert_x<<<12500, 256, 0, stream>>>(x, xb);
    convert_wT<<<16, 256, 0, stream>>>(dw1, w1bT_hi,        w1bT_lo,        128, 32);
    convert_wT<<<16, 256, 0, stream>>>(uw1, w1bT_hi + 4096, w1bT_lo + 4096, 128, 32);
    convert_wT<<<16, 256, 0, stream>>>(dw2, w2bT_hi,        w2bT_lo,        32, 128);
    convert_wT<<<16, 256, 0, stream>>>(uw2, w2bT_hi + 4096, w2bT_lo + 4096, 32, 128);
    convert_cwT<<<128, 256, 0, stream>>>(cw, cwbT_hi);

    gather_kernel<<<12500, 256, 0, stream>>>(x, xb, offs, bucket, hhi, hlo, eps_d, eps_u);

    mlp_kernel<<<1564, 256, 0, stream>>>(
        (const unsigned short*)hhi, (const unsigned short*)hlo,
        w1bT_hi, w1bT_lo, w2bT_hi, w2bT_lo,
        dg1, db1, ug1, ub1, ln1g, ln1b, ln2g, ln2b, dire, hcat);

    combine_mfma<<<782, 256, 0, stream>>>(hcat, cwbT_hi, cb, (float*)d_out);
}

// Round 8
// 264.037 us; speedup vs baseline: 3.0619x; 1.0034x over previous
//
#include <hip/hip_runtime.h>

#define N_NODES 50000
#define N_EDGES 625000
#define H 128
#define B 32
#define TOTAL_DEG (2 * N_EDGES)
#define PSTRIDE 40            // ushorts per stage-2 LDS row
#define LROW 136              // ushorts per h-row in LDS (272 B: conflict-free)
#define NPART 8
#define ROWS_PER_PART (2 * N_NODES / NPART)   // 12500
#define NGRP 3125             // node groups of 16 (exact: 3125*16 = 50000)

using bf16x8  = __attribute__((ext_vector_type(8))) short;
using f32x4   = __attribute__((ext_vector_type(4))) float;
using u16x4   = __attribute__((ext_vector_type(4))) unsigned short;

static __device__ __forceinline__ unsigned short f2bf(float f) {
    unsigned u = __float_as_uint(f);
    unsigned r = (u + 0x7fff + ((u >> 16) & 1)) >> 16;   // RNE
    return (unsigned short)r;
}
static __device__ __forceinline__ float bf2f(unsigned short h) {
    return __uint_as_float(((unsigned)h) << 16);
}

// ---------------------------------------------------------------------------
// count degrees, XCD-partitioned: block b -> partition p=b&7 of row space.
// ---------------------------------------------------------------------------
__global__ __launch_bounds__(256) void count_kernel(
    const int* __restrict__ ei, int* __restrict__ deg)
{
    int p  = blockIdx.x & 7;
    int eb = blockIdx.x >> 3;
    int e = eb * 256 + threadIdx.x;
    if (e >= N_EDGES) return;
    int lo = p * ROWS_PER_PART, hi = lo + ROWS_PER_PART;
    int s = ei[e];
    int d = ei[N_EDGES + e];
    int r2 = N_NODES + s;
    if (d >= lo && d < hi)  atomicAdd(&deg[d], 1);
    if (r2 >= lo && r2 < hi) atomicAdd(&deg[r2], 1);
}

// ---------------------------------------------------------------------------
// hierarchical exclusive scan (100000 elems)
// ---------------------------------------------------------------------------
__global__ __launch_bounds__(256) void scan_a(
    const int* __restrict__ deg, int* __restrict__ offs, int* __restrict__ bsums)
{
    __shared__ int lds[256];
    int tid = threadIdx.x;
    int base = blockIdx.x * 1024 + tid * 4;
    int v[4]; int tsum = 0;
    #pragma unroll
    for (int q = 0; q < 4; ++q) {
        v[q] = (base + q < 2 * N_NODES) ? deg[base + q] : 0;
        tsum += v[q];
    }
    lds[tid] = tsum;
    __syncthreads();
    #pragma unroll
    for (int off = 1; off < 256; off <<= 1) {
        int t = (tid >= off) ? lds[tid - off] : 0;
        __syncthreads();
        lds[tid] += t;
        __syncthreads();
    }
    int excl = lds[tid] - tsum;
    if (tid == 255) bsums[blockIdx.x] = lds[tid];
    int run = excl;
    #pragma unroll
    for (int q = 0; q < 4; ++q) {
        if (base + q < 2 * N_NODES) offs[base + q] = run;
        run += v[q];
    }
}

__global__ __launch_bounds__(128) void scan_b(int* __restrict__ bsums)
{
    __shared__ int lds[128];
    int tid = threadIdx.x;
    int v = (tid < 98) ? bsums[tid] : 0;
    lds[tid] = v;
    __syncthreads();
    #pragma unroll
    for (int off = 1; off < 128; off <<= 1) {
        int t = (tid >= off) ? lds[tid - off] : 0;
        __syncthreads();
        lds[tid] += t;
        __syncthreads();
    }
    if (tid < 98) bsums[tid] = lds[tid] - v;
}

__global__ __launch_bounds__(256) void scan_c(
    int* __restrict__ offs, int* __restrict__ cursor, const int* __restrict__ bsums)
{
    int add = bsums[blockIdx.x];
    int base = blockIdx.x * 1024 + threadIdx.x * 4;
    #pragma unroll
    for (int q = 0; q < 4; ++q) {
        int i = base + q;
        if (i < 2 * N_NODES) {
            int o = offs[i] + add;
            offs[i] = o;
            cursor[i] = o;
        }
    }
}

// ---------------------------------------------------------------------------
// fill CSR buckets, XCD-partitioned like count.
// ---------------------------------------------------------------------------
__global__ __launch_bounds__(256) void fill_kernel(
    const int* __restrict__ ei, int* __restrict__ cursor, int* __restrict__ bucket)
{
    int p  = blockIdx.x & 7;
    int eb = blockIdx.x >> 3;
    int e = eb * 256 + threadIdx.x;
    if (e >= N_EDGES) return;
    int lo = p * ROWS_PER_PART, hi = lo + ROWS_PER_PART;
    int s = ei[e];
    int d = ei[N_EDGES + e];
    int r2 = N_NODES + s;
    if (d >= lo && d < hi) {
        int pos = atomicAdd(&cursor[d], 1);
        bucket[pos] = s;
    }
    if (r2 >= lo && r2 < hi) {
        int pos = atomicAdd(&cursor[r2], 1);
        bucket[pos] = d;
    }
}

// ---------------------------------------------------------------------------
// convert_all: blocks [0,12500) -> x->xb bf16; rest -> all weight transposes
// w1 hi/lo [dir][32][128], w2 hi/lo [dir][128][32], cw hi [128][256]
// ---------------------------------------------------------------------------
__global__ __launch_bounds__(256) void convert_all(
    const float* __restrict__ x, unsigned* __restrict__ xb,
    const float* __restrict__ dw1, const float* __restrict__ uw1,
    const float* __restrict__ dw2, const float* __restrict__ uw2,
    const float* __restrict__ cw,
    unsigned short* __restrict__ w1h, unsigned short* __restrict__ w1l,
    unsigned short* __restrict__ w2h, unsigned short* __restrict__ w2l,
    unsigned short* __restrict__ cwh)
{
    int b = blockIdx.x;
    if (b < 12500) {
        int i = b * 256 + threadIdx.x;          // 3,200,000 exact
        float2 v = ((const float2*)x)[i];
        xb[i] = ((unsigned)f2bf(v.y) << 16) | f2bf(v.x);
        return;
    }
    int i = (b - 12500) * 256 + threadIdx.x;    // 0..49151
    if (i < 8192) {                             // w1, two dirs, src [128][32]
        int j = i & 4095;
        int c = j >> 7, k = j & 127;
        const float* src = (i >> 12) ? uw1 : dw1;
        float v = src[k * 32 + c];
        unsigned short h = f2bf(v);
        w1h[i] = h; w1l[i] = f2bf(v - bf2f(h));
    } else if (i < 16384) {                     // w2, two dirs, src [32][128]
        int j = i - 8192;
        int jj = j & 4095;
        int c = jj >> 5, k = jj & 31;
        const float* src = (j >> 12) ? uw2 : dw2;
        float v = src[k * 128 + c];
        unsigned short h = f2bf(v);
        w2h[j] = h; w2l[j] = f2bf(v - bf2f(h));
    } else {                                    // cw hi only, src [256][128]
        int j = i - 16384;
        int c = j >> 8, k = j & 255;
        cwh[j] = f2bf(cw[k * 128 + c]);
    }
}

// ---------------------------------------------------------------------------
// FUSED gather + MLP.  Block = 64 rows of one direction (grid 1564, 256 thr).
// Phase 1: 8 groups (32 lanes) gather 8 rows each -> h hi/lo bf16 in LDS.
// Phase 2: each of 4 waves runs the 16-row MFMA MLP from LDS -> hcat.
// ---------------------------------------------------------------------------
__global__ __launch_bounds__(256) void gather_mlp_kernel(
    const float* __restrict__ x, const unsigned* __restrict__ xb,
    const int* __restrict__ offs, const int* __restrict__ bucket,
    const float* __restrict__ eps_d_p, const float* __restrict__ eps_u_p,
    const unsigned short* __restrict__ w1bT_hi, const unsigned short* __restrict__ w1bT_lo,
    const unsigned short* __restrict__ w2bT_hi, const unsigned short* __restrict__ w2bT_lo,
    const float* __restrict__ dg1, const float* __restrict__ db1,
    const float* __restrict__ ug1, const float* __restrict__ ub1,
    const float* __restrict__ ln1g, const float* __restrict__ ln1b,
    const float* __restrict__ ln2g, const float* __restrict__ ln2b,
    const float* __restrict__ dir_emb,
    unsigned short* __restrict__ hcat)
{
    __shared__ unsigned short hi_lds[64 * LROW];
    __shared__ unsigned short lo_lds[64 * LROW];
    __shared__ unsigned short plds[4][2][16 * PSTRIDE];

    int w = threadIdx.x >> 6, lane = threadIdx.x & 63;
    int half = lane >> 5, l32 = lane & 31;
    int grp = w * 2 + half;                     // 0..7
    int blk = blockIdx.x;                       // 0..1563
    int dir = (blk >= 782) ? 1 : 0;
    int r0 = (blk - dir * 782) * 64;            // node base for this block

    float eps = 1.f + (dir ? eps_u_p[0] : eps_d_p[0]);

    // ---- phase 1: gather 8 rows per group ----
    for (int rr = 0; rr < 8; ++rr) {
        int lrow = grp * 8 + rr;
        int node = r0 + lrow;
        float a0 = 0.f, a1 = 0.f, a2 = 0.f, a3 = 0.f;
        float h0 = 0.f, h1 = 0.f, h2 = 0.f, h3 = 0.f;
        if (node < N_NODES) {
            int ridx = dir * N_NODES + node;
            int s0 = offs[ridx];
            int e0 = (ridx == 2 * N_NODES - 1) ? TOTAL_DEG : offs[ridx + 1];
            for (int base = s0; base < e0; base += 32) {
                int m = e0 - base; if (m > 32) m = 32;
                int id = (l32 < m) ? bucket[base + l32] : 0;
                int lim = m - 1;
                for (int j = 0; j < m; j += 8) {
                    uint2 r[8];
                    #pragma unroll
                    for (int q = 0; q < 8; ++q) {
                        int idx = j + q; if (idx > lim) idx = lim;
                        int nb = __shfl(id, (half << 5) + idx);
                        r[q] = ((const uint2*)(xb + nb * 64))[l32];
                    }
                    #pragma unroll
                    for (int q = 0; q < 8; ++q) {
                        if (j + q <= lim) {
                            a0 += __uint_as_float(r[q].x << 16);
                            a1 += __uint_as_float(r[q].x & 0xffff0000u);
                            a2 += __uint_as_float(r[q].y << 16);
                            a3 += __uint_as_float(r[q].y & 0xffff0000u);
                        }
                    }
                }
            }
            float4 xv = ((const float4*)(x + (size_t)node * H))[l32];
            h0 = eps * xv.x + a0;
            h1 = eps * xv.y + a1;
            h2 = eps * xv.z + a2;
            h3 = eps * xv.w + a3;
        }
        unsigned short q0 = f2bf(h0), q1 = f2bf(h1), q2 = f2bf(h2), q3 = f2bf(h3);
        u16x4 hv = {q0, q1, q2, q3};
        u16x4 lv = {f2bf(h0 - bf2f(q0)), f2bf(h1 - bf2f(q1)),
                    f2bf(h2 - bf2f(q2)), f2bf(h3 - bf2f(q3))};
        *(u16x4*)(hi_lds + lrow * LROW + 4 * l32) = hv;
        *(u16x4*)(lo_lds + lrow * LROW + 4 * l32) = lv;
    }
    __syncthreads();

    // ---- phase 2: per-wave 16-row MFMA MLP ----
    int l15 = lane & 15, g = lane >> 4;
    int rw = r0 + w * 16;                        // this wave's node base

    const unsigned short* w1h = w1bT_hi + dir * 4096;
    const unsigned short* w1l = w1bT_lo + dir * 4096;
    const unsigned short* w2h = w2bT_hi + dir * 4096;
    const unsigned short* w2l = w2bT_lo + dir * 4096;

    const unsigned short* hrow_hi = hi_lds + (w * 16 + l15) * LROW;
    const unsigned short* hrow_lo = lo_lds + (w * 16 + l15) * LROW;

    // stage 1: C1 = h @ w1 (transposed operands)
    f32x4 acc1[2];
    acc1[0] = (f32x4){0.f,0.f,0.f,0.f};
    acc1[1] = (f32x4){0.f,0.f,0.f,0.f};
    #pragma unroll
    for (int ks = 0; ks < 4; ++ks) {
        int ko = ks * 32 + g * 8;
        bf16x8 bh = *(const bf16x8*)(hrow_hi + ko);
        bf16x8 bl = *(const bf16x8*)(hrow_lo + ko);
        #pragma unroll
        for (int t = 0; t < 2; ++t) {
            bf16x8 ah = *(const bf16x8*)(w1h + (t * 16 + l15) * H + ko);
            bf16x8 al = *(const bf16x8*)(w1l + (t * 16 + l15) * H + ko);
            acc1[t] = __builtin_amdgcn_mfma_f32_16x16x32_bf16(ah, bh, acc1[t], 0, 0, 0);
            acc1[t] = __builtin_amdgcn_mfma_f32_16x16x32_bf16(al, bh, acc1[t], 0, 0, 0);
            acc1[t] = __builtin_amdgcn_mfma_f32_16x16x32_bf16(ah, bl, acc1[t], 0, 0, 0);
        }
    }

    float s = 0.f, s2 = 0.f;
    #pragma unroll
    for (int t = 0; t < 2; ++t)
        #pragma unroll
        for (int r = 0; r < 4; ++r) { float v = acc1[t][r]; s += v; s2 += v * v; }
    s  += __shfl_xor(s, 16);  s  += __shfl_xor(s, 32);
    s2 += __shfl_xor(s2, 16); s2 += __shfl_xor(s2, 32);
    float mean = s * (1.f / 32.f);
    float var  = s2 * (1.f / 32.f) - mean * mean;
    float rs   = rsqrtf(var + 1e-5f);

    const float* g1p = dir ? ug1 : dg1;
    const float* b1p = dir ? ub1 : db1;
    unsigned short* mh = &plds[w][0][0];
    unsigned short* ml = &plds[w][1][0];
    #pragma unroll
    for (int t = 0; t < 2; ++t) {
        float4 gv = *(const float4*)(g1p + t * 16 + g * 4);
        float4 bv = *(const float4*)(b1p + t * 16 + g * 4);
        float p0 = fmaxf((acc1[t][0] - mean) * rs * gv.x + bv.x, 0.f);
        float p1 = fmaxf((acc1[t][1] - mean) * rs * gv.y + bv.y, 0.f);
        float p2 = fmaxf((acc1[t][2] - mean) * rs * gv.z + bv.z, 0.f);
        float p3 = fmaxf((acc1[t][3] - mean) * rs * gv.w + bv.w, 0.f);
        unsigned short q0 = f2bf(p0), q1 = f2bf(p1), q2 = f2bf(p2), q3 = f2bf(p3);
        u16x4 ph = {q0, q1, q2, q3};
        u16x4 pl = {f2bf(p0 - bf2f(q0)), f2bf(p1 - bf2f(q1)),
                    f2bf(p2 - bf2f(q2)), f2bf(p3 - bf2f(q3))};
        int off = l15 * PSTRIDE + t * 16 + g * 4;
        *(u16x4*)(mh + off) = ph;
        *(u16x4*)(ml + off) = pl;
    }

    // stage 2
    bf16x8 pbh = *(const bf16x8*)(mh + l15 * PSTRIDE + g * 8);
    bf16x8 pbl = *(const bf16x8*)(ml + l15 * PSTRIDE + g * 8);

    f32x4 acc2[8];
    #pragma unroll
    for (int t = 0; t < 8; ++t) acc2[t] = (f32x4){0.f,0.f,0.f,0.f};
    #pragma unroll
    for (int t = 0; t < 8; ++t) {
        bf16x8 ah = *(const bf16x8*)(w2h + (t * 16 + l15) * 32 + g * 8);
        bf16x8 al = *(const bf16x8*)(w2l + (t * 16 + l15) * 32 + g * 8);
        acc2[t] = __builtin_amdgcn_mfma_f32_16x16x32_bf16(ah, pbh, acc2[t], 0, 0, 0);
        acc2[t] = __builtin_amdgcn_mfma_f32_16x16x32_bf16(al, pbh, acc2[t], 0, 0, 0);
        acc2[t] = __builtin_amdgcn_mfma_f32_16x16x32_bf16(ah, pbl, acc2[t], 0, 0, 0);
    }

    float av[8][4];
    float u = 0.f, u2 = 0.f;
    #pragma unroll
    for (int t = 0; t < 8; ++t) {
        float4 de = *(const float4*)(dir_emb + dir * H + t * 16 + g * 4);
        av[t][0] = fmaxf(acc2[t][0] + de.x, 0.f);
        av[t][1] = fmaxf(acc2[t][1] + de.y, 0.f);
        av[t][2] = fmaxf(acc2[t][2] + de.z, 0.f);
        av[t][3] = fmaxf(acc2[t][3] + de.w, 0.f);
        #pragma unroll
        for (int r = 0; r < 4; ++r) { u += av[t][r]; u2 += av[t][r] * av[t][r]; }
    }
    u  += __shfl_xor(u, 16);  u  += __shfl_xor(u, 32);
    u2 += __shfl_xor(u2, 16); u2 += __shfl_xor(u2, 32);
    float m2  = u * (1.f / 128.f);
    float v2  = u2 * (1.f / 128.f) - m2 * m2;
    float rs2 = rsqrtf(v2 + 1e-5f);

    const float* lgp = dir ? ln2g : ln1g;
    const float* lbp = dir ? ln2b : ln1b;
    if ((rw + l15) < N_NODES) {
        unsigned short* orow = hcat + (size_t)(rw + l15) * 256 + dir * 128;
        #pragma unroll
        for (int t = 0; t < 8; ++t) {
            float4 gv = *(const float4*)(lgp + t * 16 + g * 4);
            float4 bv = *(const float4*)(lbp + t * 16 + g * 4);
            u16x4 o;
            o[0] = f2bf((av[t][0] - m2) * rs2 * gv.x + bv.x);
            o[1] = f2bf((av[t][1] - m2) * rs2 * gv.y + bv.y);
            o[2] = f2bf((av[t][2] - m2) * rs2 * gv.z + bv.z);
            o[3] = f2bf((av[t][3] - m2) * rs2 * gv.w + bv.w);
            *(u16x4*)(orow + t * 16 + g * 4) = o;
        }
    }
}

// ---------------------------------------------------------------------------
// combine: out = hcat @ cw + cb.  Wave owns a 32-col strip, weights in regs,
// iterates 4 node-groups with double-buffered B-frags.
// ---------------------------------------------------------------------------
__global__ __launch_bounds__(256) void combine_mfma(
    const unsigned short* __restrict__ hcat,
    const unsigned short* __restrict__ cwh,
    const float* __restrict__ cb, float* __restrict__ out)
{
    int w = threadIdx.x >> 6, lane = threadIdx.x & 63;
    int l15 = lane & 15, g = lane >> 4;
    int gid = blockIdx.x * 4 + w;       // 0..3127
    int q = gid & 3;                    // col strip: cols q*32..q*32+31
    int j = gid >> 2;                   // 0..781

    const unsigned short* abase = cwh + (size_t)(q * 32 + l15) * 256 + g * 8;
    bf16x8 Ah[2][8];
    #pragma unroll
    for (int t = 0; t < 2; ++t)
        #pragma unroll
        for (int ks = 0; ks < 8; ++ks)
            Ah[t][ks] = *(const bf16x8*)(abase + (t * 16) * 256 + ks * 32);

    int grp[4]; int ng = 0;
    #pragma unroll
    for (int k = 0; k < 4; ++k) {
        int gg = j + 782 * k;
        if (gg < NGRP) grp[ng++] = gg;
    }
    if (ng == 0) return;

    bf16x8 Bc[8], Bn[8];
    {
        const unsigned short* bb = hcat + (size_t)grp[0] * 16 * 256 + l15 * 256 + g * 8;
        #pragma unroll
        for (int ks = 0; ks < 8; ++ks) Bc[ks] = *(const bf16x8*)(bb + ks * 32);
    }

    float4 bias0 = *(const float4*)(cb + q * 32 + g * 4);
    float4 bias1 = *(const float4*)(cb + q * 32 + 16 + g * 4);

    for (int i = 0; i < ng; ++i) {
        if (i + 1 < ng) {
            const unsigned short* bb = hcat + (size_t)grp[i + 1] * 16 * 256 + l15 * 256 + g * 8;
            #pragma unroll
            for (int ks = 0; ks < 8; ++ks) Bn[ks] = *(const bf16x8*)(bb + ks * 32);
        }

        f32x4 acc0 = (f32x4){0.f,0.f,0.f,0.f};
        f32x4 acc1 = (f32x4){0.f,0.f,0.f,0.f};
        #pragma unroll
        for (int ks = 0; ks < 8; ++ks) {
            acc0 = __builtin_amdgcn_mfma_f32_16x16x32_bf16(Ah[0][ks], Bc[ks], acc0, 0, 0, 0);
            acc1 = __builtin_amdgcn_mfma_f32_16x16x32_bf16(Ah[1][ks], Bc[ks], acc1, 0, 0, 0);
        }

        float* orow = out + (size_t)(grp[i] * 16 + l15) * 128 + q * 32;
        f32x4 v0 = acc0, v1 = acc1;
        v0[0] += bias0.x; v0[1] += bias0.y; v0[2] += bias0.z; v0[3] += bias0.w;
        v1[0] += bias1.x; v1[1] += bias1.y; v1[2] += bias1.z; v1[3] += bias1.w;
        *(f32x4*)(orow + g * 4) = v0;
        *(f32x4*)(orow + 16 + g * 4) = v1;

        #pragma unroll
        for (int ks = 0; ks < 8; ++ks) Bc[ks] = Bn[ks];
    }
}

// ---------------------------------------------------------------------------
extern "C" void kernel_launch(void* const* d_in, const int* in_sizes, int n_in,
                              void* d_out, int out_size, void* d_ws, size_t ws_size,
                              hipStream_t stream) {
    const float* x     = (const float*)d_in[0];
    const int*   ei    = (const int*)d_in[1];
    const float* eps_d = (const float*)d_in[2];
    const float* dw1   = (const float*)d_in[3];
    const float* dg1   = (const float*)d_in[4];
    const float* db1   = (const float*)d_in[5];
    const float* dw2   = (const float*)d_in[6];
    const float* eps_u = (const float*)d_in[7];
    const float* uw1   = (const float*)d_in[8];
    const float* ug1   = (const float*)d_in[9];
    const float* ub1   = (const float*)d_in[10];
    const float* uw2   = (const float*)d_in[11];
    const float* ln1g  = (const float*)d_in[12];
    const float* ln1b  = (const float*)d_in[13];
    const float* ln2g  = (const float*)d_in[14];
    const float* ln2b  = (const float*)d_in[15];
    const float* dire  = (const float*)d_in[16];
    const float* cw    = (const float*)d_in[17];
    const float* cb    = (const float*)d_in[18];

    int* deg    = (int*)d_ws;                       // 100000
    int* offs   = deg + 2 * N_NODES;                // 100000
    int* cursor = offs + 2 * N_NODES;               // 100000
    int* bsums  = cursor + 2 * N_NODES;             // 128
    int* bucket = bsums + 128;                      // 1,250,000
    unsigned* xb  = (unsigned*)(bucket + TOTAL_DEG);        // N*64
    unsigned short* hcat    = (unsigned short*)(xb + (size_t)N_NODES * 64); // N*256
    unsigned short* w1bT_hi = hcat + (size_t)N_NODES * 256;
    unsigned short* w1bT_lo = w1bT_hi + 8192;
    unsigned short* w2bT_hi = w1bT_lo + 8192;
    unsigned short* w2bT_lo = w2bT_hi + 8192;
    unsigned short* cwbT_hi = w2bT_lo + 8192;

    hipMemsetAsync(deg, 0, 2 * N_NODES * sizeof(int), stream);

    int eblocks = (N_EDGES + 255) / 256;            // 2443
    count_kernel<<<eblocks * NPART, 256, 0, stream>>>(ei, deg);
    scan_a<<<98, 256, 0, stream>>>(deg, offs, bsums);
    scan_b<<<1, 128, 0, stream>>>(bsums);
    scan_c<<<98, 256, 0, stream>>>(offs, cursor, bsums);
    fill_kernel<<<eblocks * NPART, 256, 0, stream>>>(ei, cursor, bucket);

    convert_all<<<12500 + 192, 256, 0, stream>>>(
        x, xb, dw1, uw1, dw2, uw2, cw,
        w1bT_hi, w1bT_lo, w2bT_hi, w2bT_lo, cwbT_hi);

    gather_mlp_kernel<<<1564, 256, 0, stream>>>(
        x, xb, offs, bucket, eps_d, eps_u,
        w1bT_hi, w1bT_lo, w2bT_hi, w2bT_lo,
        dg1, db1, ug1, ub1, ln1g, ln1b, ln2g, ln2b, dire, hcat);

    combine_mfma<<<782, 256, 0, stream>>>(hcat, cwbT_hi, cb, (float*)d_out);
}

// Round 9
// 181.572 us; speedup vs baseline: 4.4526x; 1.4542x over previous
//
#include <hip/hip_runtime.h>

#define N_NODES 50000
#define N_EDGES 625000
#define H 128
#define B 32
#define TOTAL_DEG (2 * N_EDGES)
#define PSTRIDE 40            // ushorts per stage-2 P row (aliased into lo_lds)
#define LROW 140              // ushorts per h-row in LDS (280 B: 6-bank row stride)
#define CAP 64                // bucket capacity per (node,dir); P(overflow) ~ 1e-24
#define NPART 8
#define ROWS_PER_PART (2 * N_NODES / NPART)   // 12500
#define NGRP 3125             // node groups of 16 (exact: 3125*16 = 50000)

using bf16x8  = __attribute__((ext_vector_type(8))) short;
using f32x4   = __attribute__((ext_vector_type(4))) float;
using u16x4   = __attribute__((ext_vector_type(4))) unsigned short;

static __device__ __forceinline__ unsigned short f2bf(float f) {
    unsigned u = __float_as_uint(f);
    unsigned r = (u + 0x7fff + ((u >> 16) & 1)) >> 16;   // RNE
    return (unsigned short)r;
}
static __device__ __forceinline__ float bf2f(unsigned short h) {
    return __uint_as_float(((unsigned)h) << 16);
}

// ---------------------------------------------------------------------------
// fill: direct-bucket CSR build, XCD-partitioned (block b -> partition b&7).
// cursor doubles as the degree counter; no count/scan needed.
// ---------------------------------------------------------------------------
__global__ __launch_bounds__(256) void fill_kernel(
    const int* __restrict__ ei, int* __restrict__ cursor, int* __restrict__ bucket)
{
    int p  = blockIdx.x & 7;
    int eb = blockIdx.x >> 3;
    int e = eb * 256 + threadIdx.x;
    if (e >= N_EDGES) return;
    int lo = p * ROWS_PER_PART, hi = lo + ROWS_PER_PART;
    int s = ei[e];
    int d = ei[N_EDGES + e];
    int r2 = N_NODES + s;
    if (d >= lo && d < hi) {
        int pos = atomicAdd(&cursor[d], 1);
        if (pos < CAP) bucket[(size_t)d * CAP + pos] = s;
    }
    if (r2 >= lo && r2 < hi) {
        int pos = atomicAdd(&cursor[r2], 1);
        if (pos < CAP) bucket[(size_t)r2 * CAP + pos] = d;
    }
}

// ---------------------------------------------------------------------------
// convert_all: blocks [0,12500) -> x->xb bf16; rest -> all weight transposes
// ---------------------------------------------------------------------------
__global__ __launch_bounds__(256) void convert_all(
    const float* __restrict__ x, unsigned* __restrict__ xb,
    const float* __restrict__ dw1, const float* __restrict__ uw1,
    const float* __restrict__ dw2, const float* __restrict__ uw2,
    const float* __restrict__ cw,
    unsigned short* __restrict__ w1h, unsigned short* __restrict__ w1l,
    unsigned short* __restrict__ w2h, unsigned short* __restrict__ w2l,
    unsigned short* __restrict__ cwh)
{
    int b = blockIdx.x;
    if (b < 12500) {
        int i = b * 256 + threadIdx.x;          // 3,200,000 exact
        float2 v = ((const float2*)x)[i];
        xb[i] = ((unsigned)f2bf(v.y) << 16) | f2bf(v.x);
        return;
    }
    int i = (b - 12500) * 256 + threadIdx.x;    // 0..49151
    if (i < 8192) {                             // w1, two dirs, src [128][32]
        int j = i & 4095;
        int c = j >> 7, k = j & 127;
        const float* src = (i >> 12) ? uw1 : dw1;
        float v = src[k * 32 + c];
        unsigned short h = f2bf(v);
        w1h[i] = h; w1l[i] = f2bf(v - bf2f(h));
    } else if (i < 16384) {                     // w2, two dirs, src [32][128]
        int j = i - 8192;
        int jj = j & 4095;
        int c = jj >> 5, k = jj & 31;
        const float* src = (j >> 12) ? uw2 : dw2;
        float v = src[k * 128 + c];
        unsigned short h = f2bf(v);
        w2h[j] = h; w2l[j] = f2bf(v - bf2f(h));
    } else {                                    // cw hi only, src [256][128]
        int j = i - 16384;
        int c = j >> 8, k = j & 255;
        cwh[j] = f2bf(cw[k * 128 + c]);
    }
}

// ---------------------------------------------------------------------------
// FUSED gather + MLP.  Block = 64 rows of one direction (grid 1564, 256 thr).
// Phase 1: 8 groups (32 lanes) gather 8 rows each -> h hi/lo bf16 in LDS.
// Phase 2: each of 4 waves runs the 16-row MFMA MLP from LDS -> hcat.
// LDS 35 KB (plds aliased into the wave's own dead lo_lds region) -> 4 blk/CU.
// ---------------------------------------------------------------------------
__global__ __launch_bounds__(256) void gather_mlp_kernel(
    const float* __restrict__ x, const unsigned* __restrict__ xb,
    const int* __restrict__ cursor, const int* __restrict__ bucket,
    const float* __restrict__ eps_d_p, const float* __restrict__ eps_u_p,
    const unsigned short* __restrict__ w1bT_hi, const unsigned short* __restrict__ w1bT_lo,
    const unsigned short* __restrict__ w2bT_hi, const unsigned short* __restrict__ w2bT_lo,
    const float* __restrict__ dg1, const float* __restrict__ db1,
    const float* __restrict__ ug1, const float* __restrict__ ub1,
    const float* __restrict__ ln1g, const float* __restrict__ ln1b,
    const float* __restrict__ ln2g, const float* __restrict__ ln2b,
    const float* __restrict__ dir_emb,
    unsigned short* __restrict__ hcat)
{
    __shared__ unsigned short hi_lds[64 * LROW];
    __shared__ unsigned short lo_lds[64 * LROW];

    int w = threadIdx.x >> 6, lane = threadIdx.x & 63;
    int half = lane >> 5, l32 = lane & 31;
    int grp = w * 2 + half;                     // 0..7 (wave w owns rows 16w..16w+15)
    int blk = blockIdx.x;                       // 0..1563
    int dir = (blk >= 782) ? 1 : 0;
    int r0 = (blk - dir * 782) * 64;            // node base for this block

    float eps = 1.f + (dir ? eps_u_p[0] : eps_d_p[0]);

    // ---- phase 1: gather 8 rows per group ----
    for (int rr = 0; rr < 8; ++rr) {
        int lrow = grp * 8 + rr;
        int node = r0 + lrow;
        float a0 = 0.f, a1 = 0.f, a2 = 0.f, a3 = 0.f;
        float h0 = 0.f, h1 = 0.f, h2 = 0.f, h3 = 0.f;
        if (node < N_NODES) {
            int ridx = dir * N_NODES + node;
            int deg = cursor[ridx]; if (deg > CAP) deg = CAP;
            const int* nb = bucket + (size_t)ridx * CAP;
            for (int base = 0; base < deg; base += 32) {
                int m = deg - base; if (m > 32) m = 32;
                int id = (l32 < m) ? nb[base + l32] : 0;
                int lim = m - 1;
                for (int j = 0; j < m; j += 8) {
                    uint2 r[8];
                    #pragma unroll
                    for (int q = 0; q < 8; ++q) {
                        int idx = j + q; if (idx > lim) idx = lim;
                        int nbid = __shfl(id, (half << 5) + idx);
                        r[q] = ((const uint2*)(xb + nbid * 64))[l32];
                    }
                    #pragma unroll
                    for (int q = 0; q < 8; ++q) {
                        if (j + q <= lim) {
                            a0 += __uint_as_float(r[q].x << 16);
                            a1 += __uint_as_float(r[q].x & 0xffff0000u);
                            a2 += __uint_as_float(r[q].y << 16);
                            a3 += __uint_as_float(r[q].y & 0xffff0000u);
                        }
                    }
                }
            }
            float4 xv = ((const float4*)(x + (size_t)node * H))[l32];
            h0 = eps * xv.x + a0;
            h1 = eps * xv.y + a1;
            h2 = eps * xv.z + a2;
            h3 = eps * xv.w + a3;
        }
        unsigned short q0 = f2bf(h0), q1 = f2bf(h1), q2 = f2bf(h2), q3 = f2bf(h3);
        u16x4 hv = {q0, q1, q2, q3};
        u16x4 lv = {f2bf(h0 - bf2f(q0)), f2bf(h1 - bf2f(q1)),
                    f2bf(h2 - bf2f(q2)), f2bf(h3 - bf2f(q3))};
        *(u16x4*)(hi_lds + lrow * LROW + 4 * l32) = hv;
        *(u16x4*)(lo_lds + lrow * LROW + 4 * l32) = lv;
    }
    __syncthreads();

    // ---- phase 2: per-wave 16-row MFMA MLP ----
    int l15 = lane & 15, g = lane >> 4;
    int rw = r0 + w * 16;                        // this wave's node base

    const unsigned short* w1h = w1bT_hi + dir * 4096;
    const unsigned short* w1l = w1bT_lo + dir * 4096;
    const unsigned short* w2h = w2bT_hi + dir * 4096;
    const unsigned short* w2l = w2bT_lo + dir * 4096;

    const unsigned short* hrow_hi = hi_lds + (w * 16 + l15) * LROW;
    const unsigned short* hrow_lo = lo_lds + (w * 16 + l15) * LROW;

    // stage 1: C1 = h @ w1 (transposed operands)
    f32x4 acc1[2];
    acc1[0] = (f32x4){0.f,0.f,0.f,0.f};
    acc1[1] = (f32x4){0.f,0.f,0.f,0.f};
    #pragma unroll
    for (int ks = 0; ks < 4; ++ks) {
        int ko = ks * 32 + g * 8;
        bf16x8 bh = *(const bf16x8*)(hrow_hi + ko);
        bf16x8 bl = *(const bf16x8*)(hrow_lo + ko);
        #pragma unroll
        for (int t = 0; t < 2; ++t) {
            bf16x8 ah = *(const bf16x8*)(w1h + (t * 16 + l15) * H + ko);
            bf16x8 al = *(const bf16x8*)(w1l + (t * 16 + l15) * H + ko);
            acc1[t] = __builtin_amdgcn_mfma_f32_16x16x32_bf16(ah, bh, acc1[t], 0, 0, 0);
            acc1[t] = __builtin_amdgcn_mfma_f32_16x16x32_bf16(al, bh, acc1[t], 0, 0, 0);
            acc1[t] = __builtin_amdgcn_mfma_f32_16x16x32_bf16(ah, bl, acc1[t], 0, 0, 0);
        }
    }

    float s = 0.f, s2 = 0.f;
    #pragma unroll
    for (int t = 0; t < 2; ++t)
        #pragma unroll
        for (int r = 0; r < 4; ++r) { float v = acc1[t][r]; s += v; s2 += v * v; }
    s  += __shfl_xor(s, 16);  s  += __shfl_xor(s, 32);
    s2 += __shfl_xor(s2, 16); s2 += __shfl_xor(s2, 32);
    float mean = s * (1.f / 32.f);
    float var  = s2 * (1.f / 32.f) - mean * mean;
    float rs   = rsqrtf(var + 1e-5f);

    // P buffers aliased into this wave's (now dead) lo_lds region
    unsigned short* mh = lo_lds + (w * 16) * LROW;
    unsigned short* ml = mh + 16 * PSTRIDE;

    const float* g1p = dir ? ug1 : dg1;
    const float* b1p = dir ? ub1 : db1;
    #pragma unroll
    for (int t = 0; t < 2; ++t) {
        float4 gv = *(const float4*)(g1p + t * 16 + g * 4);
        float4 bv = *(const float4*)(b1p + t * 16 + g * 4);
        float p0 = fmaxf((acc1[t][0] - mean) * rs * gv.x + bv.x, 0.f);
        float p1 = fmaxf((acc1[t][1] - mean) * rs * gv.y + bv.y, 0.f);
        float p2 = fmaxf((acc1[t][2] - mean) * rs * gv.z + bv.z, 0.f);
        float p3 = fmaxf((acc1[t][3] - mean) * rs * gv.w + bv.w, 0.f);
        unsigned short q0 = f2bf(p0), q1 = f2bf(p1), q2 = f2bf(p2), q3 = f2bf(p3);
        u16x4 ph = {q0, q1, q2, q3};
        u16x4 pl = {f2bf(p0 - bf2f(q0)), f2bf(p1 - bf2f(q1)),
                    f2bf(p2 - bf2f(q2)), f2bf(p3 - bf2f(q3))};
        int off = l15 * PSTRIDE + t * 16 + g * 4;
        *(u16x4*)(mh + off) = ph;
        *(u16x4*)(ml + off) = pl;
    }

    // stage 2
    bf16x8 pbh = *(const bf16x8*)(mh + l15 * PSTRIDE + g * 8);
    bf16x8 pbl = *(const bf16x8*)(ml + l15 * PSTRIDE + g * 8);

    f32x4 acc2[8];
    #pragma unroll
    for (int t = 0; t < 8; ++t) acc2[t] = (f32x4){0.f,0.f,0.f,0.f};
    #pragma unroll
    for (int t = 0; t < 8; ++t) {
        bf16x8 ah = *(const bf16x8*)(w2h + (t * 16 + l15) * 32 + g * 8);
        bf16x8 al = *(const bf16x8*)(w2l + (t * 16 + l15) * 32 + g * 8);
        acc2[t] = __builtin_amdgcn_mfma_f32_16x16x32_bf16(ah, pbh, acc2[t], 0, 0, 0);
        acc2[t] = __builtin_amdgcn_mfma_f32_16x16x32_bf16(al, pbh, acc2[t], 0, 0, 0);
        acc2[t] = __builtin_amdgcn_mfma_f32_16x16x32_bf16(ah, pbl, acc2[t], 0, 0, 0);
    }

    float av[8][4];
    float u = 0.f, u2 = 0.f;
    #pragma unroll
    for (int t = 0; t < 8; ++t) {
        float4 de = *(const float4*)(dir_emb + dir * H + t * 16 + g * 4);
        av[t][0] = fmaxf(acc2[t][0] + de.x, 0.f);
        av[t][1] = fmaxf(acc2[t][1] + de.y, 0.f);
        av[t][2] = fmaxf(acc2[t][2] + de.z, 0.f);
        av[t][3] = fmaxf(acc2[t][3] + de.w, 0.f);
        #pragma unroll
        for (int r = 0; r < 4; ++r) { u += av[t][r]; u2 += av[t][r] * av[t][r]; }
    }
    u  += __shfl_xor(u, 16);  u  += __shfl_xor(u, 32);
    u2 += __shfl_xor(u2, 16); u2 += __shfl_xor(u2, 32);
    float m2  = u * (1.f / 128.f);
    float v2  = u2 * (1.f / 128.f) - m2 * m2;
    float rs2 = rsqrtf(v2 + 1e-5f);

    const float* lgp = dir ? ln2g : ln1g;
    const float* lbp = dir ? ln2b : ln1b;
    if ((rw + l15) < N_NODES) {
        unsigned short* orow = hcat + (size_t)(rw + l15) * 256 + dir * 128;
        #pragma unroll
        for (int t = 0; t < 8; ++t) {
            float4 gv = *(const float4*)(lgp + t * 16 + g * 4);
            float4 bv = *(const float4*)(lbp + t * 16 + g * 4);
            u16x4 o;
            o[0] = f2bf((av[t][0] - m2) * rs2 * gv.x + bv.x);
            o[1] = f2bf((av[t][1] - m2) * rs2 * gv.y + bv.y);
            o[2] = f2bf((av[t][2] - m2) * rs2 * gv.z + bv.z);
            o[3] = f2bf((av[t][3] - m2) * rs2 * gv.w + bv.w);
            *(u16x4*)(orow + t * 16 + g * 4) = o;
        }
    }
}

// ---------------------------------------------------------------------------
// combine: out = hcat @ cw + cb.  Wave owns a 32-col strip, weights in regs,
// iterates 4 node-groups with double-buffered B-frags.
// ---------------------------------------------------------------------------
__global__ __launch_bounds__(256) void combine_mfma(
    const unsigned short* __restrict__ hcat,
    const unsigned short* __restrict__ cwh,
    const float* __restrict__ cb, float* __restrict__ out)
{
    int w = threadIdx.x >> 6, lane = threadIdx.x & 63;
    int l15 = lane & 15, g = lane >> 4;
    int gid = blockIdx.x * 4 + w;       // 0..3127
    int q = gid & 3;                    // col strip: cols q*32..q*32+31
    int j = gid >> 2;                   // 0..781

    const unsigned short* abase = cwh + (size_t)(q * 32 + l15) * 256 + g * 8;
    bf16x8 Ah[2][8];
    #pragma unroll
    for (int t = 0; t < 2; ++t)
        #pragma unroll
        for (int ks = 0; ks < 8; ++ks)
            Ah[t][ks] = *(const bf16x8*)(abase + (t * 16) * 256 + ks * 32);

    int grp[4]; int ng = 0;
    #pragma unroll
    for (int k = 0; k < 4; ++k) {
        int gg = j + 782 * k;
        if (gg < NGRP) grp[ng++] = gg;
    }
    if (ng == 0) return;

    bf16x8 Bc[8], Bn[8];
    {
        const unsigned short* bb = hcat + (size_t)grp[0] * 16 * 256 + l15 * 256 + g * 8;
        #pragma unroll
        for (int ks = 0; ks < 8; ++ks) Bc[ks] = *(const bf16x8*)(bb + ks * 32);
    }

    float4 bias0 = *(const float4*)(cb + q * 32 + g * 4);
    float4 bias1 = *(const float4*)(cb + q * 32 + 16 + g * 4);

    for (int i = 0; i < ng; ++i) {
        if (i + 1 < ng) {
            const unsigned short* bb = hcat + (size_t)grp[i + 1] * 16 * 256 + l15 * 256 + g * 8;
            #pragma unroll
            for (int ks = 0; ks < 8; ++ks) Bn[ks] = *(const bf16x8*)(bb + ks * 32);
        }

        f32x4 acc0 = (f32x4){0.f,0.f,0.f,0.f};
        f32x4 acc1 = (f32x4){0.f,0.f,0.f,0.f};
        #pragma unroll
        for (int ks = 0; ks < 8; ++ks) {
            acc0 = __builtin_amdgcn_mfma_f32_16x16x32_bf16(Ah[0][ks], Bc[ks], acc0, 0, 0, 0);
            acc1 = __builtin_amdgcn_mfma_f32_16x16x32_bf16(Ah[1][ks], Bc[ks], acc1, 0, 0, 0);
        }

        float* orow = out + (size_t)(grp[i] * 16 + l15) * 128 + q * 32;
        f32x4 v0 = acc0, v1 = acc1;
        v0[0] += bias0.x; v0[1] += bias0.y; v0[2] += bias0.z; v0[3] += bias0.w;
        v1[0] += bias1.x; v1[1] += bias1.y; v1[2] += bias1.z; v1[3] += bias1.w;
        *(f32x4*)(orow + g * 4) = v0;
        *(f32x4*)(orow + 16 + g * 4) = v1;

        #pragma unroll
        for (int ks = 0; ks < 8; ++ks) Bc[ks] = Bn[ks];
    }
}

// ---------------------------------------------------------------------------
extern "C" void kernel_launch(void* const* d_in, const int* in_sizes, int n_in,
                              void* d_out, int out_size, void* d_ws, size_t ws_size,
                              hipStream_t stream) {
    const float* x     = (const float*)d_in[0];
    const int*   ei    = (const int*)d_in[1];
    const float* eps_d = (const float*)d_in[2];
    const float* dw1   = (const float*)d_in[3];
    const float* dg1   = (const float*)d_in[4];
    const float* db1   = (const float*)d_in[5];
    const float* dw2   = (const float*)d_in[6];
    const float* eps_u = (const float*)d_in[7];
    const float* uw1   = (const float*)d_in[8];
    const float* ug1   = (const float*)d_in[9];
    const float* ub1   = (const float*)d_in[10];
    const float* uw2   = (const float*)d_in[11];
    const float* ln1g  = (const float*)d_in[12];
    const float* ln1b  = (const float*)d_in[13];
    const float* ln2g  = (const float*)d_in[14];
    const float* ln2b  = (const float*)d_in[15];
    const float* dire  = (const float*)d_in[16];
    const float* cw    = (const float*)d_in[17];
    const float* cb    = (const float*)d_in[18];

    int* cursor = (int*)d_ws;                               // 100000
    int* bucket = cursor + 2 * N_NODES;                     // 100000*64 = 6.4M ints
    unsigned* xb  = (unsigned*)(bucket + (size_t)2 * N_NODES * CAP);   // N*64
    unsigned short* hcat    = (unsigned short*)(xb + (size_t)N_NODES * 64); // N*256
    unsigned short* w1bT_hi = hcat + (size_t)N_NODES * 256;
    unsigned short* w1bT_lo = w1bT_hi + 8192;
    unsigned short* w2bT_hi = w1bT_lo + 8192;
    unsigned short* w2bT_lo = w2bT_hi + 8192;
    unsigned short* cwbT_hi = w2bT_lo + 8192;

    hipMemsetAsync(cursor, 0, 2 * N_NODES * sizeof(int), stream);

    int eblocks = (N_EDGES + 255) / 256;            // 2443
    fill_kernel<<<eblocks * NPART, 256, 0, stream>>>(ei, cursor, bucket);

    convert_all<<<12500 + 192, 256, 0, stream>>>(
        x, xb, dw1, uw1, dw2, uw2, cw,
        w1bT_hi, w1bT_lo, w2bT_hi, w2bT_lo, cwbT_hi);

    gather_mlp_kernel<<<1564, 256, 0, stream>>>(
        x, xb, cursor, bucket, eps_d, eps_u,
        w1bT_hi, w1bT_lo, w2bT_hi, w2bT_lo,
        dg1, db1, ug1, ub1, ln1g, ln1b, ln2g, ln2b, dire, hcat);

    combine_mfma<<<782, 256, 0, stream>>>(hcat, cwbT_hi, cb, (float*)d_out);
}

// Round 10
// 181.545 us; speedup vs baseline: 4.4532x; 1.0001x over previous
//
#include <hip/hip_runtime.h>

#define N_NODES 50000
#define N_EDGES 625000
#define H 128
#define B 32
#define PSTRIDE 40            // ushorts per stage-2 P row (aliased into hi_lds)
#define LROW 140              // ushorts per h-row in LDS (280 B row stride)
#define CAP 64                // bucket capacity per (node,dir); P(overflow) ~ 1e-24
#define NPART 8
#define ROWS_PER_PART (2 * N_NODES / NPART)   // 12500
#define NGRP 3125             // node groups of 16 (exact: 3125*16 = 50000)
#define FILLB (2443 * NPART)  // fill blocks in merged front-end kernel

using bf16x8  = __attribute__((ext_vector_type(8))) short;
using f32x4   = __attribute__((ext_vector_type(4))) float;
using u16x4   = __attribute__((ext_vector_type(4))) unsigned short;

static __device__ __forceinline__ unsigned short f2bf(float f) {
    unsigned u = __float_as_uint(f);
    unsigned r = (u + 0x7fff + ((u >> 16) & 1)) >> 16;   // RNE
    return (unsigned short)r;
}
static __device__ __forceinline__ float bf2f(unsigned short h) {
    return __uint_as_float(((unsigned)h) << 16);
}

// ---------------------------------------------------------------------------
// merged front-end: blocks [0,FILLB) build the direct-bucket CSR
// (XCD-partitioned, cursor doubles as degree); the rest do x->bf16 and
// weight transposes/hi-lo splits.
// ---------------------------------------------------------------------------
__global__ __launch_bounds__(256) void fill_convert_kernel(
    const int* __restrict__ ei, int* __restrict__ cursor, int* __restrict__ bucket,
    const float* __restrict__ x, unsigned* __restrict__ xb,
    const float* __restrict__ dw1, const float* __restrict__ uw1,
    const float* __restrict__ dw2, const float* __restrict__ uw2,
    const float* __restrict__ cw,
    unsigned short* __restrict__ w1h, unsigned short* __restrict__ w1l,
    unsigned short* __restrict__ w2h, unsigned short* __restrict__ w2l,
    unsigned short* __restrict__ cwh)
{
    int b = blockIdx.x;
    if (b < FILLB) {
        int p  = b & 7;
        int eb = b >> 3;
        int e = eb * 256 + threadIdx.x;
        if (e >= N_EDGES) return;
        int lo = p * ROWS_PER_PART, hi = lo + ROWS_PER_PART;
        int s = ei[e];
        int d = ei[N_EDGES + e];
        int r2 = N_NODES + s;
        if (d >= lo && d < hi) {
            int pos = atomicAdd(&cursor[d], 1);
            if (pos < CAP) bucket[(size_t)d * CAP + pos] = s;
        }
        if (r2 >= lo && r2 < hi) {
            int pos = atomicAdd(&cursor[r2], 1);
            if (pos < CAP) bucket[(size_t)r2 * CAP + pos] = d;
        }
        return;
    }
    b -= FILLB;
    if (b < 12500) {
        int i = b * 256 + threadIdx.x;          // 3,200,000 exact
        float2 v = ((const float2*)x)[i];
        xb[i] = ((unsigned)f2bf(v.y) << 16) | f2bf(v.x);
        return;
    }
    int i = (b - 12500) * 256 + threadIdx.x;    // 0..49151
    if (i < 8192) {                             // w1, two dirs, src [128][32]
        int j = i & 4095;
        int c = j >> 7, k = j & 127;
        const float* src = (i >> 12) ? uw1 : dw1;
        float v = src[k * 32 + c];
        unsigned short h = f2bf(v);
        w1h[i] = h; w1l[i] = f2bf(v - bf2f(h));
    } else if (i < 16384) {                     // w2, two dirs, src [32][128]
        int j = i - 8192;
        int jj = j & 4095;
        int c = jj >> 5, k = jj & 31;
        const float* src = (j >> 12) ? uw2 : dw2;
        float v = src[k * 128 + c];
        unsigned short h = f2bf(v);
        w2h[j] = h; w2l[j] = f2bf(v - bf2f(h));
    } else {                                    // cw hi only, src [256][128]
        int j = i - 16384;
        int c = j >> 8, k = j & 255;
        cwh[j] = f2bf(cw[k * 128 + c]);
    }
}

// ---------------------------------------------------------------------------
// FUSED gather + MLP.  Block = 64 rows of one direction (grid 1564, 256 thr).
// Wave w gathers rows 16w..16w+15 (its own MLP rows) -> NO barriers at all.
// h stored bf16 hi-only (17.9 KB LDS -> 8 blocks/CU); w1/w2/P keep hi+lo.
// ---------------------------------------------------------------------------
__global__ __launch_bounds__(256) void gather_mlp_kernel(
    const unsigned* __restrict__ xb,
    const int* __restrict__ cursor, const int* __restrict__ bucket,
    const float* __restrict__ eps_d_p, const float* __restrict__ eps_u_p,
    const unsigned short* __restrict__ w1bT_hi, const unsigned short* __restrict__ w1bT_lo,
    const unsigned short* __restrict__ w2bT_hi, const unsigned short* __restrict__ w2bT_lo,
    const float* __restrict__ dg1, const float* __restrict__ db1,
    const float* __restrict__ ug1, const float* __restrict__ ub1,
    const float* __restrict__ ln1g, const float* __restrict__ ln1b,
    const float* __restrict__ ln2g, const float* __restrict__ ln2b,
    const float* __restrict__ dir_emb,
    unsigned short* __restrict__ hcat)
{
    __shared__ unsigned short hi_lds[64 * LROW];

    int w = threadIdx.x >> 6, lane = threadIdx.x & 63;
    int half = lane >> 5, l32 = lane & 31;
    int blk = blockIdx.x;                       // 0..1563
    int dir = (blk >= 782) ? 1 : 0;
    int r0 = (blk - dir * 782) * 64;            // node base for this block

    float eps = 1.f + (dir ? eps_u_p[0] : eps_d_p[0]);

    // ---- phase 1: each 32-lane half gathers 8 rows (wave owns 16 rows) ----
    for (int rr = 0; rr < 8; ++rr) {
        int lrow = w * 16 + half * 8 + rr;
        int node = r0 + lrow;
        float a0 = 0.f, a1 = 0.f, a2 = 0.f, a3 = 0.f;
        float h0 = 0.f, h1 = 0.f, h2 = 0.f, h3 = 0.f;
        if (node < N_NODES) {
            int ridx = dir * N_NODES + node;
            int deg = cursor[ridx]; if (deg > CAP) deg = CAP;
            const int* nb = bucket + (size_t)ridx * CAP;
            for (int base = 0; base < deg; base += 32) {
                int m = deg - base; if (m > 32) m = 32;
                int id = (l32 < m) ? nb[base + l32] : 0;
                int lim = m - 1;
                for (int j = 0; j < m; j += 8) {
                    uint2 r[8];
                    #pragma unroll
                    for (int q = 0; q < 8; ++q) {
                        int idx = j + q; if (idx > lim) idx = lim;
                        int nbid = __shfl(id, (half << 5) + idx);
                        r[q] = ((const uint2*)(xb + nbid * 64))[l32];
                    }
                    #pragma unroll
                    for (int q = 0; q < 8; ++q) {
                        if (j + q <= lim) {
                            a0 += __uint_as_float(r[q].x << 16);
                            a1 += __uint_as_float(r[q].x & 0xffff0000u);
                            a2 += __uint_as_float(r[q].y << 16);
                            a3 += __uint_as_float(r[q].y & 0xffff0000u);
                        }
                    }
                }
            }
            uint2 xv = ((const uint2*)(xb + node * 64))[l32];   // self term (bf16)
            h0 = eps * __uint_as_float(xv.x << 16) + a0;
            h1 = eps * __uint_as_float(xv.x & 0xffff0000u) + a1;
            h2 = eps * __uint_as_float(xv.y << 16) + a2;
            h3 = eps * __uint_as_float(xv.y & 0xffff0000u) + a3;
        }
        u16x4 hv = {f2bf(h0), f2bf(h1), f2bf(h2), f2bf(h3)};
        *(u16x4*)(hi_lds + lrow * LROW + 4 * l32) = hv;
    }
    // no barrier: wave-private produce/consume

    // ---- phase 2: per-wave 16-row MFMA MLP ----
    int l15 = lane & 15, g = lane >> 4;
    int rw = r0 + w * 16;                        // this wave's node base

    const unsigned short* w1h = w1bT_hi + dir * 4096;
    const unsigned short* w1l = w1bT_lo + dir * 4096;
    const unsigned short* w2h = w2bT_hi + dir * 4096;
    const unsigned short* w2l = w2bT_lo + dir * 4096;

    const unsigned short* hrow_hi = hi_lds + (w * 16 + l15) * LROW;

    // stage 1: C1 = h @ w1 (transposed operands, w1 hi+lo)
    f32x4 acc1[2];
    acc1[0] = (f32x4){0.f,0.f,0.f,0.f};
    acc1[1] = (f32x4){0.f,0.f,0.f,0.f};
    #pragma unroll
    for (int ks = 0; ks < 4; ++ks) {
        int ko = ks * 32 + g * 8;
        bf16x8 bh = *(const bf16x8*)(hrow_hi + ko);
        #pragma unroll
        for (int t = 0; t < 2; ++t) {
            bf16x8 ah = *(const bf16x8*)(w1h + (t * 16 + l15) * H + ko);
            bf16x8 al = *(const bf16x8*)(w1l + (t * 16 + l15) * H + ko);
            acc1[t] = __builtin_amdgcn_mfma_f32_16x16x32_bf16(ah, bh, acc1[t], 0, 0, 0);
            acc1[t] = __builtin_amdgcn_mfma_f32_16x16x32_bf16(al, bh, acc1[t], 0, 0, 0);
        }
    }

    float s = 0.f, s2 = 0.f;
    #pragma unroll
    for (int t = 0; t < 2; ++t)
        #pragma unroll
        for (int r = 0; r < 4; ++r) { float v = acc1[t][r]; s += v; s2 += v * v; }
    s  += __shfl_xor(s, 16);  s  += __shfl_xor(s, 32);
    s2 += __shfl_xor(s2, 16); s2 += __shfl_xor(s2, 32);
    float mean = s * (1.f / 32.f);
    float var  = s2 * (1.f / 32.f) - mean * mean;
    float rs   = rsqrtf(var + 1e-5f);

    // P buffers aliased into this wave's (now dead) hi_lds region
    unsigned short* mh = hi_lds + (w * 16) * LROW;
    unsigned short* ml = mh + 16 * PSTRIDE;

    const float* g1p = dir ? ug1 : dg1;
    const float* b1p = dir ? ub1 : db1;
    #pragma unroll
    for (int t = 0; t < 2; ++t) {
        float4 gv = *(const float4*)(g1p + t * 16 + g * 4);
        float4 bv = *(const float4*)(b1p + t * 16 + g * 4);
        float p0 = fmaxf((acc1[t][0] - mean) * rs * gv.x + bv.x, 0.f);
        float p1 = fmaxf((acc1[t][1] - mean) * rs * gv.y + bv.y, 0.f);
        float p2 = fmaxf((acc1[t][2] - mean) * rs * gv.z + bv.z, 0.f);
        float p3 = fmaxf((acc1[t][3] - mean) * rs * gv.w + bv.w, 0.f);
        unsigned short q0 = f2bf(p0), q1 = f2bf(p1), q2 = f2bf(p2), q3 = f2bf(p3);
        u16x4 ph = {q0, q1, q2, q3};
        u16x4 pl = {f2bf(p0 - bf2f(q0)), f2bf(p1 - bf2f(q1)),
                    f2bf(p2 - bf2f(q2)), f2bf(p3 - bf2f(q3))};
        int off = l15 * PSTRIDE + t * 16 + g * 4;
        *(u16x4*)(mh + off) = ph;
        *(u16x4*)(ml + off) = pl;
    }

    // stage 2
    bf16x8 pbh = *(const bf16x8*)(mh + l15 * PSTRIDE + g * 8);
    bf16x8 pbl = *(const bf16x8*)(ml + l15 * PSTRIDE + g * 8);

    f32x4 acc2[8];
    #pragma unroll
    for (int t = 0; t < 8; ++t) acc2[t] = (f32x4){0.f,0.f,0.f,0.f};
    #pragma unroll
    for (int t = 0; t < 8; ++t) {
        bf16x8 ah = *(const bf16x8*)(w2h + (t * 16 + l15) * 32 + g * 8);
        bf16x8 al = *(const bf16x8*)(w2l + (t * 16 + l15) * 32 + g * 8);
        acc2[t] = __builtin_amdgcn_mfma_f32_16x16x32_bf16(ah, pbh, acc2[t], 0, 0, 0);
        acc2[t] = __builtin_amdgcn_mfma_f32_16x16x32_bf16(al, pbh, acc2[t], 0, 0, 0);
        acc2[t] = __builtin_amdgcn_mfma_f32_16x16x32_bf16(ah, pbl, acc2[t], 0, 0, 0);
    }

    float av[8][4];
    float u = 0.f, u2 = 0.f;
    #pragma unroll
    for (int t = 0; t < 8; ++t) {
        float4 de = *(const float4*)(dir_emb + dir * H + t * 16 + g * 4);
        av[t][0] = fmaxf(acc2[t][0] + de.x, 0.f);
        av[t][1] = fmaxf(acc2[t][1] + de.y, 0.f);
        av[t][2] = fmaxf(acc2[t][2] + de.z, 0.f);
        av[t][3] = fmaxf(acc2[t][3] + de.w, 0.f);
        #pragma unroll
        for (int r = 0; r < 4; ++r) { u += av[t][r]; u2 += av[t][r] * av[t][r]; }
    }
    u  += __shfl_xor(u, 16);  u  += __shfl_xor(u, 32);
    u2 += __shfl_xor(u2, 16); u2 += __shfl_xor(u2, 32);
    float m2  = u * (1.f / 128.f);
    float v2  = u2 * (1.f / 128.f) - m2 * m2;
    float rs2 = rsqrtf(v2 + 1e-5f);

    const float* lgp = dir ? ln2g : ln1g;
    const float* lbp = dir ? ln2b : ln1b;
    if ((rw + l15) < N_NODES) {
        unsigned short* orow = hcat + (size_t)(rw + l15) * 256 + dir * 128;
        #pragma unroll
        for (int t = 0; t < 8; ++t) {
            float4 gv = *(const float4*)(lgp + t * 16 + g * 4);
            float4 bv = *(const float4*)(lbp + t * 16 + g * 4);
            u16x4 o;
            o[0] = f2bf((av[t][0] - m2) * rs2 * gv.x + bv.x);
            o[1] = f2bf((av[t][1] - m2) * rs2 * gv.y + bv.y);
            o[2] = f2bf((av[t][2] - m2) * rs2 * gv.z + bv.z);
            o[3] = f2bf((av[t][3] - m2) * rs2 * gv.w + bv.w);
            *(u16x4*)(orow + t * 16 + g * 4) = o;
        }
    }
}

// ---------------------------------------------------------------------------
// combine: out = hcat @ cw + cb.  Wave owns a 32-col strip, weights in regs,
// iterates 4 node-groups with double-buffered B-frags.
// ---------------------------------------------------------------------------
__global__ __launch_bounds__(256) void combine_mfma(
    const unsigned short* __restrict__ hcat,
    const unsigned short* __restrict__ cwh,
    const float* __restrict__ cb, float* __restrict__ out)
{
    int w = threadIdx.x >> 6, lane = threadIdx.x & 63;
    int l15 = lane & 15, g = lane >> 4;
    int gid = blockIdx.x * 4 + w;       // 0..3127
    int q = gid & 3;                    // col strip: cols q*32..q*32+31
    int j = gid >> 2;                   // 0..781

    const unsigned short* abase = cwh + (size_t)(q * 32 + l15) * 256 + g * 8;
    bf16x8 Ah[2][8];
    #pragma unroll
    for (int t = 0; t < 2; ++t)
        #pragma unroll
        for (int ks = 0; ks < 8; ++ks)
            Ah[t][ks] = *(const bf16x8*)(abase + (t * 16) * 256 + ks * 32);

    int grp[4]; int ng = 0;
    #pragma unroll
    for (int k = 0; k < 4; ++k) {
        int gg = j + 782 * k;
        if (gg < NGRP) grp[ng++] = gg;
    }
    if (ng == 0) return;

    bf16x8 Bc[8], Bn[8];
    {
        const unsigned short* bb = hcat + (size_t)grp[0] * 16 * 256 + l15 * 256 + g * 8;
        #pragma unroll
        for (int ks = 0; ks < 8; ++ks) Bc[ks] = *(const bf16x8*)(bb + ks * 32);
    }

    float4 bias0 = *(const float4*)(cb + q * 32 + g * 4);
    float4 bias1 = *(const float4*)(cb + q * 32 + 16 + g * 4);

    for (int i = 0; i < ng; ++i) {
        if (i + 1 < ng) {
            const unsigned short* bb = hcat + (size_t)grp[i + 1] * 16 * 256 + l15 * 256 + g * 8;
            #pragma unroll
            for (int ks = 0; ks < 8; ++ks) Bn[ks] = *(const bf16x8*)(bb + ks * 32);
        }

        f32x4 acc0 = (f32x4){0.f,0.f,0.f,0.f};
        f32x4 acc1 = (f32x4){0.f,0.f,0.f,0.f};
        #pragma unroll
        for (int ks = 0; ks < 8; ++ks) {
            acc0 = __builtin_amdgcn_mfma_f32_16x16x32_bf16(Ah[0][ks], Bc[ks], acc0, 0, 0, 0);
            acc1 = __builtin_amdgcn_mfma_f32_16x16x32_bf16(Ah[1][ks], Bc[ks], acc1, 0, 0, 0);
        }

        float* orow = out + (size_t)(grp[i] * 16 + l15) * 128 + q * 32;
        f32x4 v0 = acc0, v1 = acc1;
        v0[0] += bias0.x; v0[1] += bias0.y; v0[2] += bias0.z; v0[3] += bias0.w;
        v1[0] += bias1.x; v1[1] += bias1.y; v1[2] += bias1.z; v1[3] += bias1.w;
        *(f32x4*)(orow + g * 4) = v0;
        *(f32x4*)(orow + 16 + g * 4) = v1;

        #pragma unroll
        for (int ks = 0; ks < 8; ++ks) Bc[ks] = Bn[ks];
    }
}

// ---------------------------------------------------------------------------
extern "C" void kernel_launch(void* const* d_in, const int* in_sizes, int n_in,
                              void* d_out, int out_size, void* d_ws, size_t ws_size,
                              hipStream_t stream) {
    const float* x     = (const float*)d_in[0];
    const int*   ei    = (const int*)d_in[1];
    const float* eps_d = (const float*)d_in[2];
    const float* dw1   = (const float*)d_in[3];
    const float* dg1   = (const float*)d_in[4];
    const float* db1   = (const float*)d_in[5];
    const float* dw2   = (const float*)d_in[6];
    const float* eps_u = (const float*)d_in[7];
    const float* uw1   = (const float*)d_in[8];
    const float* ug1   = (const float*)d_in[9];
    const float* ub1   = (const float*)d_in[10];
    const float* uw2   = (const float*)d_in[11];
    const float* ln1g  = (const float*)d_in[12];
    const float* ln1b  = (const float*)d_in[13];
    const float* ln2g  = (const float*)d_in[14];
    const float* ln2b  = (const float*)d_in[15];
    const float* dire  = (const float*)d_in[16];
    const float* cw    = (const float*)d_in[17];
    const float* cb    = (const float*)d_in[18];

    int* cursor = (int*)d_ws;                               // 100000
    int* bucket = cursor + 2 * N_NODES;                     // 100000*64 = 6.4M ints
    unsigned* xb  = (unsigned*)(bucket + (size_t)2 * N_NODES * CAP);   // N*64
    unsigned short* hcat    = (unsigned short*)(xb + (size_t)N_NODES * 64); // N*256
    unsigned short* w1bT_hi = hcat + (size_t)N_NODES * 256;
    unsigned short* w1bT_lo = w1bT_hi + 8192;
    unsigned short* w2bT_hi = w1bT_lo + 8192;
    unsigned short* w2bT_lo = w2bT_hi + 8192;
    unsigned short* cwbT_hi = w2bT_lo + 8192;

    hipMemsetAsync(cursor, 0, 2 * N_NODES * sizeof(int), stream);

    fill_convert_kernel<<<FILLB + 12500 + 192, 256, 0, stream>>>(
        ei, cursor, bucket, x, xb, dw1, uw1, dw2, uw2, cw,
        w1bT_hi, w1bT_lo, w2bT_hi, w2bT_lo, cwbT_hi);

    gather_mlp_kernel<<<1564, 256, 0, stream>>>(
        xb, cursor, bucket, eps_d, eps_u,
        w1bT_hi, w1bT_lo, w2bT_hi, w2bT_lo,
        dg1, db1, ug1, ub1, ln1g, ln1b, ln2g, ln2b, dire, hcat);

    combine_mfma<<<782, 256, 0, stream>>>(hcat, cwbT_hi, cb, (float*)d_out);
}

// Round 11
// 150.399 us; speedup vs baseline: 5.3754x; 1.2071x over previous
//
#include <hip/hip_runtime.h>

#define N_NODES 50000
#define NPAD 50048            // 64*782 padded rows per direction (y array)
#define N_EDGES 625000
#define H 128
#define B 32
#define PSTRIDE 40            // ushorts per stage-2 P row
#define CAP 64                // bucket capacity per (node,dir); P(overflow) ~ 1e-24
#define NPART 8
#define ROWS_PER_PART (2 * N_NODES / NPART)   // 12500
#define NGRP 3125             // node groups of 16 (exact: 3125*16 = 50000)
#define FILLB (2443 * NPART)  // fill blocks in merged front-end kernel

using bf16x8  = __attribute__((ext_vector_type(8))) short;
using f32x4   = __attribute__((ext_vector_type(4))) float;
using u16x4   = __attribute__((ext_vector_type(4))) unsigned short;

static __device__ __forceinline__ unsigned short f2bf(float f) {
    unsigned u = __float_as_uint(f);
    unsigned r = (u + 0x7fff + ((u >> 16) & 1)) >> 16;   // RNE
    return (unsigned short)r;
}
static __device__ __forceinline__ float bf2f(unsigned short h) {
    return __uint_as_float(((unsigned)h) << 16);
}

// ---------------------------------------------------------------------------
// merged front-end: blocks [0,FILLB) build the direct-bucket CSR
// (XCD-partitioned, cursor doubles as degree); the rest do x->bf16 and
// weight transposes/hi-lo splits.
// ---------------------------------------------------------------------------
__global__ __launch_bounds__(256) void fill_convert_kernel(
    const int* __restrict__ ei, int* __restrict__ cursor, int* __restrict__ bucket,
    const float* __restrict__ x, unsigned* __restrict__ xb,
    const float* __restrict__ dw1, const float* __restrict__ uw1,
    const float* __restrict__ dw2, const float* __restrict__ uw2,
    const float* __restrict__ cw,
    unsigned short* __restrict__ w1h, unsigned short* __restrict__ w1l,
    unsigned short* __restrict__ w2h, unsigned short* __restrict__ w2l,
    unsigned short* __restrict__ cwh)
{
    int b = blockIdx.x;
    if (b < FILLB) {
        int p  = b & 7;
        int eb = b >> 3;
        int e = eb * 256 + threadIdx.x;
        if (e >= N_EDGES) return;
        int lo = p * ROWS_PER_PART, hi = lo + ROWS_PER_PART;
        int s = ei[e];
        int d = ei[N_EDGES + e];
        int r2 = N_NODES + s;
        if (d >= lo && d < hi) {
            int pos = atomicAdd(&cursor[d], 1);
            if (pos < CAP) bucket[(size_t)d * CAP + pos] = s;
        }
        if (r2 >= lo && r2 < hi) {
            int pos = atomicAdd(&cursor[r2], 1);
            if (pos < CAP) bucket[(size_t)r2 * CAP + pos] = d;
        }
        return;
    }
    b -= FILLB;
    if (b < 12500) {
        int i = b * 256 + threadIdx.x;          // 3,200,000 exact
        float2 v = ((const float2*)x)[i];
        xb[i] = ((unsigned)f2bf(v.y) << 16) | f2bf(v.x);
        return;
    }
    int i = (b - 12500) * 256 + threadIdx.x;    // 0..49151
    if (i < 8192) {                             // w1, two dirs, src [128][32]
        int j = i & 4095;
        int c = j >> 7, k = j & 127;
        const float* src = (i >> 12) ? uw1 : dw1;
        float v = src[k * 32 + c];
        unsigned short h = f2bf(v);
        w1h[i] = h; w1l[i] = f2bf(v - bf2f(h));
    } else if (i < 16384) {                     // w2, two dirs, src [32][128]
        int j = i - 8192;
        int jj = j & 4095;
        int c = jj >> 5, k = jj & 31;
        const float* src = (j >> 12) ? uw2 : dw2;
        float v = src[k * 128 + c];
        unsigned short h = f2bf(v);
        w2h[j] = h; w2l[j] = f2bf(v - bf2f(h));
    } else {                                    // cw hi only, src [256][128]
        int j = i - 16384;
        int c = j >> 8, k = j & 255;
        cwh[j] = f2bf(cw[k * 128 + c]);
    }
}

// ---------------------------------------------------------------------------
// y = x @ w1 per direction, bf16 out [2][NPAD][32].  Wave = 16 rows.
// Transposed-operand MFMA (same mapping as the verified stage-1).
// ---------------------------------------------------------------------------
__global__ __launch_bounds__(256) void y_gemm_kernel(
    const unsigned short* __restrict__ xbu,
    const unsigned short* __restrict__ w1bT_hi, const unsigned short* __restrict__ w1bT_lo,
    unsigned short* __restrict__ y)
{
    int w = threadIdx.x >> 6, lane = threadIdx.x & 63;
    int l15 = lane & 15, g = lane >> 4;
    int blk = blockIdx.x;                       // 0..1563
    int dir = (blk >= 782) ? 1 : 0;
    int r0 = (blk - dir * 782) * 64 + w * 16;

    const unsigned short* wh = w1bT_hi + dir * 4096;
    const unsigned short* wl = w1bT_lo + dir * 4096;

    int node = r0 + l15; if (node >= N_NODES) node = N_NODES - 1;
    const unsigned short* xrow = xbu + (size_t)node * H;

    f32x4 acc[2];
    acc[0] = (f32x4){0.f,0.f,0.f,0.f};
    acc[1] = (f32x4){0.f,0.f,0.f,0.f};
    #pragma unroll
    for (int ks = 0; ks < 4; ++ks) {
        int ko = ks * 32 + g * 8;
        bf16x8 bh = *(const bf16x8*)(xrow + ko);
        #pragma unroll
        for (int t = 0; t < 2; ++t) {
            bf16x8 ah = *(const bf16x8*)(wh + (t * 16 + l15) * H + ko);
            bf16x8 al = *(const bf16x8*)(wl + (t * 16 + l15) * H + ko);
            acc[t] = __builtin_amdgcn_mfma_f32_16x16x32_bf16(ah, bh, acc[t], 0, 0, 0);
            acc[t] = __builtin_amdgcn_mfma_f32_16x16x32_bf16(al, bh, acc[t], 0, 0, 0);
        }
    }

    // lane (l15,g) holds row r0+l15, cols t*16+g*4+r  (pad rows written, never read)
    unsigned short* orow = y + ((size_t)dir * NPAD + r0 + l15) * B;
    #pragma unroll
    for (int t = 0; t < 2; ++t) {
        u16x4 o = {f2bf(acc[t][0]), f2bf(acc[t][1]), f2bf(acc[t][2]), f2bf(acc[t][3])};
        *(u16x4*)(orow + t * 16 + g * 4) = o;
    }
}

// ---------------------------------------------------------------------------
// FUSED gather(y-space) + LN(32) + ReLU + stage-2 MFMA + LN(128).
// Block = 64 rows of one direction; wave owns 16 rows (4 passes x 4 subgroups
// of 16 lanes).  No barriers (wave-private LDS).  LDS = 10 KB.
// ---------------------------------------------------------------------------
__global__ __launch_bounds__(256) void gather_mlp_kernel(
    const unsigned* __restrict__ y,             // [2][NPAD][16] uints (2 bf16 each)
    const int* __restrict__ cursor, const int* __restrict__ bucket,
    const float* __restrict__ eps_d_p, const float* __restrict__ eps_u_p,
    const unsigned short* __restrict__ w2bT_hi, const unsigned short* __restrict__ w2bT_lo,
    const float* __restrict__ dg1, const float* __restrict__ db1,
    const float* __restrict__ ug1, const float* __restrict__ ub1,
    const float* __restrict__ ln1g, const float* __restrict__ ln1b,
    const float* __restrict__ ln2g, const float* __restrict__ ln2b,
    const float* __restrict__ dir_emb,
    unsigned short* __restrict__ hcat)
{
    __shared__ unsigned short plds[4][2][16 * PSTRIDE];   // 10240 B

    int w = threadIdx.x >> 6, lane = threadIdx.x & 63;
    int sgrp = lane >> 4, l16 = lane & 15;
    int blk = blockIdx.x;                       // 0..1563
    int dir = (blk >= 782) ? 1 : 0;
    int r0 = (blk - dir * 782) * 64 + w * 16;   // this wave's node base

    float eps = 1.f + (dir ? eps_u_p[0] : eps_d_p[0]);
    const unsigned* yu = y + (size_t)dir * NPAD * 16;

    const float* g1p = dir ? ug1 : dg1;
    const float* b1p = dir ? ub1 : db1;
    float2 gv = ((const float2*)g1p)[l16];
    float2 bv = ((const float2*)b1p)[l16];

    unsigned short* mh = &plds[w][0][0];
    unsigned short* ml = &plds[w][1][0];

    // ---- gather + LN(32) + ReLU: 4 passes, 4 rows concurrent ----
    for (int p = 0; p < 4; ++p) {
        int rloc = p * 4 + sgrp;
        int node = r0 + rloc;
        float p0 = 0.f, p1 = 0.f;
        if (node < N_NODES) {
            int ridx = dir * N_NODES + node;
            int deg = cursor[ridx]; if (deg > CAP) deg = CAP;
            const int* nb = bucket + (size_t)ridx * CAP;
            float a0 = 0.f, a1 = 0.f;
            for (int base = 0; base < deg; base += 16) {
                int m = deg - base; if (m > 16) m = 16;
                int id = (l16 < m) ? nb[base + l16] : 0;
                int lim = m - 1;
                for (int j = 0; j < m; j += 8) {
                    unsigned r[8];
                    #pragma unroll
                    for (int q = 0; q < 8; ++q) {
                        int idx = j + q; if (idx > lim) idx = lim;
                        int nbid = __shfl(id, (sgrp << 4) + idx);
                        r[q] = yu[nbid * 16 + l16];
                    }
                    #pragma unroll
                    for (int q = 0; q < 8; ++q) {
                        if (j + q <= lim) {
                            a0 += __uint_as_float(r[q] << 16);
                            a1 += __uint_as_float(r[q] & 0xffff0000u);
                        }
                    }
                }
            }
            unsigned sv = yu[node * 16 + l16];
            float c0 = eps * __uint_as_float(sv << 16) + a0;
            float c1 = eps * __uint_as_float(sv & 0xffff0000u) + a1;
            // LN over 32 (xor masks <=8 stay within the 16-lane subgroup)
            float ss = c0 + c1, s2 = c0 * c0 + c1 * c1;
            #pragma unroll
            for (int m2 = 1; m2 <= 8; m2 <<= 1) {
                ss += __shfl_xor(ss, m2);
                s2 += __shfl_xor(s2, m2);
            }
            float mean = ss * (1.f / 32.f);
            float var  = s2 * (1.f / 32.f) - mean * mean;
            float rs   = rsqrtf(var + 1e-5f);
            p0 = fmaxf((c0 - mean) * rs * gv.x + bv.x, 0.f);
            p1 = fmaxf((c1 - mean) * rs * gv.y + bv.y, 0.f);
        }
        unsigned short q0 = f2bf(p0), q1 = f2bf(p1);
        *(unsigned*)(mh + rloc * PSTRIDE + 2 * l16) = ((unsigned)q1 << 16) | q0;
        *(unsigned*)(ml + rloc * PSTRIDE + 2 * l16) =
            ((unsigned)f2bf(p1 - bf2f(q1)) << 16) | f2bf(p0 - bf2f(q0));
    }
    // no barrier: wave-private produce/consume

    // ---- stage 2: per-wave 16-row MFMA ----
    int l15 = lane & 15, g = lane >> 4;

    const unsigned short* w2h = w2bT_hi + dir * 4096;
    const unsigned short* w2l = w2bT_lo + dir * 4096;

    bf16x8 pbh = *(const bf16x8*)(mh + l15 * PSTRIDE + g * 8);
    bf16x8 pbl = *(const bf16x8*)(ml + l15 * PSTRIDE + g * 8);

    f32x4 acc2[8];
    #pragma unroll
    for (int t = 0; t < 8; ++t) acc2[t] = (f32x4){0.f,0.f,0.f,0.f};
    #pragma unroll
    for (int t = 0; t < 8; ++t) {
        bf16x8 ah = *(const bf16x8*)(w2h + (t * 16 + l15) * 32 + g * 8);
        bf16x8 al = *(const bf16x8*)(w2l + (t * 16 + l15) * 32 + g * 8);
        acc2[t] = __builtin_amdgcn_mfma_f32_16x16x32_bf16(ah, pbh, acc2[t], 0, 0, 0);
        acc2[t] = __builtin_amdgcn_mfma_f32_16x16x32_bf16(al, pbh, acc2[t], 0, 0, 0);
        acc2[t] = __builtin_amdgcn_mfma_f32_16x16x32_bf16(ah, pbl, acc2[t], 0, 0, 0);
    }

    float av[8][4];
    float u = 0.f, u2 = 0.f;
    #pragma unroll
    for (int t = 0; t < 8; ++t) {
        float4 de = *(const float4*)(dir_emb + dir * H + t * 16 + g * 4);
        av[t][0] = fmaxf(acc2[t][0] + de.x, 0.f);
        av[t][1] = fmaxf(acc2[t][1] + de.y, 0.f);
        av[t][2] = fmaxf(acc2[t][2] + de.z, 0.f);
        av[t][3] = fmaxf(acc2[t][3] + de.w, 0.f);
        #pragma unroll
        for (int r = 0; r < 4; ++r) { u += av[t][r]; u2 += av[t][r] * av[t][r]; }
    }
    u  += __shfl_xor(u, 16);  u  += __shfl_xor(u, 32);
    u2 += __shfl_xor(u2, 16); u2 += __shfl_xor(u2, 32);
    float m2  = u * (1.f / 128.f);
    float v2  = u2 * (1.f / 128.f) - m2 * m2;
    float rs2 = rsqrtf(v2 + 1e-5f);

    const float* lgp = dir ? ln2g : ln1g;
    const float* lbp = dir ? ln2b : ln1b;
    if ((r0 + l15) < N_NODES) {
        unsigned short* orow = hcat + (size_t)(r0 + l15) * 256 + dir * 128;
        #pragma unroll
        for (int t = 0; t < 8; ++t) {
            float4 gg = *(const float4*)(lgp + t * 16 + g * 4);
            float4 bb = *(const float4*)(lbp + t * 16 + g * 4);
            u16x4 o;
            o[0] = f2bf((av[t][0] - m2) * rs2 * gg.x + bb.x);
            o[1] = f2bf((av[t][1] - m2) * rs2 * gg.y + bb.y);
            o[2] = f2bf((av[t][2] - m2) * rs2 * gg.z + bb.z);
            o[3] = f2bf((av[t][3] - m2) * rs2 * gg.w + bb.w);
            *(u16x4*)(orow + t * 16 + g * 4) = o;
        }
    }
}

// ---------------------------------------------------------------------------
// combine: out = hcat @ cw + cb.  Wave owns a 32-col strip, weights in regs,
// iterates 4 node-groups with double-buffered B-frags.
// ---------------------------------------------------------------------------
__global__ __launch_bounds__(256) void combine_mfma(
    const unsigned short* __restrict__ hcat,
    const unsigned short* __restrict__ cwh,
    const float* __restrict__ cb, float* __restrict__ out)
{
    int w = threadIdx.x >> 6, lane = threadIdx.x & 63;
    int l15 = lane & 15, g = lane >> 4;
    int gid = blockIdx.x * 4 + w;       // 0..3127
    int q = gid & 3;                    // col strip: cols q*32..q*32+31
    int j = gid >> 2;                   // 0..781

    const unsigned short* abase = cwh + (size_t)(q * 32 + l15) * 256 + g * 8;
    bf16x8 Ah[2][8];
    #pragma unroll
    for (int t = 0; t < 2; ++t)
        #pragma unroll
        for (int ks = 0; ks < 8; ++ks)
            Ah[t][ks] = *(const bf16x8*)(abase + (t * 16) * 256 + ks * 32);

    int grp[4]; int ng = 0;
    #pragma unroll
    for (int k = 0; k < 4; ++k) {
        int gg = j + 782 * k;
        if (gg < NGRP) grp[ng++] = gg;
    }
    if (ng == 0) return;

    bf16x8 Bc[8], Bn[8];
    {
        const unsigned short* bb = hcat + (size_t)grp[0] * 16 * 256 + l15 * 256 + g * 8;
        #pragma unroll
        for (int ks = 0; ks < 8; ++ks) Bc[ks] = *(const bf16x8*)(bb + ks * 32);
    }

    float4 bias0 = *(const float4*)(cb + q * 32 + g * 4);
    float4 bias1 = *(const float4*)(cb + q * 32 + 16 + g * 4);

    for (int i = 0; i < ng; ++i) {
        if (i + 1 < ng) {
            const unsigned short* bb = hcat + (size_t)grp[i + 1] * 16 * 256 + l15 * 256 + g * 8;
            #pragma unroll
            for (int ks = 0; ks < 8; ++ks) Bn[ks] = *(const bf16x8*)(bb + ks * 32);
        }

        f32x4 acc0 = (f32x4){0.f,0.f,0.f,0.f};
        f32x4 acc1 = (f32x4){0.f,0.f,0.f,0.f};
        #pragma unroll
        for (int ks = 0; ks < 8; ++ks) {
            acc0 = __builtin_amdgcn_mfma_f32_16x16x32_bf16(Ah[0][ks], Bc[ks], acc0, 0, 0, 0);
            acc1 = __builtin_amdgcn_mfma_f32_16x16x32_bf16(Ah[1][ks], Bc[ks], acc1, 0, 0, 0);
        }

        float* orow = out + (size_t)(grp[i] * 16 + l15) * 128 + q * 32;
        f32x4 v0 = acc0, v1 = acc1;
        v0[0] += bias0.x; v0[1] += bias0.y; v0[2] += bias0.z; v0[3] += bias0.w;
        v1[0] += bias1.x; v1[1] += bias1.y; v1[2] += bias1.z; v1[3] += bias1.w;
        *(f32x4*)(orow + g * 4) = v0;
        *(f32x4*)(orow + 16 + g * 4) = v1;

        #pragma unroll
        for (int ks = 0; ks < 8; ++ks) Bc[ks] = Bn[ks];
    }
}

// ---------------------------------------------------------------------------
extern "C" void kernel_launch(void* const* d_in, const int* in_sizes, int n_in,
                              void* d_out, int out_size, void* d_ws, size_t ws_size,
                              hipStream_t stream) {
    const float* x     = (const float*)d_in[0];
    const int*   ei    = (const int*)d_in[1];
    const float* eps_d = (const float*)d_in[2];
    const float* dw1   = (const float*)d_in[3];
    const float* dg1   = (const float*)d_in[4];
    const float* db1   = (const float*)d_in[5];
    const float* dw2   = (const float*)d_in[6];
    const float* eps_u = (const float*)d_in[7];
    const float* uw1   = (const float*)d_in[8];
    const float* ug1   = (const float*)d_in[9];
    const float* ub1   = (const float*)d_in[10];
    const float* uw2   = (const float*)d_in[11];
    const float* ln1g  = (const float*)d_in[12];
    const float* ln1b  = (const float*)d_in[13];
    const float* ln2g  = (const float*)d_in[14];
    const float* ln2b  = (const float*)d_in[15];
    const float* dire  = (const float*)d_in[16];
    const float* cw    = (const float*)d_in[17];
    const float* cb    = (const float*)d_in[18];

    int* cursor = (int*)d_ws;                               // 100000
    int* bucket = cursor + 2 * N_NODES;                     // 100000*64 ints
    unsigned* xb  = (unsigned*)(bucket + (size_t)2 * N_NODES * CAP);   // N*64
    unsigned short* yarr = (unsigned short*)(xb + (size_t)N_NODES * 64); // 2*NPAD*32
    unsigned short* hcat = yarr + (size_t)2 * NPAD * B;                  // N*256
    unsigned short* w1bT_hi = hcat + (size_t)N_NODES * 256;
    unsigned short* w1bT_lo = w1bT_hi + 8192;
    unsigned short* w2bT_hi = w1bT_lo + 8192;
    unsigned short* w2bT_lo = w2bT_hi + 8192;
    unsigned short* cwbT_hi = w2bT_lo + 8192;

    hipMemsetAsync(cursor, 0, 2 * N_NODES * sizeof(int), stream);

    fill_convert_kernel<<<FILLB + 12500 + 192, 256, 0, stream>>>(
        ei, cursor, bucket, x, xb, dw1, uw1, dw2, uw2, cw,
        w1bT_hi, w1bT_lo, w2bT_hi, w2bT_lo, cwbT_hi);

    y_gemm_kernel<<<1564, 256, 0, stream>>>(
        (const unsigned short*)xb, w1bT_hi, w1bT_lo, yarr);

    gather_mlp_kernel<<<1564, 256, 0, stream>>>(
        (const unsigned*)yarr, cursor, bucket, eps_d, eps_u,
        w2bT_hi, w2bT_lo,
        dg1, db1, ug1, ub1, ln1g, ln1b, ln2g, ln2b, dire, hcat);

    combine_mfma<<<782, 256, 0, stream>>>(hcat, cwbT_hi, cb, (float*)d_out);
}

// Round 12
// 149.713 us; speedup vs baseline: 5.4001x; 1.0046x over previous
//
#include <hip/hip_runtime.h>

#define N_NODES 50000
#define NPAD 50048            // 64*782 padded rows per direction (y array)
#define N_EDGES 625000
#define H 128
#define B 32
#define PSTRIDE 40            // ushorts per stage-2 P row
#define CAP 64                // bucket capacity per (node,dir); P(overflow) ~ 1e-24
#define NPART 8
#define ROWS_PER_PART (2 * N_NODES / NPART)   // 12500
#define NGRP 3125             // node groups of 16 (exact: 3125*16 = 50000)
#define FILLB (2443 * NPART)  // fill blocks in merged front-end kernel

using bf16x8  = __attribute__((ext_vector_type(8))) short;
using f32x4   = __attribute__((ext_vector_type(4))) float;
using u16x4   = __attribute__((ext_vector_type(4))) unsigned short;

static __device__ __forceinline__ unsigned short f2bf(float f) {
    unsigned u = __float_as_uint(f);
    unsigned r = (u + 0x7fff + ((u >> 16) & 1)) >> 16;   // RNE
    return (unsigned short)r;
}
static __device__ __forceinline__ float bf2f(unsigned short h) {
    return __uint_as_float(((unsigned)h) << 16);
}

// ---------------------------------------------------------------------------
// merged front-end: blocks [0,FILLB) build the direct-bucket CSR with
// USHORT neighbor ids (node ids < 50000 < 65536) -> halves scattered writes.
// Remaining blocks: x->bf16 and weight transposes/hi-lo splits.
// ---------------------------------------------------------------------------
__global__ __launch_bounds__(256) void fill_convert_kernel(
    const int* __restrict__ ei, int* __restrict__ cursor,
    unsigned short* __restrict__ bucket,
    const float* __restrict__ x, unsigned* __restrict__ xb,
    const float* __restrict__ dw1, const float* __restrict__ uw1,
    const float* __restrict__ dw2, const float* __restrict__ uw2,
    const float* __restrict__ cw,
    unsigned short* __restrict__ w1h, unsigned short* __restrict__ w1l,
    unsigned short* __restrict__ w2h, unsigned short* __restrict__ w2l,
    unsigned short* __restrict__ cwh)
{
    int b = blockIdx.x;
    if (b < FILLB) {
        int p  = b & 7;
        int eb = b >> 3;
        int e = eb * 256 + threadIdx.x;
        if (e >= N_EDGES) return;
        int lo = p * ROWS_PER_PART, hi = lo + ROWS_PER_PART;
        int s = ei[e];
        int d = ei[N_EDGES + e];
        int r2 = N_NODES + s;
        if (d >= lo && d < hi) {
            int pos = atomicAdd(&cursor[d], 1);
            if (pos < CAP) bucket[(size_t)d * CAP + pos] = (unsigned short)s;
        }
        if (r2 >= lo && r2 < hi) {
            int pos = atomicAdd(&cursor[r2], 1);
            if (pos < CAP) bucket[(size_t)r2 * CAP + pos] = (unsigned short)d;
        }
        return;
    }
    b -= FILLB;
    if (b < 12500) {
        int i = b * 256 + threadIdx.x;          // 3,200,000 exact
        float2 v = ((const float2*)x)[i];
        xb[i] = ((unsigned)f2bf(v.y) << 16) | f2bf(v.x);
        return;
    }
    int i = (b - 12500) * 256 + threadIdx.x;    // 0..49151
    if (i < 8192) {                             // w1, two dirs, src [128][32]
        int j = i & 4095;
        int c = j >> 7, k = j & 127;
        const float* src = (i >> 12) ? uw1 : dw1;
        float v = src[k * 32 + c];
        unsigned short h = f2bf(v);
        w1h[i] = h; w1l[i] = f2bf(v - bf2f(h));
    } else if (i < 16384) {                     // w2, two dirs, src [32][128]
        int j = i - 8192;
        int jj = j & 4095;
        int c = jj >> 5, k = jj & 31;
        const float* src = (j >> 12) ? uw2 : dw2;
        float v = src[k * 128 + c];
        unsigned short h = f2bf(v);
        w2h[j] = h; w2l[j] = f2bf(v - bf2f(h));
    } else {                                    // cw hi only, src [256][128]
        int j = i - 16384;
        int c = j >> 8, k = j & 255;
        cwh[j] = f2bf(cw[k * 128 + c]);
    }
}

// ---------------------------------------------------------------------------
// y = x @ w1 per direction, bf16 out [2][NPAD][32].  Wave = 16 rows.
// ---------------------------------------------------------------------------
__global__ __launch_bounds__(256) void y_gemm_kernel(
    const unsigned short* __restrict__ xbu,
    const unsigned short* __restrict__ w1bT_hi, const unsigned short* __restrict__ w1bT_lo,
    unsigned short* __restrict__ y)
{
    int w = threadIdx.x >> 6, lane = threadIdx.x & 63;
    int l15 = lane & 15, g = lane >> 4;
    int blk = blockIdx.x;                       // 0..1563
    int dir = (blk >= 782) ? 1 : 0;
    int r0 = (blk - dir * 782) * 64 + w * 16;

    const unsigned short* wh = w1bT_hi + dir * 4096;
    const unsigned short* wl = w1bT_lo + dir * 4096;

    int node = r0 + l15; if (node >= N_NODES) node = N_NODES - 1;
    const unsigned short* xrow = xbu + (size_t)node * H;

    f32x4 acc[2];
    acc[0] = (f32x4){0.f,0.f,0.f,0.f};
    acc[1] = (f32x4){0.f,0.f,0.f,0.f};
    #pragma unroll
    for (int ks = 0; ks < 4; ++ks) {
        int ko = ks * 32 + g * 8;
        bf16x8 bh = *(const bf16x8*)(xrow + ko);
        #pragma unroll
        for (int t = 0; t < 2; ++t) {
            bf16x8 ah = *(const bf16x8*)(wh + (t * 16 + l15) * H + ko);
            bf16x8 al = *(const bf16x8*)(wl + (t * 16 + l15) * H + ko);
            acc[t] = __builtin_amdgcn_mfma_f32_16x16x32_bf16(ah, bh, acc[t], 0, 0, 0);
            acc[t] = __builtin_amdgcn_mfma_f32_16x16x32_bf16(al, bh, acc[t], 0, 0, 0);
        }
    }

    unsigned short* orow = y + ((size_t)dir * NPAD + r0 + l15) * B;
    #pragma unroll
    for (int t = 0; t < 2; ++t) {
        u16x4 o = {f2bf(acc[t][0]), f2bf(acc[t][1]), f2bf(acc[t][2]), f2bf(acc[t][3])};
        *(u16x4*)(orow + t * 16 + g * 4) = o;
    }
}

// ---------------------------------------------------------------------------
// FUSED gather(y-space) + LN(32) + ReLU + stage-2 MFMA + LN(128).
// Block = 64 rows of one direction; wave owns 16 rows (4 passes x 4 subgroups
// of 16 lanes).  No barriers (wave-private LDS).  LDS = 10 KB.
// ---------------------------------------------------------------------------
__global__ __launch_bounds__(256) void gather_mlp_kernel(
    const unsigned* __restrict__ y,             // [2][NPAD][16] uints (2 bf16 each)
    const int* __restrict__ cursor, const unsigned short* __restrict__ bucket,
    const float* __restrict__ eps_d_p, const float* __restrict__ eps_u_p,
    const unsigned short* __restrict__ w2bT_hi, const unsigned short* __restrict__ w2bT_lo,
    const float* __restrict__ dg1, const float* __restrict__ db1,
    const float* __restrict__ ug1, const float* __restrict__ ub1,
    const float* __restrict__ ln1g, const float* __restrict__ ln1b,
    const float* __restrict__ ln2g, const float* __restrict__ ln2b,
    const float* __restrict__ dir_emb,
    unsigned short* __restrict__ hcat)
{
    __shared__ unsigned short plds[4][2][16 * PSTRIDE];   // 10240 B

    int w = threadIdx.x >> 6, lane = threadIdx.x & 63;
    int sgrp = lane >> 4, l16 = lane & 15;
    int blk = blockIdx.x;                       // 0..1563
    int dir = (blk >= 782) ? 1 : 0;
    int r0 = (blk - dir * 782) * 64 + w * 16;   // this wave's node base

    float eps = 1.f + (dir ? eps_u_p[0] : eps_d_p[0]);
    const unsigned* yu = y + (size_t)dir * NPAD * 16;

    const float* g1p = dir ? ug1 : dg1;
    const float* b1p = dir ? ub1 : db1;
    float2 gv = ((const float2*)g1p)[l16];
    float2 bv = ((const float2*)b1p)[l16];

    unsigned short* mh = &plds[w][0][0];
    unsigned short* ml = &plds[w][1][0];

    // ---- gather + LN(32) + ReLU: 4 passes, 4 rows concurrent ----
    for (int p = 0; p < 4; ++p) {
        int rloc = p * 4 + sgrp;
        int node = r0 + rloc;
        float p0 = 0.f, p1 = 0.f;
        if (node < N_NODES) {
            int ridx = dir * N_NODES + node;
            int deg = cursor[ridx]; if (deg > CAP) deg = CAP;
            const unsigned short* nb = bucket + (size_t)ridx * CAP;
            float a0 = 0.f, a1 = 0.f;
            for (int base = 0; base < deg; base += 16) {
                int m = deg - base; if (m > 16) m = 16;
                int id = (l16 < m) ? (int)nb[base + l16] : 0;
                int lim = m - 1;
                for (int j = 0; j < m; j += 8) {
                    unsigned r[8];
                    #pragma unroll
                    for (int q = 0; q < 8; ++q) {
                        int idx = j + q; if (idx > lim) idx = lim;
                        int nbid = __shfl(id, (sgrp << 4) + idx);
                        r[q] = yu[nbid * 16 + l16];
                    }
                    #pragma unroll
                    for (int q = 0; q < 8; ++q) {
                        if (j + q <= lim) {
                            a0 += __uint_as_float(r[q] << 16);
                            a1 += __uint_as_float(r[q] & 0xffff0000u);
                        }
                    }
                }
            }
            unsigned sv = yu[node * 16 + l16];
            float c0 = eps * __uint_as_float(sv << 16) + a0;
            float c1 = eps * __uint_as_float(sv & 0xffff0000u) + a1;
            // LN over 32 (xor masks <=8 stay within the 16-lane subgroup)
            float ss = c0 + c1, s2 = c0 * c0 + c1 * c1;
            #pragma unroll
            for (int m2 = 1; m2 <= 8; m2 <<= 1) {
                ss += __shfl_xor(ss, m2);
                s2 += __shfl_xor(s2, m2);
            }
            float mean = ss * (1.f / 32.f);
            float var  = s2 * (1.f / 32.f) - mean * mean;
            float rs   = rsqrtf(var + 1e-5f);
            p0 = fmaxf((c0 - mean) * rs * gv.x + bv.x, 0.f);
            p1 = fmaxf((c1 - mean) * rs * gv.y + bv.y, 0.f);
        }
        unsigned short q0 = f2bf(p0), q1 = f2bf(p1);
        *(unsigned*)(mh + rloc * PSTRIDE + 2 * l16) = ((unsigned)q1 << 16) | q0;
        *(unsigned*)(ml + rloc * PSTRIDE + 2 * l16) =
            ((unsigned)f2bf(p1 - bf2f(q1)) << 16) | f2bf(p0 - bf2f(q0));
    }
    // no barrier: wave-private produce/consume

    // ---- stage 2: per-wave 16-row MFMA ----
    int l15 = lane & 15, g = lane >> 4;

    const unsigned short* w2h = w2bT_hi + dir * 4096;
    const unsigned short* w2l = w2bT_lo + dir * 4096;

    bf16x8 pbh = *(const bf16x8*)(mh + l15 * PSTRIDE + g * 8);
    bf16x8 pbl = *(const bf16x8*)(ml + l15 * PSTRIDE + g * 8);

    f32x4 acc2[8];
    #pragma unroll
    for (int t = 0; t < 8; ++t) acc2[t] = (f32x4){0.f,0.f,0.f,0.f};
    #pragma unroll
    for (int t = 0; t < 8; ++t) {
        bf16x8 ah = *(const bf16x8*)(w2h + (t * 16 + l15) * 32 + g * 8);
        bf16x8 al = *(const bf16x8*)(w2l + (t * 16 + l15) * 32 + g * 8);
        acc2[t] = __builtin_amdgcn_mfma_f32_16x16x32_bf16(ah, pbh, acc2[t], 0, 0, 0);
        acc2[t] = __builtin_amdgcn_mfma_f32_16x16x32_bf16(al, pbh, acc2[t], 0, 0, 0);
        acc2[t] = __builtin_amdgcn_mfma_f32_16x16x32_bf16(ah, pbl, acc2[t], 0, 0, 0);
    }

    float av[8][4];
    float u = 0.f, u2 = 0.f;
    #pragma unroll
    for (int t = 0; t < 8; ++t) {
        float4 de = *(const float4*)(dir_emb + dir * H + t * 16 + g * 4);
        av[t][0] = fmaxf(acc2[t][0] + de.x, 0.f);
        av[t][1] = fmaxf(acc2[t][1] + de.y, 0.f);
        av[t][2] = fmaxf(acc2[t][2] + de.z, 0.f);
        av[t][3] = fmaxf(acc2[t][3] + de.w, 0.f);
        #pragma unroll
        for (int r = 0; r < 4; ++r) { u += av[t][r]; u2 += av[t][r] * av[t][r]; }
    }
    u  += __shfl_xor(u, 16);  u  += __shfl_xor(u, 32);
    u2 += __shfl_xor(u2, 16); u2 += __shfl_xor(u2, 32);
    float m2  = u * (1.f / 128.f);
    float v2  = u2 * (1.f / 128.f) - m2 * m2;
    float rs2 = rsqrtf(v2 + 1e-5f);

    const float* lgp = dir ? ln2g : ln1g;
    const float* lbp = dir ? ln2b : ln1b;
    if ((r0 + l15) < N_NODES) {
        unsigned short* orow = hcat + (size_t)(r0 + l15) * 256 + dir * 128;
        #pragma unroll
        for (int t = 0; t < 8; ++t) {
            float4 gg = *(const float4*)(lgp + t * 16 + g * 4);
            float4 bb = *(const float4*)(lbp + t * 16 + g * 4);
            u16x4 o;
            o[0] = f2bf((av[t][0] - m2) * rs2 * gg.x + bb.x);
            o[1] = f2bf((av[t][1] - m2) * rs2 * gg.y + bb.y);
            o[2] = f2bf((av[t][2] - m2) * rs2 * gg.z + bb.z);
            o[3] = f2bf((av[t][3] - m2) * rs2 * gg.w + bb.w);
            *(u16x4*)(orow + t * 16 + g * 4) = o;
        }
    }
}

// ---------------------------------------------------------------------------
// combine: out = hcat @ cw + cb.  Wave owns a 32-col strip, weights in regs,
// iterates 4 node-groups with double-buffered B-frags.
// ---------------------------------------------------------------------------
__global__ __launch_bounds__(256) void combine_mfma(
    const unsigned short* __restrict__ hcat,
    const unsigned short* __restrict__ cwh,
    const float* __restrict__ cb, float* __restrict__ out)
{
    int w = threadIdx.x >> 6, lane = threadIdx.x & 63;
    int l15 = lane & 15, g = lane >> 4;
    int gid = blockIdx.x * 4 + w;       // 0..3127
    int q = gid & 3;                    // col strip: cols q*32..q*32+31
    int j = gid >> 2;                   // 0..781

    const unsigned short* abase = cwh + (size_t)(q * 32 + l15) * 256 + g * 8;
    bf16x8 Ah[2][8];
    #pragma unroll
    for (int t = 0; t < 2; ++t)
        #pragma unroll
        for (int ks = 0; ks < 8; ++ks)
            Ah[t][ks] = *(const bf16x8*)(abase + (t * 16) * 256 + ks * 32);

    int grp[4]; int ng = 0;
    #pragma unroll
    for (int k = 0; k < 4; ++k) {
        int gg = j + 782 * k;
        if (gg < NGRP) grp[ng++] = gg;
    }
    if (ng == 0) return;

    bf16x8 Bc[8], Bn[8];
    {
        const unsigned short* bb = hcat + (size_t)grp[0] * 16 * 256 + l15 * 256 + g * 8;
        #pragma unroll
        for (int ks = 0; ks < 8; ++ks) Bc[ks] = *(const bf16x8*)(bb + ks * 32);
    }

    float4 bias0 = *(const float4*)(cb + q * 32 + g * 4);
    float4 bias1 = *(const float4*)(cb + q * 32 + 16 + g * 4);

    for (int i = 0; i < ng; ++i) {
        if (i + 1 < ng) {
            const unsigned short* bb = hcat + (size_t)grp[i + 1] * 16 * 256 + l15 * 256 + g * 8;
            #pragma unroll
            for (int ks = 0; ks < 8; ++ks) Bn[ks] = *(const bf16x8*)(bb + ks * 32);
        }

        f32x4 acc0 = (f32x4){0.f,0.f,0.f,0.f};
        f32x4 acc1 = (f32x4){0.f,0.f,0.f,0.f};
        #pragma unroll
        for (int ks = 0; ks < 8; ++ks) {
            acc0 = __builtin_amdgcn_mfma_f32_16x16x32_bf16(Ah[0][ks], Bc[ks], acc0, 0, 0, 0);
            acc1 = __builtin_amdgcn_mfma_f32_16x16x32_bf16(Ah[1][ks], Bc[ks], acc1, 0, 0, 0);
        }

        float* orow = out + (size_t)(grp[i] * 16 + l15) * 128 + q * 32;
        f32x4 v0 = acc0, v1 = acc1;
        v0[0] += bias0.x; v0[1] += bias0.y; v0[2] += bias0.z; v0[3] += bias0.w;
        v1[0] += bias1.x; v1[1] += bias1.y; v1[2] += bias1.z; v1[3] += bias1.w;
        *(f32x4*)(orow + g * 4) = v0;
        *(f32x4*)(orow + 16 + g * 4) = v1;

        #pragma unroll
        for (int ks = 0; ks < 8; ++ks) Bc[ks] = Bn[ks];
    }
}

// ---------------------------------------------------------------------------
extern "C" void kernel_launch(void* const* d_in, const int* in_sizes, int n_in,
                              void* d_out, int out_size, void* d_ws, size_t ws_size,
                              hipStream_t stream) {
    const float* x     = (const float*)d_in[0];
    const int*   ei    = (const int*)d_in[1];
    const float* eps_d = (const float*)d_in[2];
    const float* dw1   = (const float*)d_in[3];
    const float* dg1   = (const float*)d_in[4];
    const float* db1   = (const float*)d_in[5];
    const float* dw2   = (const float*)d_in[6];
    const float* eps_u = (const float*)d_in[7];
    const float* uw1   = (const float*)d_in[8];
    const float* ug1   = (const float*)d_in[9];
    const float* ub1   = (const float*)d_in[10];
    const float* uw2   = (const float*)d_in[11];
    const float* ln1g  = (const float*)d_in[12];
    const float* ln1b  = (const float*)d_in[13];
    const float* ln2g  = (const float*)d_in[14];
    const float* ln2b  = (const float*)d_in[15];
    const float* dire  = (const float*)d_in[16];
    const float* cw    = (const float*)d_in[17];
    const float* cb    = (const float*)d_in[18];

    int* cursor = (int*)d_ws;                                   // 100000 ints
    unsigned short* bucket = (unsigned short*)(cursor + 2 * N_NODES); // 6.4M ushorts
    unsigned* xb  = (unsigned*)(bucket + (size_t)2 * N_NODES * CAP);  // N*64 uints
    unsigned short* yarr = (unsigned short*)(xb + (size_t)N_NODES * 64); // 2*NPAD*32
    unsigned short* hcat = yarr + (size_t)2 * NPAD * B;               // N*256
    unsigned short* w1bT_hi = hcat + (size_t)N_NODES * 256;
    unsigned short* w1bT_lo = w1bT_hi + 8192;
    unsigned short* w2bT_hi = w1bT_lo + 8192;
    unsigned short* w2bT_lo = w2bT_hi + 8192;
    unsigned short* cwbT_hi = w2bT_lo + 8192;

    hipMemsetAsync(cursor, 0, 2 * N_NODES * sizeof(int), stream);

    fill_convert_kernel<<<FILLB + 12500 + 192, 256, 0, stream>>>(
        ei, cursor, bucket, x, xb, dw1, uw1, dw2, uw2, cw,
        w1bT_hi, w1bT_lo, w2bT_hi, w2bT_lo, cwbT_hi);

    y_gemm_kernel<<<1564, 256, 0, stream>>>(
        (const unsigned short*)xb, w1bT_hi, w1bT_lo, yarr);

    gather_mlp_kernel<<<1564, 256, 0, stream>>>(
        (const unsigned*)yarr, cursor, bucket, eps_d, eps_u,
        w2bT_hi, w2bT_lo,
        dg1, db1, ug1, ub1, ln1g, ln1b, ln2g, ln2b, dire, hcat);

    combine_mfma<<<782, 256, 0, stream>>>(hcat, cwbT_hi, cb, (float*)d_out);
}